// Round 11
// baseline (363.499 us; speedup 1.0000x reference)
//
#include <hip/hip_runtime.h>
#include <math.h>

typedef __attribute__((ext_vector_type(8))) short short8;
typedef __attribute__((ext_vector_type(4))) float float4v;

#define QS 0.17677669529663687f   // 1/sqrt(32), folded into wq/bq; exp via __expf

__device__ __forceinline__ float waveReduceSum(float v){
  #pragma unroll
  for(int o=32;o>0;o>>=1) v += __shfl_down(v,o,64);
  return v;
}

__device__ __forceinline__ unsigned short f2bf(float f){
  unsigned int u = __float_as_uint(f);
  return (unsigned short)((u + 0x7FFFu + ((u>>16)&1u)) >> 16);
}
__device__ __forceinline__ float bf2f(unsigned short u){
  return __uint_as_float(((unsigned int)u)<<16);
}

// ---------------- fused prep: x->bf16 + weight transposes + qkv concat ----------------
__global__ __launch_bounds__(256) void prep(const float* __restrict__ x, unsigned short* __restrict__ xb,
                     const float* __restrict__ W0, unsigned short* __restrict__ W0t,
                     const float* __restrict__ W1, unsigned short* __restrict__ W1t,
                     const float* __restrict__ W2, unsigned short* __restrict__ W2t,
                     const float* __restrict__ wq, const float* __restrict__ wk,
                     const float* __restrict__ wv, unsigned short* __restrict__ wqkvt,
                     const float* __restrict__ bq, const float* __restrict__ bk,
                     const float* __restrict__ bv, float* __restrict__ bqkv,
                     const float* __restrict__ wo, unsigned short* __restrict__ wot){
  int b = blockIdx.x, t = threadIdx.x;
  if(b < 2048){ int i = b*256 + t; xb[i] = f2bf(x[i]); return; }
  if(b == 4864){ bqkv[t] = bq[t]*QS; bqkv[256+t] = bk[t]; bqkv[512+t] = bv[t]; return; }
  const float* src; unsigned short* dst; int K,N,base,roff; float sc = 1.f;
  if(b<2304){src=W0;dst=W0t;K=128;N=512;base=2048;roff=0;}
  else if(b<3328){src=W1;dst=W1t;K=512;N=512;base=2304;roff=0;}
  else if(b<3840){src=W2;dst=W2t;K=512;N=256;base=3328;roff=0;}
  else if(b<4096){src=wq;dst=wqkvt;K=256;N=256;base=3840;roff=0;sc=QS;}
  else if(b<4352){src=wk;dst=wqkvt;K=256;N=256;base=4096;roff=256;}
  else if(b<4608){src=wv;dst=wqkvt;K=256;N=256;base=4352;roff=512;}
  else            {src=wo;dst=wot;K=256;N=256;base=4608;roff=0;}
  int idx = (b-base)*256 + t;
  int k = idx / N, n = idx - k*N;
  dst[(n+roff)*K + k] = f2bf(src[idx]*sc);
}

// --------- Wsd[16][K] bf16: rows 0..H-1 = W@a_s per head, 4..4+H-1 = W@a_d, rest 0 ---------
__global__ __launch_bounds__(256) void make_wsd(const float* __restrict__ W0, const float* __restrict__ as0, const float* __restrict__ ad0, unsigned short* __restrict__ S0,
                                                const float* __restrict__ W1, const float* __restrict__ as1, const float* __restrict__ ad1, unsigned short* __restrict__ S1,
                                                const float* __restrict__ W2, const float* __restrict__ as2, const float* __restrict__ ad2, unsigned short* __restrict__ S2){
  int b = blockIdx.x, t = threadIdx.x;
  const float *W,*as,*ad; unsigned short* S; int K,C,H,k;
  if(b<128){W=W0;as=as0;ad=ad0;S=S0;K=128;C=128;H=4;k=b;}
  else if(b<640){W=W1;as=as1;ad=ad1;S=S1;K=512;C=128;H=4;k=b-128;}
  else {W=W2;as=as2;ad=ad2;S=S2;K=512;C=256;H=1;k=b-640;}
  int D = H*C;
  __shared__ float s1[4], s2[4];
  int lane=t&63, wid=t>>6;
  for(int h=0;h<H;h++){
    float ps=0.f, pd=0.f;
    for(int c=t;c<C;c+=256){
      float wv = W[k*D + h*C + c];
      ps += wv*as[h*C+c];
      pd += wv*ad[h*C+c];
    }
    ps = waveReduceSum(ps); pd = waveReduceSum(pd);
    if(lane==0){ s1[wid]=ps; s2[wid]=pd; }
    __syncthreads();
    if(t==0){
      float u=s1[0]+s1[1]+s1[2]+s1[3], v=s2[0]+s2[1]+s2[2]+s2[3];
      S[h*K+k]=f2bf(u); S[(4+h)*K+k]=f2bf(v);
    }
    __syncthreads();
  }
  if(t==0){
    for(int h=H;h<4;h++){ S[h*K+k]=0; S[(4+h)*K+k]=0; }
    for(int r=8;r<16;r++) S[r*K+k]=0;
  }
}

// ---------------- MFMA bf16 GEMM, zero-LDS; optional fused als/ald ----------------
// If Vt != null: cols >= 512 are written transposed to Vt[(col-512)*M+row] (bf16)
// instead of Cb (fused V-transpose for the QKV GEMM).
__global__ __launch_bounds__(256) void gemm_mfma(const unsigned short* __restrict__ A,
                                                 const unsigned short* __restrict__ Bt,
                                                 const float* __restrict__ bias,
                                                 float* __restrict__ C,
                                                 unsigned short* __restrict__ Cb,
                                                 unsigned short* __restrict__ Vt,
                                                 const unsigned short* __restrict__ Wsd,
                                                 float* __restrict__ als,
                                                 float* __restrict__ ald,
                                                 int M, int K, int N){
  int t = threadIdx.x, lane = t & 63, w = t >> 6;
  int m = lane & 15, g = lane >> 4;
  int bm = blockIdx.y * 64, bn = blockIdx.x * 64;

  const unsigned short* Ap = A + (bm + w*16 + m)*K + g*8;
  const unsigned short* Bp = Bt + (bn + m)*K + g*8;
  bool doC = (Wsd != nullptr) && (blockIdx.x == 0);

  float4v acc[4];
  #pragma unroll
  for(int nt=0;nt<4;nt++) acc[nt] = (float4v){0.f,0.f,0.f,0.f};
  float4v acc2 = (float4v){0.f,0.f,0.f,0.f};

  for(int k0=0;k0<K;k0+=32){
    short8 aA = *(const short8*)(Ap + k0);
    #pragma unroll
    for(int nt=0;nt<4;nt++){
      short8 bB = *(const short8*)(Bp + nt*16*K + k0);
      acc[nt] = __builtin_amdgcn_mfma_f32_16x16x32_bf16(aA, bB, acc[nt], 0,0,0);
    }
    if(doC){
      short8 bW = *(const short8*)(Wsd + m*K + g*8 + k0);
      acc2 = __builtin_amdgcn_mfma_f32_16x16x32_bf16(aA, bW, acc2, 0,0,0);
    }
  }
  bool vcols = (Vt != nullptr) && (bn >= 512);
  #pragma unroll
  for(int nt=0;nt<4;nt++){
    int col = bn + nt*16 + m;
    float bv = bias ? bias[col] : 0.f;
    #pragma unroll
    for(int r=0;r<4;r++){
      int row = bm + w*16 + g*4 + r;
      float v = acc[nt][r] + bv;
      if(C)  C[row*N + col]  = v;
      if(vcols)       Vt[(col-512)*M + row] = f2bf(v);
      else if(Cb)     Cb[row*N + col] = f2bf(v);
    }
  }
  if(doC){
    #pragma unroll
    for(int r=0;r<4;r++){
      int row = bm + w*16 + g*4 + r;
      if(m<4)      als[row*4 + m]     = acc2[r];
      else if(m<8) ald[row*4 + (m-4)] = acc2[r];
    }
  }
}

// ---------------- CSR build ----------------
__global__ void csr_count(const int* __restrict__ ei, int E, int Etot,
                          int* __restrict__ hist){
  int e = blockIdx.x*256 + threadIdx.x;
  if(e>=Etot) return;
  int d = (e<E) ? (ei[E+e]&4095) : (e-E);
  atomicAdd(&hist[d], 1);
}

__global__ __launch_bounds__(1024) void csr_scan(const int* __restrict__ hist,
                                                 int* __restrict__ row_ptr,
                                                 int* __restrict__ wcnt, int N){
  __shared__ int sh[1024];
  int t = threadIdx.x;
  int base[4];
  int s = 0;
  #pragma unroll
  for(int i=0;i<4;i++){ base[i]=s; s += hist[t*4+i]; }
  sh[t] = s;
  __syncthreads();
  for(int off=1; off<1024; off<<=1){
    int x = (t>=off) ? sh[t-off] : 0;
    __syncthreads();
    sh[t] += x;
    __syncthreads();
  }
  int excl = (t==0) ? 0 : sh[t-1];
  #pragma unroll
  for(int i=0;i<4;i++){
    row_ptr[t*4+i] = excl + base[i];
    wcnt[t*4+i]    = excl + base[i];
  }
  if(t==1023) row_ptr[N] = excl + s;
}

__global__ void csr_scatter(const int* __restrict__ ei, int E, int Etot,
                            int* __restrict__ wcnt, int* __restrict__ col){
  int e = blockIdx.x*256 + threadIdx.x;
  if(e>=Etot) return;
  int s,d;
  if(e<E){ s=ei[e]&4095; d=ei[E+e]&4095; } else { s=d=e-E; }
  int pos = atomicAdd(&wcnt[d], 1);
  col[pos] = s;
}

// ------- fused GAT gather + softmax + bias + ELU + LayerNorm (+residual) -------
#define CE 128
__global__ void gat_gather_ln(const int* __restrict__ rp,
                              const int* __restrict__ col,
                              const unsigned short* __restrict__ xlb,
                              const float* __restrict__ als,
                              const float* __restrict__ ald,
                              const float* __restrict__ bias,
                              const float* __restrict__ gw,
                              const float* __restrict__ be,
                              const float* __restrict__ res,
                              float* __restrict__ out,
                              unsigned short* __restrict__ outb,
                              int D, int logC, int do_elu){
  int n = blockIdx.x, t = threadIdx.x;
  int c0 = t*2;
  int h = c0 >> logC;            // wave-uniform
  int rowW = D >> 1;
  float4 advv = *(const float4*)(ald + n*4);
  int start = rp[n], end = rp[n+1];
  const unsigned int* xw = (const unsigned int*)xlb;

  __shared__ float pw[CE*4];
  __shared__ int offs[CE];

  float acc0=0.f, acc1=0.f, den=0.f;

  for(int base=start; base<end; base+=CE){
    int cnt = min(CE, end-base);
    __syncthreads();
    if(t < cnt){
      int s = col[base+t];
      offs[t] = s*rowW;
      float4 av = *(const float4*)(als + s*4);
      #pragma unroll
      for(int hh=0;hh<4;hh++){
        float a = ((const float*)&av)[hh] + ((const float*)&advv)[hh];
        a = a>0.f ? a : 0.2f*a;
        pw[t*4+hh] = __expf(a);
      }
    }
    __syncthreads();
    #pragma unroll 4
    for(int j=0;j<cnt;j++){
      float p = pw[j*4+h];
      unsigned int u = xw[offs[j] + t];
      acc0 += p * bf2f((unsigned short)(u & 0xffffu));
      acc1 += p * bf2f((unsigned short)(u >> 16));
      den += p;
    }
  }

  float inv_d = 1.f/(den + 1e-16f);
  float v0 = acc0*inv_d + bias[c0];
  float v1 = acc1*inv_d + bias[c0+1];
  if(do_elu){
    v0 = v0>0.f ? v0 : expm1f(v0);
    v1 = v1>0.f ? v1 : expm1f(v1);
  }
  __shared__ float sh[4];
  int lane=t&63, wid=t>>6, nw = blockDim.x>>6;
  float sum = waveReduceSum(v0+v1);
  if(lane==0) sh[wid]=sum;
  __syncthreads();
  float mean = 0.f;
  for(int i=0;i<nw;i++) mean += sh[i];
  mean /= (float)D;
  __syncthreads();
  float d0 = v0-mean, d1 = v1-mean;
  float vs = waveReduceSum(d0*d0 + d1*d1);
  if(lane==0) sh[wid]=vs;
  __syncthreads();
  float var = 0.f;
  for(int i=0;i<nw;i++) var += sh[i];
  var /= (float)D;
  float inv = rsqrtf(var + 1e-5f);
  float y0 = d0*inv*gw[c0]   + be[c0];
  float y1 = d1*inv*gw[c0+1] + be[c0+1];
  if(res){ float2 rv = *(const float2*)(res + n*D + c0); y0 += rv.x; y1 += rv.y; }
  if(out) *(float2*)(out + n*D + c0) = make_float2(y0, y1);
  if(outb) ((unsigned int*)outb)[n*rowW + t] =
      (unsigned int)f2bf(y0) | ((unsigned int)f2bf(y1) << 16);
}

// --------- MFMA bf16 MHA, flash-decode: block=(64q, head, ksplit) ---------
// Single-buffered Vs + bf16 Ps (R6 geometry); S^T MFMA (lane owns 4 consecutive
// keys of one query, b64 Ps writes, scalar l). exp via __expf (2-inst native).
#define KS 4
__global__ __launch_bounds__(256) void attention9(const unsigned short* __restrict__ QKV,
                                                  const unsigned short* __restrict__ Vt,
                                                  float* __restrict__ Op,
                                                  float* __restrict__ lp, int S){
  const int RS = 768;
  int qb = blockIdx.x * 64;
  int h  = blockIdx.y;
  int ks = blockIdx.z;
  int t  = threadIdx.x;
  int lane = t & 63, w = t >> 6;
  int m = lane & 15, g = lane >> 4;

  __shared__ unsigned short Ps[64*72];   // [q][key] bf16, stride 72
  __shared__ unsigned short Vs[32*72];   // [dim][key] bf16, stride 72

  short8 aQ = *(const short8*)(QKV + (qb + w*16 + m)*RS + h*32 + g*8);

  float4v o0 = {0.f,0.f,0.f,0.f}, o1 = {0.f,0.f,0.f,0.f};
  float l = 0.f;

  int r8 = t>>3, c8 = (t&7)*8;
  int kA = ks*(S/KS), kB = kA + S/KS;

  for(int kt=kA; kt<kB; kt+=64){
    // stage V^T tile (coalesced b128 read, b128 LDS write)
    short8 v = *(const short8*)(Vt + (h*32 + r8)*S + kt + c8);
    *(short8*)&Vs[r8*72 + c8] = v;
    __syncthreads();

    // S^T strip: mfma(A=K-frag, B=Q-frag) -> lane holds 4 consecutive keys of query m
    const unsigned short* Kp = QKV + (kt + m)*RS + 256 + h*32 + g*8;
    #pragma unroll
    for(int nt=0;nt<4;nt++){
      short8 aK = *(const short8*)(Kp + nt*16*RS);
      float4v acc = {0.f,0.f,0.f,0.f};
      acc = __builtin_amdgcn_mfma_f32_16x16x32_bf16(aK, aQ, acc, 0,0,0);
      float p0 = __expf(acc[0]);
      float p1 = __expf(acc[1]);
      float p2 = __expf(acc[2]);
      float p3 = __expf(acc[3]);
      l += (p0+p1) + (p2+p3);
      unsigned int r0 = __float_as_uint(p0) + 0x8000u;
      unsigned int r1 = __float_as_uint(p1) + 0x8000u;
      unsigned int r2 = __float_as_uint(p2) + 0x8000u;
      unsigned int r3 = __float_as_uint(p3) + 0x8000u;
      uint2 pk;
      pk.x = __builtin_amdgcn_perm(r1, r0, 0x07060302u);
      pk.y = __builtin_amdgcn_perm(r3, r2, 0x07060302u);
      *(uint2*)&Ps[(w*16 + m)*72 + nt*16 + g*4] = pk;
    }

    // O strip += P @ V (aP rows wave-private; same-wave LDS order suffices)
    #pragma unroll
    for(int kh=0;kh<2;kh++){
      short8 aP  = *(const short8*)&Ps[(w*16 + m)*72 + kh*32 + g*8];
      short8 bV0 = *(const short8*)&Vs[(m)*72    + kh*32 + g*8];
      short8 bV1 = *(const short8*)&Vs[(16+m)*72 + kh*32 + g*8];
      o0 = __builtin_amdgcn_mfma_f32_16x16x32_bf16(aP, bV0, o0, 0,0,0);
      o1 = __builtin_amdgcn_mfma_f32_16x16x32_bf16(aP, bV1, o1, 0,0,0);
    }
    __syncthreads();
  }

  l += __shfl_xor(l, 16, 64);
  l += __shfl_xor(l, 32, 64);

  float* Ob = Op + (size_t)ks*S*256;
  #pragma unroll
  for(int r=0;r<4;r++){
    int q = qb + w*16 + g*4 + r;
    Ob[q*256 + h*32 + m]      = o0[r];
    Ob[q*256 + h*32 + 16 + m] = o1[r];
  }
  if(g==0) lp[ks*S*8 + (qb + w*16 + m)*8 + h] = l;
}

__global__ __launch_bounds__(256) void combine(const float* __restrict__ Op,
                                               const float* __restrict__ lp,
                                               unsigned short* __restrict__ aob, int S){
  int q = blockIdx.x, t = threadIdx.x;
  int h = t >> 5;
  float o = 0.f, l = 0.f;
  #pragma unroll
  for(int s=0;s<KS;s++) o += Op[(size_t)s*S*256 + q*256 + t];
  #pragma unroll
  for(int s=0;s<KS;s++) l += lp[s*S*8 + q*8 + h];
  aob[q*256 + t] = f2bf(o / l);
}

extern "C" void kernel_launch(void* const* d_in, const int* in_sizes, int n_in,
                              void* d_out, int out_size, void* d_ws, size_t ws_size,
                              hipStream_t stream) {
  const float* x   = (const float*)d_in[0];
  const int*   ei  = (const int*)d_in[1];
  const float* W0  = (const float*)d_in[2];
  const float* as0 = (const float*)d_in[3];
  const float* ad0 = (const float*)d_in[4];
  const float* b0  = (const float*)d_in[5];
  const float* W1  = (const float*)d_in[6];
  const float* as1 = (const float*)d_in[7];
  const float* ad1 = (const float*)d_in[8];
  const float* b1  = (const float*)d_in[9];
  const float* W2  = (const float*)d_in[10];
  const float* as2 = (const float*)d_in[11];
  const float* ad2 = (const float*)d_in[12];
  const float* b2  = (const float*)d_in[13];
  const float* g0  = (const float*)d_in[14];
  const float* be0 = (const float*)d_in[15];
  const float* g1  = (const float*)d_in[16];
  const float* be1 = (const float*)d_in[17];
  const float* g2  = (const float*)d_in[18];
  const float* be2 = (const float*)d_in[19];
  const float* wq  = (const float*)d_in[20];
  const float* bq  = (const float*)d_in[21];
  const float* wk  = (const float*)d_in[22];
  const float* bk  = (const float*)d_in[23];
  const float* wv  = (const float*)d_in[24];
  const float* bv  = (const float*)d_in[25];
  const float* wo  = (const float*)d_in[26];
  const float* bo  = (const float*)d_in[27];
  float* out = (float*)d_out;

  const int N = 4096;
  const int E = in_sizes[1] / 2;
  const int Etot = E + N;

  char* p = (char*)d_ws;
  auto alloc = [&](size_t bytes){ char* r = p; p += (bytes + 255) & ~(size_t)255; return r; };

  float* h0   = (float*)alloc(N*512*4);
  float* als  = (float*)alloc(N*4*4);
  float* ald  = (float*)alloc(N*4*4);
  unsigned short* xb   = (unsigned short*)alloc(N*128*2);
  unsigned short* xlb  = (unsigned short*)alloc(N*512*2);
  unsigned short* h0b  = (unsigned short*)alloc(N*512*2);
  unsigned short* h1b  = (unsigned short*)alloc(N*512*2);
  unsigned short* h2b  = (unsigned short*)alloc(N*256*2);
  unsigned short* QKVb = (unsigned short*)alloc((size_t)N*768*2);
  unsigned short* Vt   = (unsigned short*)alloc(256*N*2);
  unsigned short* aob  = (unsigned short*)alloc(N*256*2);
  unsigned short* W0t  = (unsigned short*)alloc(512*128*2);
  unsigned short* W1t  = (unsigned short*)alloc(512*512*2);
  unsigned short* W2t  = (unsigned short*)alloc(256*512*2);
  unsigned short* wqkvt= (unsigned short*)alloc(768*256*2);
  float* bqkv = (float*)alloc(768*4);
  unsigned short* wot  = (unsigned short*)alloc(256*256*2);
  unsigned short* Wsd0 = (unsigned short*)alloc(16*128*2);
  unsigned short* Wsd1 = (unsigned short*)alloc(16*512*2);
  unsigned short* Wsd2 = (unsigned short*)alloc(16*512*2);
  float* Op = (float*)alloc((size_t)KS*N*256*4);
  float* lp = (float*)alloc((size_t)KS*N*8*4);
  int* hist = (int*)alloc(N*4);
  int* wcnt = (int*)alloc(N*4);
  int* rp   = (int*)alloc((N+2)*4);
  int* col  = (int*)alloc(Etot*4);

  // ---------- prep ----------
  prep<<<4865, 256, 0, stream>>>(x, xb, W0, W0t, W1, W1t, W2, W2t,
                                 wq, wk, wv, wqkvt, bq, bk, bv, bqkv, wo, wot);
  make_wsd<<<1152, 256, 0, stream>>>(W0, as0, ad0, Wsd0, W1, as1, ad1, Wsd1, W2, as2, ad2, Wsd2);

  // ---------- CSR build (by destination) ----------
  hipMemsetAsync(hist, 0, N*sizeof(int), stream);
  csr_count<<<(Etot+255)/256, 256, 0, stream>>>(ei, E, Etot, hist);
  csr_scan<<<1, 1024, 0, stream>>>(hist, rp, wcnt, N);
  csr_scatter<<<(Etot+255)/256, 256, 0, stream>>>(ei, E, Etot, wcnt, col);

  // ---------- GAT layer 0: 128 -> 4x128 (512) ----------
  gemm_mfma<<<dim3(8, 64), 256, 0, stream>>>(xb, W0t, nullptr, nullptr, xlb, nullptr, Wsd0, als, ald, N, 128, 512);
  gat_gather_ln<<<N, 256, 0, stream>>>(rp, col, xlb, als, ald, b0, g0, be0,
                                       nullptr, h0, h0b, 512, 7, 1);

  // ---------- GAT layer 1: 512 -> 4x128 (512), residual ----------
  gemm_mfma<<<dim3(8, 64), 256, 0, stream>>>(h0b, W1t, nullptr, nullptr, xlb, nullptr, Wsd1, als, ald, N, 512, 512);
  gat_gather_ln<<<N, 256, 0, stream>>>(rp, col, xlb, als, ald, b1, g1, be1,
                                       h0, nullptr, h1b, 512, 7, 1);

  // ---------- GAT layer 2: 512 -> 1x256, 1 head, no ELU ----------
  gemm_mfma<<<dim3(4, 64), 256, 0, stream>>>(h1b, W2t, nullptr, nullptr, xlb, nullptr, Wsd2, als, ald, N, 512, 256);
  gat_gather_ln<<<N, 128, 0, stream>>>(rp, col, xlb, als, ald, b2, g2, be2,
                                       nullptr, nullptr, h2b, 256, 8, 0);

  // ---------- dense MHA (bf16 MFMA, flash-decode, fused QKV + fused V-transpose) ----------
  gemm_mfma<<<dim3(12, 64), 256, 0, stream>>>(h2b, wqkvt, bqkv, nullptr, QKVb, Vt, nullptr, nullptr, nullptr, N, 256, 768);
  attention9<<<dim3(N/64, 8, KS), 256, 0, stream>>>(QKVb, Vt, Op, lp, N);
  combine<<<N, 256, 0, stream>>>(Op, lp, aob, N);
  gemm_mfma<<<dim3(4, 64), 256, 0, stream>>>(aob, wot, bo, out, nullptr, nullptr, nullptr, nullptr, nullptr, N, 256, 256);
}

// Round 12
// 317.607 us; speedup vs baseline: 1.1445x; 1.1445x over previous
//
#include <hip/hip_runtime.h>
#include <math.h>

typedef __attribute__((ext_vector_type(8))) short short8;
typedef __attribute__((ext_vector_type(4))) float float4v;

#define QS 0.17677669529663687f   // 1/sqrt(32), folded into wq/bq; exp via __expf

__device__ __forceinline__ float waveReduceSum(float v){
  #pragma unroll
  for(int o=32;o>0;o>>=1) v += __shfl_down(v,o,64);
  return v;
}

__device__ __forceinline__ unsigned short f2bf(float f){
  unsigned int u = __float_as_uint(f);
  return (unsigned short)((u + 0x7FFFu + ((u>>16)&1u)) >> 16);
}
__device__ __forceinline__ float bf2f(unsigned short u){
  return __uint_as_float(((unsigned int)u)<<16);
}

// ---------------- fused prep: x->bf16 + weight transposes + qkv concat ----------------
__global__ __launch_bounds__(256) void prep(const float* __restrict__ x, unsigned short* __restrict__ xb,
                     const float* __restrict__ W0, unsigned short* __restrict__ W0t,
                     const float* __restrict__ W1, unsigned short* __restrict__ W1t,
                     const float* __restrict__ W2, unsigned short* __restrict__ W2t,
                     const float* __restrict__ wq, const float* __restrict__ wk,
                     const float* __restrict__ wv, unsigned short* __restrict__ wqkvt,
                     const float* __restrict__ bq, const float* __restrict__ bk,
                     const float* __restrict__ bv, float* __restrict__ bqkv,
                     const float* __restrict__ wo, unsigned short* __restrict__ wot){
  int b = blockIdx.x, t = threadIdx.x;
  if(b < 2048){ int i = b*256 + t; xb[i] = f2bf(x[i]); return; }
  if(b == 4864){ bqkv[t] = bq[t]*QS; bqkv[256+t] = bk[t]; bqkv[512+t] = bv[t]; return; }
  const float* src; unsigned short* dst; int K,N,base,roff; float sc = 1.f;
  if(b<2304){src=W0;dst=W0t;K=128;N=512;base=2048;roff=0;}
  else if(b<3328){src=W1;dst=W1t;K=512;N=512;base=2304;roff=0;}
  else if(b<3840){src=W2;dst=W2t;K=512;N=256;base=3328;roff=0;}
  else if(b<4096){src=wq;dst=wqkvt;K=256;N=256;base=3840;roff=0;sc=QS;}
  else if(b<4352){src=wk;dst=wqkvt;K=256;N=256;base=4096;roff=256;}
  else if(b<4608){src=wv;dst=wqkvt;K=256;N=256;base=4352;roff=512;}
  else            {src=wo;dst=wot;K=256;N=256;base=4608;roff=0;}
  int idx = (b-base)*256 + t;
  int k = idx / N, n = idx - k*N;
  dst[(n+roff)*K + k] = f2bf(src[idx]*sc);
}

// --------- Wsd[16][K] bf16: rows 0..H-1 = W@a_s per head, 4..4+H-1 = W@a_d, rest 0 ---------
__global__ __launch_bounds__(256) void make_wsd(const float* __restrict__ W0, const float* __restrict__ as0, const float* __restrict__ ad0, unsigned short* __restrict__ S0,
                                                const float* __restrict__ W1, const float* __restrict__ as1, const float* __restrict__ ad1, unsigned short* __restrict__ S1,
                                                const float* __restrict__ W2, const float* __restrict__ as2, const float* __restrict__ ad2, unsigned short* __restrict__ S2){
  int b = blockIdx.x, t = threadIdx.x;
  const float *W,*as,*ad; unsigned short* S; int K,C,H,k;
  if(b<128){W=W0;as=as0;ad=ad0;S=S0;K=128;C=128;H=4;k=b;}
  else if(b<640){W=W1;as=as1;ad=ad1;S=S1;K=512;C=128;H=4;k=b-128;}
  else {W=W2;as=as2;ad=ad2;S=S2;K=512;C=256;H=1;k=b-640;}
  int D = H*C;
  __shared__ float s1[4], s2[4];
  int lane=t&63, wid=t>>6;
  for(int h=0;h<H;h++){
    float ps=0.f, pd=0.f;
    for(int c=t;c<C;c+=256){
      float wv = W[k*D + h*C + c];
      ps += wv*as[h*C+c];
      pd += wv*ad[h*C+c];
    }
    ps = waveReduceSum(ps); pd = waveReduceSum(pd);
    if(lane==0){ s1[wid]=ps; s2[wid]=pd; }
    __syncthreads();
    if(t==0){
      float u=s1[0]+s1[1]+s1[2]+s1[3], v=s2[0]+s2[1]+s2[2]+s2[3];
      S[h*K+k]=f2bf(u); S[(4+h)*K+k]=f2bf(v);
    }
    __syncthreads();
  }
  if(t==0){
    for(int h=H;h<4;h++){ S[h*K+k]=0; S[(4+h)*K+k]=0; }
    for(int r=8;r<16;r++) S[r*K+k]=0;
  }
}

// ---------------- MFMA bf16 GEMM, LDS-staged tiles (coalesced b128) ----------------
// A bf16 [M,K]; Bt bf16 [N,K]. 64x64 tile, BK=64. Fragments from LDS stride-72
// rows (2-way bank alias = free). Global tile loads issued BEFORE the barrier.
__global__ __launch_bounds__(256) void gemm_mfma(const unsigned short* __restrict__ A,
                                                 const unsigned short* __restrict__ Bt,
                                                 const float* __restrict__ bias,
                                                 float* __restrict__ C,
                                                 unsigned short* __restrict__ Cb,
                                                 const unsigned short* __restrict__ Wsd,
                                                 float* __restrict__ als,
                                                 float* __restrict__ ald,
                                                 int M, int K, int N){
  int t = threadIdx.x, lane = t & 63, w = t >> 6;
  int m = lane & 15, g = lane >> 4;
  int bm = blockIdx.y * 64, bn = blockIdx.x * 64;

  __shared__ unsigned short As[64*72];
  __shared__ unsigned short Bs[64*72];

  int sr = t >> 3;          // 0..31 staging row
  int sc = (t & 7) * 8;     // 0..56 staging col chunk
  const unsigned short* Ap = A  + (bm + sr)*K + sc;
  const unsigned short* Bp = Bt + (bn + sr)*K + sc;
  bool doC = (Wsd != nullptr) && (blockIdx.x == 0);

  float4v acc[4];
  #pragma unroll
  for(int nt=0;nt<4;nt++) acc[nt] = (float4v){0.f,0.f,0.f,0.f};
  float4v acc2 = (float4v){0.f,0.f,0.f,0.f};

  for(int k0=0;k0<K;k0+=64){
    // global tile loads first (latency overlaps previous compute + barrier)
    short8 a0 = *(const short8*)(Ap + k0);
    short8 a1 = *(const short8*)(Ap + 32*K + k0);
    short8 b0 = *(const short8*)(Bp + k0);
    short8 b1 = *(const short8*)(Bp + 32*K + k0);
    __syncthreads();   // previous iteration's fragment reads complete
    *(short8*)&As[sr*72 + sc]      = a0;
    *(short8*)&As[(sr+32)*72 + sc] = a1;
    *(short8*)&Bs[sr*72 + sc]      = b0;
    *(short8*)&Bs[(sr+32)*72 + sc] = b1;
    __syncthreads();

    #pragma unroll
    for(int ks=0;ks<2;ks++){
      short8 aA = *(const short8*)&As[(w*16 + m)*72 + ks*32 + g*8];
      #pragma unroll
      for(int nt=0;nt<4;nt++){
        short8 bB = *(const short8*)&Bs[(nt*16 + m)*72 + ks*32 + g*8];
        acc[nt] = __builtin_amdgcn_mfma_f32_16x16x32_bf16(aA, bB, acc[nt], 0,0,0);
      }
      if(doC){
        short8 bW = *(const short8*)(Wsd + m*K + k0 + ks*32 + g*8);
        acc2 = __builtin_amdgcn_mfma_f32_16x16x32_bf16(aA, bW, acc2, 0,0,0);
      }
    }
  }
  #pragma unroll
  for(int nt=0;nt<4;nt++){
    int col = bn + nt*16 + m;
    float bv = bias ? bias[col] : 0.f;
    #pragma unroll
    for(int r=0;r<4;r++){
      int row = bm + w*16 + g*4 + r;
      float v = acc[nt][r] + bv;
      if(C)  C[row*N + col]  = v;
      if(Cb) Cb[row*N + col] = f2bf(v);
    }
  }
  if(doC){
    #pragma unroll
    for(int r=0;r<4;r++){
      int row = bm + w*16 + g*4 + r;
      if(m<4)      als[row*4 + m]     = acc2[r];
      else if(m<8) ald[row*4 + (m-4)] = acc2[r];
    }
  }
}

// ---------------- CSR build ----------------
__global__ void csr_count(const int* __restrict__ ei, int E, int Etot,
                          int* __restrict__ hist){
  int e = blockIdx.x*256 + threadIdx.x;
  if(e>=Etot) return;
  int d = (e<E) ? (ei[E+e]&4095) : (e-E);
  atomicAdd(&hist[d], 1);
}

__global__ __launch_bounds__(1024) void csr_scan(const int* __restrict__ hist,
                                                 int* __restrict__ row_ptr,
                                                 int* __restrict__ wcnt, int N){
  __shared__ int sh[1024];
  int t = threadIdx.x;
  int base[4];
  int s = 0;
  #pragma unroll
  for(int i=0;i<4;i++){ base[i]=s; s += hist[t*4+i]; }
  sh[t] = s;
  __syncthreads();
  for(int off=1; off<1024; off<<=1){
    int x = (t>=off) ? sh[t-off] : 0;
    __syncthreads();
    sh[t] += x;
    __syncthreads();
  }
  int excl = (t==0) ? 0 : sh[t-1];
  #pragma unroll
  for(int i=0;i<4;i++){
    row_ptr[t*4+i] = excl + base[i];
    wcnt[t*4+i]    = excl + base[i];
  }
  if(t==1023) row_ptr[N] = excl + s;
}

__global__ void csr_scatter(const int* __restrict__ ei, int E, int Etot,
                            int* __restrict__ wcnt, int* __restrict__ col){
  int e = blockIdx.x*256 + threadIdx.x;
  if(e>=Etot) return;
  int s,d;
  if(e<E){ s=ei[e]&4095; d=ei[E+e]&4095; } else { s=d=e-E; }
  int pos = atomicAdd(&wcnt[d], 1);
  col[pos] = s;
}

// ------- fused GAT gather + softmax + bias + ELU + LayerNorm (+residual) -------
#define CE 128
__global__ void gat_gather_ln(const int* __restrict__ rp,
                              const int* __restrict__ col,
                              const unsigned short* __restrict__ xlb,
                              const float* __restrict__ als,
                              const float* __restrict__ ald,
                              const float* __restrict__ bias,
                              const float* __restrict__ gw,
                              const float* __restrict__ be,
                              const float* __restrict__ res,
                              float* __restrict__ out,
                              unsigned short* __restrict__ outb,
                              int D, int logC, int do_elu){
  int n = blockIdx.x, t = threadIdx.x;
  int c0 = t*2;
  int h = c0 >> logC;            // wave-uniform
  int rowW = D >> 1;
  float4 advv = *(const float4*)(ald + n*4);
  int start = rp[n], end = rp[n+1];
  const unsigned int* xw = (const unsigned int*)xlb;

  __shared__ float pw[CE*4];
  __shared__ int offs[CE];

  float acc0=0.f, acc1=0.f, den=0.f;

  for(int base=start; base<end; base+=CE){
    int cnt = min(CE, end-base);
    __syncthreads();
    if(t < cnt){
      int s = col[base+t];
      offs[t] = s*rowW;
      float4 av = *(const float4*)(als + s*4);
      #pragma unroll
      for(int hh=0;hh<4;hh++){
        float a = ((const float*)&av)[hh] + ((const float*)&advv)[hh];
        a = a>0.f ? a : 0.2f*a;
        pw[t*4+hh] = __expf(a);
      }
    }
    __syncthreads();
    #pragma unroll 4
    for(int j=0;j<cnt;j++){
      float p = pw[j*4+h];
      unsigned int u = xw[offs[j] + t];
      acc0 += p * bf2f((unsigned short)(u & 0xffffu));
      acc1 += p * bf2f((unsigned short)(u >> 16));
      den += p;
    }
  }

  float inv_d = 1.f/(den + 1e-16f);
  float v0 = acc0*inv_d + bias[c0];
  float v1 = acc1*inv_d + bias[c0+1];
  if(do_elu){
    v0 = v0>0.f ? v0 : expm1f(v0);
    v1 = v1>0.f ? v1 : expm1f(v1);
  }
  __shared__ float sh[4];
  int lane=t&63, wid=t>>6, nw = blockDim.x>>6;
  float sum = waveReduceSum(v0+v1);
  if(lane==0) sh[wid]=sum;
  __syncthreads();
  float mean = 0.f;
  for(int i=0;i<nw;i++) mean += sh[i];
  mean /= (float)D;
  __syncthreads();
  float d0 = v0-mean, d1 = v1-mean;
  float vs = waveReduceSum(d0*d0 + d1*d1);
  if(lane==0) sh[wid]=vs;
  __syncthreads();
  float var = 0.f;
  for(int i=0;i<nw;i++) var += sh[i];
  var /= (float)D;
  float inv = rsqrtf(var + 1e-5f);
  float y0 = d0*inv*gw[c0]   + be[c0];
  float y1 = d1*inv*gw[c0+1] + be[c0+1];
  if(res){ float2 rv = *(const float2*)(res + n*D + c0); y0 += rv.x; y1 += rv.y; }
  if(out) *(float2*)(out + n*D + c0) = make_float2(y0, y1);
  if(outb) ((unsigned int*)outb)[n*rowW + t] =
      (unsigned int)f2bf(y0) | ((unsigned int)f2bf(y1) << 16);
}

// --------- V transpose: QKV[:,512:768] bf16 [S,768] -> Vt bf16 [256,S] ---------
__global__ __launch_bounds__(256) void transpose_v(const unsigned short* __restrict__ QKV,
                                                   unsigned short* __restrict__ Vt, int S){
  __shared__ unsigned short tile[64][72];
  int bs = blockIdx.x*64;
  int bd = blockIdx.y*64;
  int t = threadIdx.x;
  int r8 = t>>3, c8 = (t&7)*8;
  #pragma unroll
  for(int it=0; it<2; it++){
    int row = r8 + it*32;
    short8 v = *(const short8*)(QKV + (bs+row)*768 + 512 + bd + c8);
    *(short8*)&tile[row][c8] = v;
  }
  __syncthreads();
  #pragma unroll
  for(int it=0; it<2; it++){
    int drow = r8 + it*32;
    short8 o;
    #pragma unroll
    for(int j=0;j<8;j++) o[j] = (short)tile[c8+j][drow];
    *(short8*)(Vt + (bd+drow)*S + bs + c8) = o;
  }
}

// --------- MFMA bf16 MHA, flash-decode: block=(64q, head, ksplit) ---------
#define KS 4
__global__ __launch_bounds__(256) void attention9(const unsigned short* __restrict__ QKV,
                                                  const unsigned short* __restrict__ Vt,
                                                  float* __restrict__ Op,
                                                  float* __restrict__ lp, int S){
  const int RS = 768;
  int qb = blockIdx.x * 64;
  int h  = blockIdx.y;
  int ks = blockIdx.z;
  int t  = threadIdx.x;
  int lane = t & 63, w = t >> 6;
  int m = lane & 15, g = lane >> 4;

  __shared__ unsigned short Ps[64*72];   // [q][key] bf16, stride 72
  __shared__ unsigned short Vs[32*72];   // [dim][key] bf16, stride 72

  short8 aQ = *(const short8*)(QKV + (qb + w*16 + m)*RS + h*32 + g*8);

  float4v o0 = {0.f,0.f,0.f,0.f}, o1 = {0.f,0.f,0.f,0.f};
  float l = 0.f;

  int r8 = t>>3, c8 = (t&7)*8;
  int kA = ks*(S/KS), kB = kA + S/KS;

  for(int kt=kA; kt<kB; kt+=64){
    short8 v = *(const short8*)(Vt + (h*32 + r8)*S + kt + c8);
    *(short8*)&Vs[r8*72 + c8] = v;
    __syncthreads();

    const unsigned short* Kp = QKV + (kt + m)*RS + 256 + h*32 + g*8;
    #pragma unroll
    for(int nt=0;nt<4;nt++){
      short8 aK = *(const short8*)(Kp + nt*16*RS);
      float4v acc = {0.f,0.f,0.f,0.f};
      acc = __builtin_amdgcn_mfma_f32_16x16x32_bf16(aK, aQ, acc, 0,0,0);
      float p0 = __expf(acc[0]);
      float p1 = __expf(acc[1]);
      float p2 = __expf(acc[2]);
      float p3 = __expf(acc[3]);
      l += (p0+p1) + (p2+p3);
      unsigned int r0 = __float_as_uint(p0) + 0x8000u;
      unsigned int r1 = __float_as_uint(p1) + 0x8000u;
      unsigned int r2 = __float_as_uint(p2) + 0x8000u;
      unsigned int r3 = __float_as_uint(p3) + 0x8000u;
      uint2 pk;
      pk.x = __builtin_amdgcn_perm(r1, r0, 0x07060302u);
      pk.y = __builtin_amdgcn_perm(r3, r2, 0x07060302u);
      *(uint2*)&Ps[(w*16 + m)*72 + nt*16 + g*4] = pk;
    }

    #pragma unroll
    for(int kh=0;kh<2;kh++){
      short8 aP  = *(const short8*)&Ps[(w*16 + m)*72 + kh*32 + g*8];
      short8 bV0 = *(const short8*)&Vs[(m)*72    + kh*32 + g*8];
      short8 bV1 = *(const short8*)&Vs[(16+m)*72 + kh*32 + g*8];
      o0 = __builtin_amdgcn_mfma_f32_16x16x32_bf16(aP, bV0, o0, 0,0,0);
      o1 = __builtin_amdgcn_mfma_f32_16x16x32_bf16(aP, bV1, o1, 0,0,0);
    }
    __syncthreads();
  }

  l += __shfl_xor(l, 16, 64);
  l += __shfl_xor(l, 32, 64);

  float* Ob = Op + (size_t)ks*S*256;
  #pragma unroll
  for(int r=0;r<4;r++){
    int q = qb + w*16 + g*4 + r;
    Ob[q*256 + h*32 + m]      = o0[r];
    Ob[q*256 + h*32 + 16 + m] = o1[r];
  }
  if(g==0) lp[ks*S*8 + (qb + w*16 + m)*8 + h] = l;
}

__global__ __launch_bounds__(256) void combine(const float* __restrict__ Op,
                                               const float* __restrict__ lp,
                                               unsigned short* __restrict__ aob, int S){
  int q = blockIdx.x, t = threadIdx.x;
  int h = t >> 5;
  float o = 0.f, l = 0.f;
  #pragma unroll
  for(int s=0;s<KS;s++) o += Op[(size_t)s*S*256 + q*256 + t];
  #pragma unroll
  for(int s=0;s<KS;s++) l += lp[s*S*8 + q*8 + h];
  aob[q*256 + t] = f2bf(o / l);
}

extern "C" void kernel_launch(void* const* d_in, const int* in_sizes, int n_in,
                              void* d_out, int out_size, void* d_ws, size_t ws_size,
                              hipStream_t stream) {
  const float* x   = (const float*)d_in[0];
  const int*   ei  = (const int*)d_in[1];
  const float* W0  = (const float*)d_in[2];
  const float* as0 = (const float*)d_in[3];
  const float* ad0 = (const float*)d_in[4];
  const float* b0  = (const float*)d_in[5];
  const float* W1  = (const float*)d_in[6];
  const float* as1 = (const float*)d_in[7];
  const float* ad1 = (const float*)d_in[8];
  const float* b1  = (const float*)d_in[9];
  const float* W2  = (const float*)d_in[10];
  const float* as2 = (const float*)d_in[11];
  const float* ad2 = (const float*)d_in[12];
  const float* b2  = (const float*)d_in[13];
  const float* g0  = (const float*)d_in[14];
  const float* be0 = (const float*)d_in[15];
  const float* g1  = (const float*)d_in[16];
  const float* be1 = (const float*)d_in[17];
  const float* g2  = (const float*)d_in[18];
  const float* be2 = (const float*)d_in[19];
  const float* wq  = (const float*)d_in[20];
  const float* bq  = (const float*)d_in[21];
  const float* wk  = (const float*)d_in[22];
  const float* bk  = (const float*)d_in[23];
  const float* wv  = (const float*)d_in[24];
  const float* bv  = (const float*)d_in[25];
  const float* wo  = (const float*)d_in[26];
  const float* bo  = (const float*)d_in[27];
  float* out = (float*)d_out;

  const int N = 4096;
  const int E = in_sizes[1] / 2;
  const int Etot = E + N;

  char* p = (char*)d_ws;
  auto alloc = [&](size_t bytes){ char* r = p; p += (bytes + 255) & ~(size_t)255; return r; };

  float* h0   = (float*)alloc(N*512*4);
  float* als  = (float*)alloc(N*4*4);
  float* ald  = (float*)alloc(N*4*4);
  unsigned short* xb   = (unsigned short*)alloc(N*128*2);
  unsigned short* xlb  = (unsigned short*)alloc(N*512*2);
  unsigned short* h0b  = (unsigned short*)alloc(N*512*2);
  unsigned short* h1b  = (unsigned short*)alloc(N*512*2);
  unsigned short* h2b  = (unsigned short*)alloc(N*256*2);
  unsigned short* QKVb = (unsigned short*)alloc((size_t)N*768*2);
  unsigned short* Vt   = (unsigned short*)alloc(256*N*2);
  unsigned short* aob  = (unsigned short*)alloc(N*256*2);
  unsigned short* W0t  = (unsigned short*)alloc(512*128*2);
  unsigned short* W1t  = (unsigned short*)alloc(512*512*2);
  unsigned short* W2t  = (unsigned short*)alloc(256*512*2);
  unsigned short* wqkvt= (unsigned short*)alloc(768*256*2);
  float* bqkv = (float*)alloc(768*4);
  unsigned short* wot  = (unsigned short*)alloc(256*256*2);
  unsigned short* Wsd0 = (unsigned short*)alloc(16*128*2);
  unsigned short* Wsd1 = (unsigned short*)alloc(16*512*2);
  unsigned short* Wsd2 = (unsigned short*)alloc(16*512*2);
  float* Op = (float*)alloc((size_t)KS*N*256*4);
  float* lp = (float*)alloc((size_t)KS*N*8*4);
  int* hist = (int*)alloc(N*4);
  int* wcnt = (int*)alloc(N*4);
  int* rp   = (int*)alloc((N+2)*4);
  int* col  = (int*)alloc(Etot*4);

  // ---------- prep ----------
  prep<<<4865, 256, 0, stream>>>(x, xb, W0, W0t, W1, W1t, W2, W2t,
                                 wq, wk, wv, wqkvt, bq, bk, bv, bqkv, wo, wot);
  make_wsd<<<1152, 256, 0, stream>>>(W0, as0, ad0, Wsd0, W1, as1, ad1, Wsd1, W2, as2, ad2, Wsd2);

  // ---------- CSR build (by destination) ----------
  hipMemsetAsync(hist, 0, N*sizeof(int), stream);
  csr_count<<<(Etot+255)/256, 256, 0, stream>>>(ei, E, Etot, hist);
  csr_scan<<<1, 1024, 0, stream>>>(hist, rp, wcnt, N);
  csr_scatter<<<(Etot+255)/256, 256, 0, stream>>>(ei, E, Etot, wcnt, col);

  // ---------- GAT layer 0: 128 -> 4x128 (512) ----------
  gemm_mfma<<<dim3(8, 64), 256, 0, stream>>>(xb, W0t, nullptr, nullptr, xlb, Wsd0, als, ald, N, 128, 512);
  gat_gather_ln<<<N, 256, 0, stream>>>(rp, col, xlb, als, ald, b0, g0, be0,
                                       nullptr, h0, h0b, 512, 7, 1);

  // ---------- GAT layer 1: 512 -> 4x128 (512), residual ----------
  gemm_mfma<<<dim3(8, 64), 256, 0, stream>>>(h0b, W1t, nullptr, nullptr, xlb, Wsd1, als, ald, N, 512, 512);
  gat_gather_ln<<<N, 256, 0, stream>>>(rp, col, xlb, als, ald, b1, g1, be1,
                                       h0, nullptr, h1b, 512, 7, 1);

  // ---------- GAT layer 2: 512 -> 1x256, 1 head, no ELU ----------
  gemm_mfma<<<dim3(4, 64), 256, 0, stream>>>(h1b, W2t, nullptr, nullptr, xlb, Wsd2, als, ald, N, 512, 256);
  gat_gather_ln<<<N, 128, 0, stream>>>(rp, col, xlb, als, ald, b2, g2, be2,
                                       nullptr, nullptr, h2b, 256, 8, 0);

  // ---------- dense MHA (bf16 MFMA, flash-decode, fused QKV) ----------
  gemm_mfma<<<dim3(12, 64), 256, 0, stream>>>(h2b, wqkvt, bqkv, nullptr, QKVb, nullptr, nullptr, nullptr, N, 256, 768);
  transpose_v<<<dim3(N/64, 4), 256, 0, stream>>>(QKVb, Vt, N);
  attention9<<<dim3(N/64, 8, KS), 256, 0, stream>>>(QKVb, Vt, Op, lp, N);
  combine<<<N, 256, 0, stream>>>(Op, lp, aob, N);
  gemm_mfma<<<dim3(4, 64), 256, 0, stream>>>(aob, wot, bo, out, nullptr, nullptr, nullptr, nullptr, N, 256, 256);
}

// Round 13
// 286.649 us; speedup vs baseline: 1.2681x; 1.1080x over previous
//
#include <hip/hip_runtime.h>
#include <math.h>

typedef __attribute__((ext_vector_type(8))) short short8;
typedef __attribute__((ext_vector_type(4))) float float4v;

#define QS 0.17677669529663687f   // 1/sqrt(32), folded into wq/bq; exp via __expf

__device__ __forceinline__ float waveReduceSum(float v){
  #pragma unroll
  for(int o=32;o>0;o>>=1) v += __shfl_down(v,o,64);
  return v;
}

__device__ __forceinline__ unsigned short f2bf(float f){
  unsigned int u = __float_as_uint(f);
  return (unsigned short)((u + 0x7FFFu + ((u>>16)&1u)) >> 16);
}
__device__ __forceinline__ float bf2f(unsigned short u){
  return __uint_as_float(((unsigned int)u)<<16);
}

// ------- fused prep: x->bf16 + weight transposes + qkv concat + Wsd build -------
// blocks: [0,2048) x conv; [2048,4864) transposes; 4864 bqkv; [4865,6017) Wsd.
__global__ __launch_bounds__(256) void prep(const float* __restrict__ x, unsigned short* __restrict__ xb,
                     const float* __restrict__ W0, unsigned short* __restrict__ W0t,
                     const float* __restrict__ W1, unsigned short* __restrict__ W1t,
                     const float* __restrict__ W2, unsigned short* __restrict__ W2t,
                     const float* __restrict__ wq, const float* __restrict__ wk,
                     const float* __restrict__ wv, unsigned short* __restrict__ wqkvt,
                     const float* __restrict__ bq, const float* __restrict__ bk,
                     const float* __restrict__ bv, float* __restrict__ bqkv,
                     const float* __restrict__ wo, unsigned short* __restrict__ wot,
                     const float* __restrict__ as0, const float* __restrict__ ad0, unsigned short* __restrict__ S0,
                     const float* __restrict__ as1, const float* __restrict__ ad1, unsigned short* __restrict__ S1,
                     const float* __restrict__ as2, const float* __restrict__ ad2, unsigned short* __restrict__ S2){
  int b = blockIdx.x, t = threadIdx.x;
  if(b < 2048){ int i = b*256 + t; xb[i] = f2bf(x[i]); return; }
  if(b == 4864){ bqkv[t] = bq[t]*QS; bqkv[256+t] = bk[t]; bqkv[512+t] = bv[t]; return; }
  if(b >= 4865){
    // ---- Wsd build: rows 0..H-1 = W@a_s per head, 4..4+H-1 = W@a_d, rest 0 ----
    int bb = b - 4865;
    const float *W,*as,*ad; unsigned short* S; int K,C,H,k;
    if(bb<128){W=W0;as=as0;ad=ad0;S=S0;K=128;C=128;H=4;k=bb;}
    else if(bb<640){W=W1;as=as1;ad=ad1;S=S1;K=512;C=128;H=4;k=bb-128;}
    else {W=W2;as=as2;ad=ad2;S=S2;K=512;C=256;H=1;k=bb-640;}
    int D = H*C;
    __shared__ float s1[4], s2[4];
    int lane=t&63, wid=t>>6;
    for(int h=0;h<H;h++){
      float ps=0.f, pd=0.f;
      for(int c=t;c<C;c+=256){
        float wv2 = W[k*D + h*C + c];
        ps += wv2*as[h*C+c];
        pd += wv2*ad[h*C+c];
      }
      ps = waveReduceSum(ps); pd = waveReduceSum(pd);
      if(lane==0){ s1[wid]=ps; s2[wid]=pd; }
      __syncthreads();
      if(t==0){
        float u=s1[0]+s1[1]+s1[2]+s1[3], v=s2[0]+s2[1]+s2[2]+s2[3];
        S[h*K+k]=f2bf(u); S[(4+h)*K+k]=f2bf(v);
      }
      __syncthreads();
    }
    if(t==0){
      for(int h=H;h<4;h++){ S[h*K+k]=0; S[(4+h)*K+k]=0; }
      for(int r=8;r<16;r++) S[r*K+k]=0;
    }
    return;
  }
  const float* src; unsigned short* dst; int K,N,base,roff; float sc = 1.f;
  if(b<2304){src=W0;dst=W0t;K=128;N=512;base=2048;roff=0;}
  else if(b<3328){src=W1;dst=W1t;K=512;N=512;base=2304;roff=0;}
  else if(b<3840){src=W2;dst=W2t;K=512;N=256;base=3328;roff=0;}
  else if(b<4096){src=wq;dst=wqkvt;K=256;N=256;base=3840;roff=0;sc=QS;}
  else if(b<4352){src=wk;dst=wqkvt;K=256;N=256;base=4096;roff=256;}
  else if(b<4608){src=wv;dst=wqkvt;K=256;N=256;base=4352;roff=512;}
  else            {src=wo;dst=wot;K=256;N=256;base=4608;roff=0;}
  int idx = (b-base)*256 + t;
  int k = idx / N, n = idx - k*N;
  dst[(n+roff)*K + k] = f2bf(src[idx]*sc);
}

// ---------------- MFMA bf16 GEMM, LDS-staged tiles (coalesced b128) ----------------
__global__ __launch_bounds__(256) void gemm_mfma(const unsigned short* __restrict__ A,
                                                 const unsigned short* __restrict__ Bt,
                                                 const float* __restrict__ bias,
                                                 float* __restrict__ C,
                                                 unsigned short* __restrict__ Cb,
                                                 const unsigned short* __restrict__ Wsd,
                                                 float* __restrict__ als,
                                                 float* __restrict__ ald,
                                                 int M, int K, int N){
  int t = threadIdx.x, lane = t & 63, w = t >> 6;
  int m = lane & 15, g = lane >> 4;
  int bm = blockIdx.y * 64, bn = blockIdx.x * 64;

  __shared__ unsigned short As[64*72];
  __shared__ unsigned short Bs[64*72];

  int sr = t >> 3;          // 0..31 staging row
  int sc = (t & 7) * 8;     // 0..56 staging col chunk
  const unsigned short* Ap = A  + (bm + sr)*K + sc;
  const unsigned short* Bp = Bt + (bn + sr)*K + sc;
  bool doC = (Wsd != nullptr) && (blockIdx.x == 0);

  float4v acc[4];
  #pragma unroll
  for(int nt=0;nt<4;nt++) acc[nt] = (float4v){0.f,0.f,0.f,0.f};
  float4v acc2 = (float4v){0.f,0.f,0.f,0.f};

  for(int k0=0;k0<K;k0+=64){
    short8 a0 = *(const short8*)(Ap + k0);
    short8 a1 = *(const short8*)(Ap + 32*K + k0);
    short8 b0 = *(const short8*)(Bp + k0);
    short8 b1 = *(const short8*)(Bp + 32*K + k0);
    __syncthreads();
    *(short8*)&As[sr*72 + sc]      = a0;
    *(short8*)&As[(sr+32)*72 + sc] = a1;
    *(short8*)&Bs[sr*72 + sc]      = b0;
    *(short8*)&Bs[(sr+32)*72 + sc] = b1;
    __syncthreads();

    #pragma unroll
    for(int ks=0;ks<2;ks++){
      short8 aA = *(const short8*)&As[(w*16 + m)*72 + ks*32 + g*8];
      #pragma unroll
      for(int nt=0;nt<4;nt++){
        short8 bB = *(const short8*)&Bs[(nt*16 + m)*72 + ks*32 + g*8];
        acc[nt] = __builtin_amdgcn_mfma_f32_16x16x32_bf16(aA, bB, acc[nt], 0,0,0);
      }
      if(doC){
        short8 bW = *(const short8*)(Wsd + m*K + k0 + ks*32 + g*8);
        acc2 = __builtin_amdgcn_mfma_f32_16x16x32_bf16(aA, bW, acc2, 0,0,0);
      }
    }
  }
  #pragma unroll
  for(int nt=0;nt<4;nt++){
    int col = bn + nt*16 + m;
    float bv = bias ? bias[col] : 0.f;
    #pragma unroll
    for(int r=0;r<4;r++){
      int row = bm + w*16 + g*4 + r;
      float v = acc[nt][r] + bv;
      if(C)  C[row*N + col]  = v;
      if(Cb) Cb[row*N + col] = f2bf(v);
    }
  }
  if(doC){
    #pragma unroll
    for(int r=0;r<4;r++){
      int row = bm + w*16 + g*4 + r;
      if(m<4)      als[row*4 + m]     = acc2[r];
      else if(m<8) ald[row*4 + (m-4)] = acc2[r];
    }
  }
}

// ---------------- CSR build ----------------
__global__ void csr_count(const int* __restrict__ ei, int E, int Etot,
                          int* __restrict__ hist){
  int e = blockIdx.x*256 + threadIdx.x;
  if(e>=Etot) return;
  int d = (e<E) ? (ei[E+e]&4095) : (e-E);
  atomicAdd(&hist[d], 1);
}

__global__ __launch_bounds__(1024) void csr_scan(const int* __restrict__ hist,
                                                 int* __restrict__ row_ptr,
                                                 int* __restrict__ wcnt, int N){
  __shared__ int sh[1024];
  int t = threadIdx.x;
  int base[4];
  int s = 0;
  #pragma unroll
  for(int i=0;i<4;i++){ base[i]=s; s += hist[t*4+i]; }
  sh[t] = s;
  __syncthreads();
  for(int off=1; off<1024; off<<=1){
    int x = (t>=off) ? sh[t-off] : 0;
    __syncthreads();
    sh[t] += x;
    __syncthreads();
  }
  int excl = (t==0) ? 0 : sh[t-1];
  #pragma unroll
  for(int i=0;i<4;i++){
    row_ptr[t*4+i] = excl + base[i];
    wcnt[t*4+i]    = excl + base[i];
  }
  if(t==1023) row_ptr[N] = excl + s;
}

__global__ void csr_scatter(const int* __restrict__ ei, int E, int Etot,
                            int* __restrict__ wcnt, int* __restrict__ col){
  int e = blockIdx.x*256 + threadIdx.x;
  if(e>=Etot) return;
  int s,d;
  if(e<E){ s=ei[e]&4095; d=ei[E+e]&4095; } else { s=d=e-E; }
  int pos = atomicAdd(&wcnt[d], 1);
  col[pos] = s;
}

// ------- fused GAT gather + softmax + bias + ELU + LayerNorm (+residual) -------
#define CE 128
__global__ void gat_gather_ln(const int* __restrict__ rp,
                              const int* __restrict__ col,
                              const unsigned short* __restrict__ xlb,
                              const float* __restrict__ als,
                              const float* __restrict__ ald,
                              const float* __restrict__ bias,
                              const float* __restrict__ gw,
                              const float* __restrict__ be,
                              const float* __restrict__ res,
                              float* __restrict__ out,
                              unsigned short* __restrict__ outb,
                              int D, int logC, int do_elu){
  int n = blockIdx.x, t = threadIdx.x;
  int c0 = t*2;
  int h = c0 >> logC;            // wave-uniform
  int rowW = D >> 1;
  float4 advv = *(const float4*)(ald + n*4);
  int start = rp[n], end = rp[n+1];
  const unsigned int* xw = (const unsigned int*)xlb;

  __shared__ float pw[CE*4];
  __shared__ int offs[CE];

  float acc0=0.f, acc1=0.f, den=0.f;

  for(int base=start; base<end; base+=CE){
    int cnt = min(CE, end-base);
    __syncthreads();
    if(t < cnt){
      int s = col[base+t];
      offs[t] = s*rowW;
      float4 av = *(const float4*)(als + s*4);
      #pragma unroll
      for(int hh=0;hh<4;hh++){
        float a = ((const float*)&av)[hh] + ((const float*)&advv)[hh];
        a = a>0.f ? a : 0.2f*a;
        pw[t*4+hh] = __expf(a);
      }
    }
    __syncthreads();
    #pragma unroll 4
    for(int j=0;j<cnt;j++){
      float p = pw[j*4+h];
      unsigned int u = xw[offs[j] + t];
      acc0 += p * bf2f((unsigned short)(u & 0xffffu));
      acc1 += p * bf2f((unsigned short)(u >> 16));
      den += p;
    }
  }

  float inv_d = 1.f/(den + 1e-16f);
  float v0 = acc0*inv_d + bias[c0];
  float v1 = acc1*inv_d + bias[c0+1];
  if(do_elu){
    v0 = v0>0.f ? v0 : expm1f(v0);
    v1 = v1>0.f ? v1 : expm1f(v1);
  }
  __shared__ float sh[4];
  int lane=t&63, wid=t>>6, nw = blockDim.x>>6;
  float sum = waveReduceSum(v0+v1);
  if(lane==0) sh[wid]=sum;
  __syncthreads();
  float mean = 0.f;
  for(int i=0;i<nw;i++) mean += sh[i];
  mean /= (float)D;
  __syncthreads();
  float d0 = v0-mean, d1 = v1-mean;
  float vs = waveReduceSum(d0*d0 + d1*d1);
  if(lane==0) sh[wid]=vs;
  __syncthreads();
  float var = 0.f;
  for(int i=0;i<nw;i++) var += sh[i];
  var /= (float)D;
  float inv = rsqrtf(var + 1e-5f);
  float y0 = d0*inv*gw[c0]   + be[c0];
  float y1 = d1*inv*gw[c0+1] + be[c0+1];
  if(res){ float2 rv = *(const float2*)(res + n*D + c0); y0 += rv.x; y1 += rv.y; }
  if(out) *(float2*)(out + n*D + c0) = make_float2(y0, y1);
  if(outb) ((unsigned int*)outb)[n*rowW + t] =
      (unsigned int)f2bf(y0) | ((unsigned int)f2bf(y1) << 16);
}

// --------- V transpose: QKV[:,512:768] bf16 [S,768] -> Vt bf16 [256,S] ---------
__global__ __launch_bounds__(256) void transpose_v(const unsigned short* __restrict__ QKV,
                                                   unsigned short* __restrict__ Vt, int S){
  __shared__ unsigned short tile[64][72];
  int bs = blockIdx.x*64;
  int bd = blockIdx.y*64;
  int t = threadIdx.x;
  int r8 = t>>3, c8 = (t&7)*8;
  #pragma unroll
  for(int it=0; it<2; it++){
    int row = r8 + it*32;
    short8 v = *(const short8*)(QKV + (bs+row)*768 + 512 + bd + c8);
    *(short8*)&tile[row][c8] = v;
  }
  __syncthreads();
  #pragma unroll
  for(int it=0; it<2; it++){
    int drow = r8 + it*32;
    short8 o;
    #pragma unroll
    for(int j=0;j<8;j++) o[j] = (short)tile[c8+j][drow];
    *(short8*)(Vt + (bd+drow)*S + bs + c8) = o;
  }
}

// --------- MFMA bf16 MHA, flash-decode: block=(64q, head, ksplit) ---------
// K now staged through LDS with coalesced 64B-per-row loads (same fix that won
// R12's GEMM): kills the 16-lane x 1536B-stride scattered L2 requests.
#define KS 4
__global__ __launch_bounds__(256) void attention10(const unsigned short* __restrict__ QKV,
                                                   const unsigned short* __restrict__ Vt,
                                                   float* __restrict__ Op,
                                                   float* __restrict__ lp, int S){
  const int RS = 768;
  int qb = blockIdx.x * 64;
  int h  = blockIdx.y;
  int ks = blockIdx.z;
  int t  = threadIdx.x;
  int lane = t & 63, w = t >> 6;
  int m = lane & 15, g = lane >> 4;

  __shared__ unsigned short Ps[64*72];   // [q][key] bf16, stride 72
  __shared__ unsigned short Vs[32*72];   // [dim][key] bf16, stride 72
  __shared__ unsigned short Ks[64*36];   // [key][dim] bf16, stride 36

  short8 aQ = *(const short8*)(QKV + (qb + w*16 + m)*RS + h*32 + g*8);

  float4v o0 = {0.f,0.f,0.f,0.f}, o1 = {0.f,0.f,0.f,0.f};
  float l = 0.f;

  int r8 = t>>3, c8 = (t&7)*8;    // V staging: dim row 0..31, key chunk
  int kr = t>>2, kc = (t&3)*8;    // K staging: key row 0..63, dim chunk
  int kA = ks*(S/KS), kB = kA + S/KS;

  for(int kt=kA; kt<kB; kt+=64){
    // global loads first (latency overlaps previous tile's compute)
    short8 v = *(const short8*)(Vt + (h*32 + r8)*S + kt + c8);
    short8 kv = *(const short8*)(QKV + (kt + kr)*RS + 256 + h*32 + kc);
    __syncthreads();   // previous tile's LDS reads complete
    *(short8*)&Vs[r8*72 + c8] = v;
    *(short8*)&Ks[kr*36 + kc] = kv;
    __syncthreads();

    // S^T strip: mfma(A=K-frag from LDS, B=Q-frag) -> lane owns 4 consecutive keys of query m
    #pragma unroll
    for(int nt=0;nt<4;nt++){
      short8 aK = *(const short8*)&Ks[(nt*16 + m)*36 + g*8];
      float4v acc = {0.f,0.f,0.f,0.f};
      acc = __builtin_amdgcn_mfma_f32_16x16x32_bf16(aK, aQ, acc, 0,0,0);
      float p0 = __expf(acc[0]);
      float p1 = __expf(acc[1]);
      float p2 = __expf(acc[2]);
      float p3 = __expf(acc[3]);
      l += (p0+p1) + (p2+p3);
      unsigned int r0 = __float_as_uint(p0) + 0x8000u;
      unsigned int r1 = __float_as_uint(p1) + 0x8000u;
      unsigned int r2 = __float_as_uint(p2) + 0x8000u;
      unsigned int r3 = __float_as_uint(p3) + 0x8000u;
      uint2 pk;
      pk.x = __builtin_amdgcn_perm(r1, r0, 0x07060302u);
      pk.y = __builtin_amdgcn_perm(r3, r2, 0x07060302u);
      *(uint2*)&Ps[(w*16 + m)*72 + nt*16 + g*4] = pk;
    }

    // O strip += P @ V (aP rows wave-private; same-wave LDS order suffices)
    #pragma unroll
    for(int kh=0;kh<2;kh++){
      short8 aP  = *(const short8*)&Ps[(w*16 + m)*72 + kh*32 + g*8];
      short8 bV0 = *(const short8*)&Vs[(m)*72    + kh*32 + g*8];
      short8 bV1 = *(const short8*)&Vs[(16+m)*72 + kh*32 + g*8];
      o0 = __builtin_amdgcn_mfma_f32_16x16x32_bf16(aP, bV0, o0, 0,0,0);
      o1 = __builtin_amdgcn_mfma_f32_16x16x32_bf16(aP, bV1, o1, 0,0,0);
    }
  }

  l += __shfl_xor(l, 16, 64);
  l += __shfl_xor(l, 32, 64);

  float* Ob = Op + (size_t)ks*S*256;
  #pragma unroll
  for(int r=0;r<4;r++){
    int q = qb + w*16 + g*4 + r;
    Ob[q*256 + h*32 + m]      = o0[r];
    Ob[q*256 + h*32 + 16 + m] = o1[r];
  }
  if(g==0) lp[ks*S*8 + (qb + w*16 + m)*8 + h] = l;
}

__global__ __launch_bounds__(256) void combine(const float* __restrict__ Op,
                                               const float* __restrict__ lp,
                                               unsigned short* __restrict__ aob, int S){
  int q = blockIdx.x, t = threadIdx.x;
  int h = t >> 5;
  float o = 0.f, l = 0.f;
  #pragma unroll
  for(int s=0;s<KS;s++) o += Op[(size_t)s*S*256 + q*256 + t];
  #pragma unroll
  for(int s=0;s<KS;s++) l += lp[s*S*8 + q*8 + h];
  aob[q*256 + t] = f2bf(o / l);
}

extern "C" void kernel_launch(void* const* d_in, const int* in_sizes, int n_in,
                              void* d_out, int out_size, void* d_ws, size_t ws_size,
                              hipStream_t stream) {
  const float* x   = (const float*)d_in[0];
  const int*   ei  = (const int*)d_in[1];
  const float* W0  = (const float*)d_in[2];
  const float* as0 = (const float*)d_in[3];
  const float* ad0 = (const float*)d_in[4];
  const float* b0  = (const float*)d_in[5];
  const float* W1  = (const float*)d_in[6];
  const float* as1 = (const float*)d_in[7];
  const float* ad1 = (const float*)d_in[8];
  const float* b1  = (const float*)d_in[9];
  const float* W2  = (const float*)d_in[10];
  const float* as2 = (const float*)d_in[11];
  const float* ad2 = (const float*)d_in[12];
  const float* b2  = (const float*)d_in[13];
  const float* g0  = (const float*)d_in[14];
  const float* be0 = (const float*)d_in[15];
  const float* g1  = (const float*)d_in[16];
  const float* be1 = (const float*)d_in[17];
  const float* g2  = (const float*)d_in[18];
  const float* be2 = (const float*)d_in[19];
  const float* wq  = (const float*)d_in[20];
  const float* bq  = (const float*)d_in[21];
  const float* wk  = (const float*)d_in[22];
  const float* bk  = (const float*)d_in[23];
  const float* wv  = (const float*)d_in[24];
  const float* bv  = (const float*)d_in[25];
  const float* wo  = (const float*)d_in[26];
  const float* bo  = (const float*)d_in[27];
  float* out = (float*)d_out;

  const int N = 4096;
  const int E = in_sizes[1] / 2;
  const int Etot = E + N;

  char* p = (char*)d_ws;
  auto alloc = [&](size_t bytes){ char* r = p; p += (bytes + 255) & ~(size_t)255; return r; };

  float* h0   = (float*)alloc(N*512*4);
  float* als  = (float*)alloc(N*4*4);
  float* ald  = (float*)alloc(N*4*4);
  unsigned short* xb   = (unsigned short*)alloc(N*128*2);
  unsigned short* xlb  = (unsigned short*)alloc(N*512*2);
  unsigned short* h0b  = (unsigned short*)alloc(N*512*2);
  unsigned short* h1b  = (unsigned short*)alloc(N*512*2);
  unsigned short* h2b  = (unsigned short*)alloc(N*256*2);
  unsigned short* QKVb = (unsigned short*)alloc((size_t)N*768*2);
  unsigned short* Vt   = (unsigned short*)alloc(256*N*2);
  unsigned short* aob  = (unsigned short*)alloc(N*256*2);
  unsigned short* W0t  = (unsigned short*)alloc(512*128*2);
  unsigned short* W1t  = (unsigned short*)alloc(512*512*2);
  unsigned short* W2t  = (unsigned short*)alloc(256*512*2);
  unsigned short* wqkvt= (unsigned short*)alloc(768*256*2);
  float* bqkv = (float*)alloc(768*4);
  unsigned short* wot  = (unsigned short*)alloc(256*256*2);
  unsigned short* Wsd0 = (unsigned short*)alloc(16*128*2);
  unsigned short* Wsd1 = (unsigned short*)alloc(16*512*2);
  unsigned short* Wsd2 = (unsigned short*)alloc(16*512*2);
  float* Op = (float*)alloc((size_t)KS*N*256*4);
  float* lp = (float*)alloc((size_t)KS*N*8*4);
  int* hist = (int*)alloc(N*4);
  int* wcnt = (int*)alloc(N*4);
  int* rp   = (int*)alloc((N+2)*4);
  int* col  = (int*)alloc(Etot*4);

  // ---------- prep (x conv + transposes + bqkv + Wsd) ----------
  prep<<<6017, 256, 0, stream>>>(x, xb, W0, W0t, W1, W1t, W2, W2t,
                                 wq, wk, wv, wqkvt, bq, bk, bv, bqkv, wo, wot,
                                 as0, ad0, Wsd0, as1, ad1, Wsd1, as2, ad2, Wsd2);

  // ---------- CSR build (by destination) ----------
  hipMemsetAsync(hist, 0, N*sizeof(int), stream);
  csr_count<<<(Etot+255)/256, 256, 0, stream>>>(ei, E, Etot, hist);
  csr_scan<<<1, 1024, 0, stream>>>(hist, rp, wcnt, N);
  csr_scatter<<<(Etot+255)/256, 256, 0, stream>>>(ei, E, Etot, wcnt, col);

  // ---------- GAT layer 0: 128 -> 4x128 (512) ----------
  gemm_mfma<<<dim3(8, 64), 256, 0, stream>>>(xb, W0t, nullptr, nullptr, xlb, Wsd0, als, ald, N, 128, 512);
  gat_gather_ln<<<N, 256, 0, stream>>>(rp, col, xlb, als, ald, b0, g0, be0,
                                       nullptr, h0, h0b, 512, 7, 1);

  // ---------- GAT layer 1: 512 -> 4x128 (512), residual ----------
  gemm_mfma<<<dim3(8, 64), 256, 0, stream>>>(h0b, W1t, nullptr, nullptr, xlb, Wsd1, als, ald, N, 512, 512);
  gat_gather_ln<<<N, 256, 0, stream>>>(rp, col, xlb, als, ald, b1, g1, be1,
                                       h0, nullptr, h1b, 512, 7, 1);

  // ---------- GAT layer 2: 512 -> 1x256, 1 head, no ELU ----------
  gemm_mfma<<<dim3(4, 64), 256, 0, stream>>>(h1b, W2t, nullptr, nullptr, xlb, Wsd2, als, ald, N, 512, 256);
  gat_gather_ln<<<N, 128, 0, stream>>>(rp, col, xlb, als, ald, b2, g2, be2,
                                       nullptr, nullptr, h2b, 256, 8, 0);

  // ---------- dense MHA (bf16 MFMA, flash-decode, fused QKV) ----------
  gemm_mfma<<<dim3(12, 64), 256, 0, stream>>>(h2b, wqkvt, bqkv, nullptr, QKVb, nullptr, nullptr, nullptr, N, 256, 768);
  transpose_v<<<dim3(N/64, 4), 256, 0, stream>>>(QKVb, Vt, N);
  attention10<<<dim3(N/64, 8, KS), 256, 0, stream>>>(QKVb, Vt, Op, lp, N);
  combine<<<N, 256, 0, stream>>>(Op, lp, aob, N);
  gemm_mfma<<<dim3(4, 64), 256, 0, stream>>>(aob, wot, bo, out, nullptr, nullptr, nullptr, nullptr, N, 256, 256);
}

// Round 14
// 284.385 us; speedup vs baseline: 1.2782x; 1.0080x over previous
//
#include <hip/hip_runtime.h>
#include <math.h>

typedef __attribute__((ext_vector_type(8))) short short8;
typedef __attribute__((ext_vector_type(4))) float float4v;

#define QS 0.17677669529663687f   // 1/sqrt(32), folded into wq/bq; exp via __expf

__device__ __forceinline__ float waveReduceSum(float v){
  #pragma unroll
  for(int o=32;o>0;o>>=1) v += __shfl_down(v,o,64);
  return v;
}

__device__ __forceinline__ unsigned short f2bf(float f){
  unsigned int u = __float_as_uint(f);
  return (unsigned short)((u + 0x7FFFu + ((u>>16)&1u)) >> 16);
}
__device__ __forceinline__ float bf2f(unsigned short u){
  return __uint_as_float(((unsigned int)u)<<16);
}

// ------- fused prep: x->bf16 + weight transposes + qkv concat + Wsd build -------
__global__ __launch_bounds__(256) void prep(const float* __restrict__ x, unsigned short* __restrict__ xb,
                     const float* __restrict__ W0, unsigned short* __restrict__ W0t,
                     const float* __restrict__ W1, unsigned short* __restrict__ W1t,
                     const float* __restrict__ W2, unsigned short* __restrict__ W2t,
                     const float* __restrict__ wq, const float* __restrict__ wk,
                     const float* __restrict__ wv, unsigned short* __restrict__ wqkvt,
                     const float* __restrict__ bq, const float* __restrict__ bk,
                     const float* __restrict__ bv, float* __restrict__ bqkv,
                     const float* __restrict__ wo, unsigned short* __restrict__ wot,
                     const float* __restrict__ as0, const float* __restrict__ ad0, unsigned short* __restrict__ S0,
                     const float* __restrict__ as1, const float* __restrict__ ad1, unsigned short* __restrict__ S1,
                     const float* __restrict__ as2, const float* __restrict__ ad2, unsigned short* __restrict__ S2){
  int b = blockIdx.x, t = threadIdx.x;
  if(b < 2048){ int i = b*256 + t; xb[i] = f2bf(x[i]); return; }
  if(b == 4864){ bqkv[t] = bq[t]*QS; bqkv[256+t] = bk[t]; bqkv[512+t] = bv[t]; return; }
  if(b >= 4865){
    int bb = b - 4865;
    const float *W,*as,*ad; unsigned short* S; int K,C,H,k;
    if(bb<128){W=W0;as=as0;ad=ad0;S=S0;K=128;C=128;H=4;k=bb;}
    else if(bb<640){W=W1;as=as1;ad=ad1;S=S1;K=512;C=128;H=4;k=bb-128;}
    else {W=W2;as=as2;ad=ad2;S=S2;K=512;C=256;H=1;k=bb-640;}
    int D = H*C;
    __shared__ float s1[4], s2[4];
    int lane=t&63, wid=t>>6;
    for(int h=0;h<H;h++){
      float ps=0.f, pd=0.f;
      for(int c=t;c<C;c+=256){
        float wv2 = W[k*D + h*C + c];
        ps += wv2*as[h*C+c];
        pd += wv2*ad[h*C+c];
      }
      ps = waveReduceSum(ps); pd = waveReduceSum(pd);
      if(lane==0){ s1[wid]=ps; s2[wid]=pd; }
      __syncthreads();
      if(t==0){
        float u=s1[0]+s1[1]+s1[2]+s1[3], v=s2[0]+s2[1]+s2[2]+s2[3];
        S[h*K+k]=f2bf(u); S[(4+h)*K+k]=f2bf(v);
      }
      __syncthreads();
    }
    if(t==0){
      for(int h=H;h<4;h++){ S[h*K+k]=0; S[(4+h)*K+k]=0; }
      for(int r=8;r<16;r++) S[r*K+k]=0;
    }
    return;
  }
  const float* src; unsigned short* dst; int K,N,base,roff; float sc = 1.f;
  if(b<2304){src=W0;dst=W0t;K=128;N=512;base=2048;roff=0;}
  else if(b<3328){src=W1;dst=W1t;K=512;N=512;base=2304;roff=0;}
  else if(b<3840){src=W2;dst=W2t;K=512;N=256;base=3328;roff=0;}
  else if(b<4096){src=wq;dst=wqkvt;K=256;N=256;base=3840;roff=0;sc=QS;}
  else if(b<4352){src=wk;dst=wqkvt;K=256;N=256;base=4096;roff=256;}
  else if(b<4608){src=wv;dst=wqkvt;K=256;N=256;base=4352;roff=512;}
  else            {src=wo;dst=wot;K=256;N=256;base=4608;roff=0;}
  int idx = (b-base)*256 + t;
  int k = idx / N, n = idx - k*N;
  dst[(n+roff)*K + k] = f2bf(src[idx]*sc);
}

// ------- MFMA bf16 GEMM: double-buffered LDS, software-pipelined, 1 barrier/iter -------
// Occupancy is grid-limited (<=4 blocks/CU), so the 37 KB LDS is free.
__global__ __launch_bounds__(256) void gemm_mfma(const unsigned short* __restrict__ A,
                                                 const unsigned short* __restrict__ Bt,
                                                 const float* __restrict__ bias,
                                                 float* __restrict__ C,
                                                 unsigned short* __restrict__ Cb,
                                                 const unsigned short* __restrict__ Wsd,
                                                 float* __restrict__ als,
                                                 float* __restrict__ ald,
                                                 int M, int K, int N){
  int t = threadIdx.x, lane = t & 63, w = t >> 6;
  int m = lane & 15, g = lane >> 4;
  int bm = blockIdx.y * 64, bn = blockIdx.x * 64;

  __shared__ unsigned short As[2][64*72];
  __shared__ unsigned short Bs[2][64*72];

  int sr = t >> 3;          // 0..31 staging row
  int sc = (t & 7) * 8;     // 0..56 staging col chunk
  const unsigned short* Ap = A  + (bm + sr)*K + sc;
  const unsigned short* Bp = Bt + (bn + sr)*K + sc;
  bool doC = (Wsd != nullptr) && (blockIdx.x == 0);

  float4v acc[4];
  #pragma unroll
  for(int nt=0;nt<4;nt++) acc[nt] = (float4v){0.f,0.f,0.f,0.f};
  float4v acc2 = (float4v){0.f,0.f,0.f,0.f};

  // preload tile 0
  short8 a0 = *(const short8*)(Ap);
  short8 a1 = *(const short8*)(Ap + 32*K);
  short8 b0 = *(const short8*)(Bp);
  short8 b1 = *(const short8*)(Bp + 32*K);

  int buf = 0;
  for(int k0=0;k0<K;k0+=64){
    *(short8*)&As[buf][sr*72 + sc]      = a0;
    *(short8*)&As[buf][(sr+32)*72 + sc] = a1;
    *(short8*)&Bs[buf][sr*72 + sc]      = b0;
    *(short8*)&Bs[buf][(sr+32)*72 + sc] = b1;
    if(k0+64 < K){
      a0 = *(const short8*)(Ap + k0+64);
      a1 = *(const short8*)(Ap + 32*K + k0+64);
      b0 = *(const short8*)(Bp + k0+64);
      b1 = *(const short8*)(Bp + 32*K + k0+64);
    }
    __syncthreads();

    #pragma unroll
    for(int ks=0;ks<2;ks++){
      short8 aA = *(const short8*)&As[buf][(w*16 + m)*72 + ks*32 + g*8];
      #pragma unroll
      for(int nt=0;nt<4;nt++){
        short8 bB = *(const short8*)&Bs[buf][(nt*16 + m)*72 + ks*32 + g*8];
        acc[nt] = __builtin_amdgcn_mfma_f32_16x16x32_bf16(aA, bB, acc[nt], 0,0,0);
      }
      if(doC){
        short8 bW = *(const short8*)(Wsd + m*K + k0 + ks*32 + g*8);
        acc2 = __builtin_amdgcn_mfma_f32_16x16x32_bf16(aA, bW, acc2, 0,0,0);
      }
    }
    buf ^= 1;
  }
  #pragma unroll
  for(int nt=0;nt<4;nt++){
    int col = bn + nt*16 + m;
    float bv = bias ? bias[col] : 0.f;
    #pragma unroll
    for(int r=0;r<4;r++){
      int row = bm + w*16 + g*4 + r;
      float v = acc[nt][r] + bv;
      if(C)  C[row*N + col]  = v;
      if(Cb) Cb[row*N + col] = f2bf(v);
    }
  }
  if(doC){
    #pragma unroll
    for(int r=0;r<4;r++){
      int row = bm + w*16 + g*4 + r;
      if(m<4)      als[row*4 + m]     = acc2[r];
      else if(m<8) ald[row*4 + (m-4)] = acc2[r];
    }
  }
}

// ---------------- CSR build ----------------
__global__ void csr_count(const int* __restrict__ ei, int E, int Etot,
                          int* __restrict__ hist){
  int e = blockIdx.x*256 + threadIdx.x;
  if(e>=Etot) return;
  int d = (e<E) ? (ei[E+e]&4095) : (e-E);
  atomicAdd(&hist[d], 1);
}

__global__ __launch_bounds__(1024) void csr_scan(const int* __restrict__ hist,
                                                 int* __restrict__ row_ptr,
                                                 int* __restrict__ wcnt, int N){
  __shared__ int sh[1024];
  int t = threadIdx.x;
  int base[4];
  int s = 0;
  #pragma unroll
  for(int i=0;i<4;i++){ base[i]=s; s += hist[t*4+i]; }
  sh[t] = s;
  __syncthreads();
  for(int off=1; off<1024; off<<=1){
    int x = (t>=off) ? sh[t-off] : 0;
    __syncthreads();
    sh[t] += x;
    __syncthreads();
  }
  int excl = (t==0) ? 0 : sh[t-1];
  #pragma unroll
  for(int i=0;i<4;i++){
    row_ptr[t*4+i] = excl + base[i];
    wcnt[t*4+i]    = excl + base[i];
  }
  if(t==1023) row_ptr[N] = excl + s;
}

__global__ void csr_scatter(const int* __restrict__ ei, int E, int Etot,
                            int* __restrict__ wcnt, int* __restrict__ col){
  int e = blockIdx.x*256 + threadIdx.x;
  if(e>=Etot) return;
  int s,d;
  if(e<E){ s=ei[e]&4095; d=ei[E+e]&4095; } else { s=d=e-E; }
  int pos = atomicAdd(&wcnt[d], 1);
  col[pos] = s;
}

// ------- fused GAT gather + softmax + bias + ELU + LayerNorm (+residual) -------
#define CE 128
__global__ void gat_gather_ln(const int* __restrict__ rp,
                              const int* __restrict__ col,
                              const unsigned short* __restrict__ xlb,
                              const float* __restrict__ als,
                              const float* __restrict__ ald,
                              const float* __restrict__ bias,
                              const float* __restrict__ gw,
                              const float* __restrict__ be,
                              const float* __restrict__ res,
                              float* __restrict__ out,
                              unsigned short* __restrict__ outb,
                              int D, int logC, int do_elu){
  int n = blockIdx.x, t = threadIdx.x;
  int c0 = t*2;
  int h = c0 >> logC;            // wave-uniform
  int rowW = D >> 1;
  float4 advv = *(const float4*)(ald + n*4);
  int start = rp[n], end = rp[n+1];
  const unsigned int* xw = (const unsigned int*)xlb;

  __shared__ float pw[CE*4];
  __shared__ int offs[CE];

  float acc0=0.f, acc1=0.f, den=0.f;

  for(int base=start; base<end; base+=CE){
    int cnt = min(CE, end-base);
    __syncthreads();
    if(t < cnt){
      int s = col[base+t];
      offs[t] = s*rowW;
      float4 av = *(const float4*)(als + s*4);
      #pragma unroll
      for(int hh=0;hh<4;hh++){
        float a = ((const float*)&av)[hh] + ((const float*)&advv)[hh];
        a = a>0.f ? a : 0.2f*a;
        pw[t*4+hh] = __expf(a);
      }
    }
    __syncthreads();
    #pragma unroll 4
    for(int j=0;j<cnt;j++){
      float p = pw[j*4+h];
      unsigned int u = xw[offs[j] + t];
      acc0 += p * bf2f((unsigned short)(u & 0xffffu));
      acc1 += p * bf2f((unsigned short)(u >> 16));
      den += p;
    }
  }

  float inv_d = 1.f/(den + 1e-16f);
  float v0 = acc0*inv_d + bias[c0];
  float v1 = acc1*inv_d + bias[c0+1];
  if(do_elu){
    v0 = v0>0.f ? v0 : expm1f(v0);
    v1 = v1>0.f ? v1 : expm1f(v1);
  }
  __shared__ float sh[4];
  int lane=t&63, wid=t>>6, nw = blockDim.x>>6;
  float sum = waveReduceSum(v0+v1);
  if(lane==0) sh[wid]=sum;
  __syncthreads();
  float mean = 0.f;
  for(int i=0;i<nw;i++) mean += sh[i];
  mean /= (float)D;
  __syncthreads();
  float d0 = v0-mean, d1 = v1-mean;
  float vs = waveReduceSum(d0*d0 + d1*d1);
  if(lane==0) sh[wid]=vs;
  __syncthreads();
  float var = 0.f;
  for(int i=0;i<nw;i++) var += sh[i];
  var /= (float)D;
  float inv = rsqrtf(var + 1e-5f);
  float y0 = d0*inv*gw[c0]   + be[c0];
  float y1 = d1*inv*gw[c0+1] + be[c0+1];
  if(res){ float2 rv = *(const float2*)(res + n*D + c0); y0 += rv.x; y1 += rv.y; }
  if(out) *(float2*)(out + n*D + c0) = make_float2(y0, y1);
  if(outb) ((unsigned int*)outb)[n*rowW + t] =
      (unsigned int)f2bf(y0) | ((unsigned int)f2bf(y1) << 16);
}

// --------- V transpose: QKV[:,512:768] bf16 [S,768] -> Vt bf16 [256,S] ---------
__global__ __launch_bounds__(256) void transpose_v(const unsigned short* __restrict__ QKV,
                                                   unsigned short* __restrict__ Vt, int S){
  __shared__ unsigned short tile[64][72];
  int bs = blockIdx.x*64;
  int bd = blockIdx.y*64;
  int t = threadIdx.x;
  int r8 = t>>3, c8 = (t&7)*8;
  #pragma unroll
  for(int it=0; it<2; it++){
    int row = r8 + it*32;
    short8 v = *(const short8*)(QKV + (bs+row)*768 + 512 + bd + c8);
    *(short8*)&tile[row][c8] = v;
  }
  __syncthreads();
  #pragma unroll
  for(int it=0; it<2; it++){
    int drow = r8 + it*32;
    short8 o;
    #pragma unroll
    for(int j=0;j<8;j++) o[j] = (short)tile[c8+j][drow];
    *(short8*)(Vt + (bd+drow)*S + bs + c8) = o;
  }
}

// --------- MFMA bf16 MHA, flash-decode + XOR-swizzled Ps/Vs (bank-balanced) ---------
// Ps/Vs rows stride 64 shorts; chunk-of-8 swizzled by (chunk ^ (row&7)):
// every b128/b64 LDS op lands 2 lanes/bank (minimum). Ks stride-36 already ~2-way.
#define KS 4
__global__ __launch_bounds__(256) void attention11(const unsigned short* __restrict__ QKV,
                                                   const unsigned short* __restrict__ Vt,
                                                   float* __restrict__ Op,
                                                   float* __restrict__ lp, int S){
  const int RS = 768;
  int qb = blockIdx.x * 64;
  int h  = blockIdx.y;
  int ks = blockIdx.z;
  int t  = threadIdx.x;
  int lane = t & 63, w = t >> 6;
  int m = lane & 15, g = lane >> 4;
  int m7 = m & 7;

  __shared__ unsigned short Ps[64*64];   // [q][key] bf16, swizzled chunks
  __shared__ unsigned short Vs[32*64];   // [dim][key] bf16, swizzled chunks
  __shared__ unsigned short Ks[64*36];   // [key][dim] bf16, stride 36

  short8 aQ = *(const short8*)(QKV + (qb + w*16 + m)*RS + h*32 + g*8);

  float4v o0 = {0.f,0.f,0.f,0.f}, o1 = {0.f,0.f,0.f,0.f};
  float l = 0.f;

  int r8 = t>>3, c8 = t&7;        // V staging: dim row 0..31, key chunk 0..7
  int kr = t>>2, kc = (t&3)*8;    // K staging: key row 0..63, dim chunk
  int kA = ks*(S/KS), kB = kA + S/KS;

  for(int kt=kA; kt<kB; kt+=64){
    // global loads first (latency overlaps previous tile's compute)
    short8 v = *(const short8*)(Vt + (h*32 + r8)*S + kt + c8*8);
    short8 kv = *(const short8*)(QKV + (kt + kr)*RS + 256 + h*32 + kc);
    __syncthreads();   // previous tile's LDS reads complete
    *(short8*)&Vs[r8*64 + ((c8 ^ (r8&7))<<3)] = v;
    *(short8*)&Ks[kr*36 + kc] = kv;
    __syncthreads();

    // S^T strip: lane owns keys nt*16+g*4..+3 of query m
    #pragma unroll
    for(int nt=0;nt<4;nt++){
      short8 aK = *(const short8*)&Ks[(nt*16 + m)*36 + g*8];
      float4v acc = {0.f,0.f,0.f,0.f};
      acc = __builtin_amdgcn_mfma_f32_16x16x32_bf16(aK, aQ, acc, 0,0,0);
      float p0 = __expf(acc[0]);
      float p1 = __expf(acc[1]);
      float p2 = __expf(acc[2]);
      float p3 = __expf(acc[3]);
      l += (p0+p1) + (p2+p3);
      unsigned int r0 = __float_as_uint(p0) + 0x8000u;
      unsigned int r1 = __float_as_uint(p1) + 0x8000u;
      unsigned int r2 = __float_as_uint(p2) + 0x8000u;
      unsigned int r3 = __float_as_uint(p3) + 0x8000u;
      uint2 pk;
      pk.x = __builtin_amdgcn_perm(r1, r0, 0x07060302u);
      pk.y = __builtin_amdgcn_perm(r3, r2, 0x07060302u);
      // chunk = 2nt+(g>>1), swizzle by m&7, half-chunk offset (g&1)*4
      *(uint2*)&Ps[(w*16 + m)*64 + (((2*nt + (g>>1)) ^ m7)<<3) + ((g&1)<<2)] = pk;
    }

    // O strip += P @ V (aP rows wave-private; same-wave LDS order suffices)
    #pragma unroll
    for(int kh=0;kh<2;kh++){
      int swz = ((kh*4 + g) ^ m7) << 3;
      short8 aP  = *(const short8*)&Ps[(w*16 + m)*64 + swz];
      short8 bV0 = *(const short8*)&Vs[m*64       + swz];
      short8 bV1 = *(const short8*)&Vs[(16+m)*64  + swz];
      o0 = __builtin_amdgcn_mfma_f32_16x16x32_bf16(aP, bV0, o0, 0,0,0);
      o1 = __builtin_amdgcn_mfma_f32_16x16x32_bf16(aP, bV1, o1, 0,0,0);
    }
  }

  l += __shfl_xor(l, 16, 64);
  l += __shfl_xor(l, 32, 64);

  float* Ob = Op + (size_t)ks*S*256;
  #pragma unroll
  for(int r=0;r<4;r++){
    int q = qb + w*16 + g*4 + r;
    Ob[q*256 + h*32 + m]      = o0[r];
    Ob[q*256 + h*32 + 16 + m] = o1[r];
  }
  if(g==0) lp[ks*S*8 + (qb + w*16 + m)*8 + h] = l;
}

__global__ __launch_bounds__(256) void combine(const float* __restrict__ Op,
                                               const float* __restrict__ lp,
                                               unsigned short* __restrict__ aob, int S){
  int q = blockIdx.x, t = threadIdx.x;
  int h = t >> 5;
  float o = 0.f, l = 0.f;
  #pragma unroll
  for(int s=0;s<KS;s++) o += Op[(size_t)s*S*256 + q*256 + t];
  #pragma unroll
  for(int s=0;s<KS;s++) l += lp[s*S*8 + q*8 + h];
  aob[q*256 + t] = f2bf(o / l);
}

extern "C" void kernel_launch(void* const* d_in, const int* in_sizes, int n_in,
                              void* d_out, int out_size, void* d_ws, size_t ws_size,
                              hipStream_t stream) {
  const float* x   = (const float*)d_in[0];
  const int*   ei  = (const int*)d_in[1];
  const float* W0  = (const float*)d_in[2];
  const float* as0 = (const float*)d_in[3];
  const float* ad0 = (const float*)d_in[4];
  const float* b0  = (const float*)d_in[5];
  const float* W1  = (const float*)d_in[6];
  const float* as1 = (const float*)d_in[7];
  const float* ad1 = (const float*)d_in[8];
  const float* b1  = (const float*)d_in[9];
  const float* W2  = (const float*)d_in[10];
  const float* as2 = (const float*)d_in[11];
  const float* ad2 = (const float*)d_in[12];
  const float* b2  = (const float*)d_in[13];
  const float* g0  = (const float*)d_in[14];
  const float* be0 = (const float*)d_in[15];
  const float* g1  = (const float*)d_in[16];
  const float* be1 = (const float*)d_in[17];
  const float* g2  = (const float*)d_in[18];
  const float* be2 = (const float*)d_in[19];
  const float* wq  = (const float*)d_in[20];
  const float* bq  = (const float*)d_in[21];
  const float* wk  = (const float*)d_in[22];
  const float* bk  = (const float*)d_in[23];
  const float* wv  = (const float*)d_in[24];
  const float* bv  = (const float*)d_in[25];
  const float* wo  = (const float*)d_in[26];
  const float* bo  = (const float*)d_in[27];
  float* out = (float*)d_out;

  const int N = 4096;
  const int E = in_sizes[1] / 2;
  const int Etot = E + N;

  char* p = (char*)d_ws;
  auto alloc = [&](size_t bytes){ char* r = p; p += (bytes + 255) & ~(size_t)255; return r; };

  float* h0   = (float*)alloc(N*512*4);
  float* als  = (float*)alloc(N*4*4);
  float* ald  = (float*)alloc(N*4*4);
  unsigned short* xb   = (unsigned short*)alloc(N*128*2);
  unsigned short* xlb  = (unsigned short*)alloc(N*512*2);
  unsigned short* h0b  = (unsigned short*)alloc(N*512*2);
  unsigned short* h1b  = (unsigned short*)alloc(N*512*2);
  unsigned short* h2b  = (unsigned short*)alloc(N*256*2);
  unsigned short* QKVb = (unsigned short*)alloc((size_t)N*768*2);
  unsigned short* Vt   = (unsigned short*)alloc(256*N*2);
  unsigned short* aob  = (unsigned short*)alloc(N*256*2);
  unsigned short* W0t  = (unsigned short*)alloc(512*128*2);
  unsigned short* W1t  = (unsigned short*)alloc(512*512*2);
  unsigned short* W2t  = (unsigned short*)alloc(256*512*2);
  unsigned short* wqkvt= (unsigned short*)alloc(768*256*2);
  float* bqkv = (float*)alloc(768*4);
  unsigned short* wot  = (unsigned short*)alloc(256*256*2);
  unsigned short* Wsd0 = (unsigned short*)alloc(16*128*2);
  unsigned short* Wsd1 = (unsigned short*)alloc(16*512*2);
  unsigned short* Wsd2 = (unsigned short*)alloc(16*512*2);
  float* Op = (float*)alloc((size_t)KS*N*256*4);
  float* lp = (float*)alloc((size_t)KS*N*8*4);
  int* hist = (int*)alloc(N*4);
  int* wcnt = (int*)alloc(N*4);
  int* rp   = (int*)alloc((N+2)*4);
  int* col  = (int*)alloc(Etot*4);

  // ---------- prep (x conv + transposes + bqkv + Wsd) ----------
  prep<<<6017, 256, 0, stream>>>(x, xb, W0, W0t, W1, W1t, W2, W2t,
                                 wq, wk, wv, wqkvt, bq, bk, bv, bqkv, wo, wot,
                                 as0, ad0, Wsd0, as1, ad1, Wsd1, as2, ad2, Wsd2);

  // ---------- CSR build (by destination) ----------
  hipMemsetAsync(hist, 0, N*sizeof(int), stream);
  csr_count<<<(Etot+255)/256, 256, 0, stream>>>(ei, E, Etot, hist);
  csr_scan<<<1, 1024, 0, stream>>>(hist, rp, wcnt, N);
  csr_scatter<<<(Etot+255)/256, 256, 0, stream>>>(ei, E, Etot, wcnt, col);

  // ---------- GAT layer 0: 128 -> 4x128 (512) ----------
  gemm_mfma<<<dim3(8, 64), 256, 0, stream>>>(xb, W0t, nullptr, nullptr, xlb, Wsd0, als, ald, N, 128, 512);
  gat_gather_ln<<<N, 256, 0, stream>>>(rp, col, xlb, als, ald, b0, g0, be0,
                                       nullptr, h0, h0b, 512, 7, 1);

  // ---------- GAT layer 1: 512 -> 4x128 (512), residual ----------
  gemm_mfma<<<dim3(8, 64), 256, 0, stream>>>(h0b, W1t, nullptr, nullptr, xlb, Wsd1, als, ald, N, 512, 512);
  gat_gather_ln<<<N, 256, 0, stream>>>(rp, col, xlb, als, ald, b1, g1, be1,
                                       h0, nullptr, h1b, 512, 7, 1);

  // ---------- GAT layer 2: 512 -> 1x256, 1 head, no ELU ----------
  gemm_mfma<<<dim3(4, 64), 256, 0, stream>>>(h1b, W2t, nullptr, nullptr, xlb, Wsd2, als, ald, N, 512, 256);
  gat_gather_ln<<<N, 128, 0, stream>>>(rp, col, xlb, als, ald, b2, g2, be2,
                                       nullptr, nullptr, h2b, 256, 8, 0);

  // ---------- dense MHA (bf16 MFMA, flash-decode, fused QKV) ----------
  gemm_mfma<<<dim3(12, 64), 256, 0, stream>>>(h2b, wqkvt, bqkv, nullptr, QKVb, nullptr, nullptr, nullptr, N, 256, 768);
  transpose_v<<<dim3(N/64, 4), 256, 0, stream>>>(QKVb, Vt, N);
  attention11<<<dim3(N/64, 8, KS), 256, 0, stream>>>(QKVb, Vt, Op, lp, N);
  combine<<<N, 256, 0, stream>>>(Op, lp, aob, N);
  gemm_mfma<<<dim3(4, 64), 256, 0, stream>>>(aob, wot, bo, out, nullptr, nullptr, nullptr, nullptr, N, 256, 256);
}

// Round 15
// 277.159 us; speedup vs baseline: 1.3115x; 1.0261x over previous
//
#include <hip/hip_runtime.h>
#include <math.h>

typedef __attribute__((ext_vector_type(8))) short short8;
typedef __attribute__((ext_vector_type(4))) float float4v;

#define QS 0.17677669529663687f   // 1/sqrt(32), folded into wq/bq; exp via __expf

__device__ __forceinline__ float waveReduceSum(float v){
  #pragma unroll
  for(int o=32;o>0;o>>=1) v += __shfl_down(v,o,64);
  return v;
}

__device__ __forceinline__ unsigned short f2bf(float f){
  unsigned int u = __float_as_uint(f);
  return (unsigned short)((u + 0x7FFFu + ((u>>16)&1u)) >> 16);
}
__device__ __forceinline__ float bf2f(unsigned short u){
  return __uint_as_float(((unsigned int)u)<<16);
}

// ------- fused prep: x->bf16 + weight transposes + qkv concat + Wsd build -------
__global__ __launch_bounds__(256) void prep(const float* __restrict__ x, unsigned short* __restrict__ xb,
                     const float* __restrict__ W0, unsigned short* __restrict__ W0t,
                     const float* __restrict__ W1, unsigned short* __restrict__ W1t,
                     const float* __restrict__ W2, unsigned short* __restrict__ W2t,
                     const float* __restrict__ wq, const float* __restrict__ wk,
                     const float* __restrict__ wv, unsigned short* __restrict__ wqkvt,
                     const float* __restrict__ bq, const float* __restrict__ bk,
                     const float* __restrict__ bv, float* __restrict__ bqkv,
                     const float* __restrict__ wo, unsigned short* __restrict__ wot,
                     const float* __restrict__ as0, const float* __restrict__ ad0, unsigned short* __restrict__ S0,
                     const float* __restrict__ as1, const float* __restrict__ ad1, unsigned short* __restrict__ S1,
                     const float* __restrict__ as2, const float* __restrict__ ad2, unsigned short* __restrict__ S2){
  int b = blockIdx.x, t = threadIdx.x;
  if(b < 2048){ int i = b*256 + t; xb[i] = f2bf(x[i]); return; }
  if(b == 4864){ bqkv[t] = bq[t]*QS; bqkv[256+t] = bk[t]; bqkv[512+t] = bv[t]; return; }
  if(b >= 4865){
    int bb = b - 4865;
    const float *W,*as,*ad; unsigned short* S; int K,C,H,k;
    if(bb<128){W=W0;as=as0;ad=ad0;S=S0;K=128;C=128;H=4;k=bb;}
    else if(bb<640){W=W1;as=as1;ad=ad1;S=S1;K=512;C=128;H=4;k=bb-128;}
    else {W=W2;as=as2;ad=ad2;S=S2;K=512;C=256;H=1;k=bb-640;}
    int D = H*C;
    __shared__ float s1[4], s2[4];
    int lane=t&63, wid=t>>6;
    for(int h=0;h<H;h++){
      float ps=0.f, pd=0.f;
      for(int c=t;c<C;c+=256){
        float wv2 = W[k*D + h*C + c];
        ps += wv2*as[h*C+c];
        pd += wv2*ad[h*C+c];
      }
      ps = waveReduceSum(ps); pd = waveReduceSum(pd);
      if(lane==0){ s1[wid]=ps; s2[wid]=pd; }
      __syncthreads();
      if(t==0){
        float u=s1[0]+s1[1]+s1[2]+s1[3], v=s2[0]+s2[1]+s2[2]+s2[3];
        S[h*K+k]=f2bf(u); S[(4+h)*K+k]=f2bf(v);
      }
      __syncthreads();
    }
    if(t==0){
      for(int h=H;h<4;h++){ S[h*K+k]=0; S[(4+h)*K+k]=0; }
      for(int r=8;r<16;r++) S[r*K+k]=0;
    }
    return;
  }
  const float* src; unsigned short* dst; int K,N,base,roff; float sc = 1.f;
  if(b<2304){src=W0;dst=W0t;K=128;N=512;base=2048;roff=0;}
  else if(b<3328){src=W1;dst=W1t;K=512;N=512;base=2304;roff=0;}
  else if(b<3840){src=W2;dst=W2t;K=512;N=256;base=3328;roff=0;}
  else if(b<4096){src=wq;dst=wqkvt;K=256;N=256;base=3840;roff=0;sc=QS;}
  else if(b<4352){src=wk;dst=wqkvt;K=256;N=256;base=4096;roff=256;}
  else if(b<4608){src=wv;dst=wqkvt;K=256;N=256;base=4352;roff=512;}
  else            {src=wo;dst=wot;K=256;N=256;base=4608;roff=0;}
  int idx = (b-base)*256 + t;
  int k = idx / N, n = idx - k*N;
  dst[(n+roff)*K + k] = f2bf(src[idx]*sc);
}

// ------- MFMA bf16 GEMM: double-buffered LDS, software-pipelined -------
// If VtT != null: output-column blocks with bn>=512 write their 64x64 tile
// TRANSPOSED to VtT[(col-512)*M+row] via an LDS-tiled epilogue (coalesced 16B
// stores) instead of Cb. (Fused V-transpose for the QKV GEMM.)
__global__ __launch_bounds__(256) void gemm_mfma(const unsigned short* __restrict__ A,
                                                 const unsigned short* __restrict__ Bt,
                                                 const float* __restrict__ bias,
                                                 float* __restrict__ C,
                                                 unsigned short* __restrict__ Cb,
                                                 unsigned short* __restrict__ VtT,
                                                 const unsigned short* __restrict__ Wsd,
                                                 float* __restrict__ als,
                                                 float* __restrict__ ald,
                                                 int M, int K, int N){
  int t = threadIdx.x, lane = t & 63, w = t >> 6;
  int m = lane & 15, g = lane >> 4;
  int bm = blockIdx.y * 64, bn = blockIdx.x * 64;

  __shared__ unsigned short As[2][64*72];
  __shared__ unsigned short Bs[2][64*72];

  int sr = t >> 3;          // 0..31 staging row
  int sc = (t & 7) * 8;     // 0..56 staging col chunk
  const unsigned short* Ap = A  + (bm + sr)*K + sc;
  const unsigned short* Bp = Bt + (bn + sr)*K + sc;
  bool doC = (Wsd != nullptr) && (blockIdx.x == 0);

  float4v acc[4];
  #pragma unroll
  for(int nt=0;nt<4;nt++) acc[nt] = (float4v){0.f,0.f,0.f,0.f};
  float4v acc2 = (float4v){0.f,0.f,0.f,0.f};

  short8 a0 = *(const short8*)(Ap);
  short8 a1 = *(const short8*)(Ap + 32*K);
  short8 b0 = *(const short8*)(Bp);
  short8 b1 = *(const short8*)(Bp + 32*K);

  int buf = 0;
  for(int k0=0;k0<K;k0+=64){
    *(short8*)&As[buf][sr*72 + sc]      = a0;
    *(short8*)&As[buf][(sr+32)*72 + sc] = a1;
    *(short8*)&Bs[buf][sr*72 + sc]      = b0;
    *(short8*)&Bs[buf][(sr+32)*72 + sc] = b1;
    if(k0+64 < K){
      a0 = *(const short8*)(Ap + k0+64);
      a1 = *(const short8*)(Ap + 32*K + k0+64);
      b0 = *(const short8*)(Bp + k0+64);
      b1 = *(const short8*)(Bp + 32*K + k0+64);
    }
    __syncthreads();

    #pragma unroll
    for(int ks=0;ks<2;ks++){
      short8 aA = *(const short8*)&As[buf][(w*16 + m)*72 + ks*32 + g*8];
      #pragma unroll
      for(int nt=0;nt<4;nt++){
        short8 bB = *(const short8*)&Bs[buf][(nt*16 + m)*72 + ks*32 + g*8];
        acc[nt] = __builtin_amdgcn_mfma_f32_16x16x32_bf16(aA, bB, acc[nt], 0,0,0);
      }
      if(doC){
        short8 bW = *(const short8*)(Wsd + m*K + k0 + ks*32 + g*8);
        acc2 = __builtin_amdgcn_mfma_f32_16x16x32_bf16(aA, bW, acc2, 0,0,0);
      }
    }
    buf ^= 1;
  }

  if(VtT && bn >= 512){
    // ---- transposed epilogue: pack tile into LDS, write Vt coalesced ----
    __syncthreads();                       // all waves done reading As/Bs
    unsigned short* T = &As[0][0];         // 64 rows x stride 72
    #pragma unroll
    for(int nt=0;nt<4;nt++){
      int col = bn + nt*16 + m;
      float bv = bias ? bias[col] : 0.f;
      unsigned int r0 = __float_as_uint(acc[nt][0]+bv) + 0x8000u;
      unsigned int r1 = __float_as_uint(acc[nt][1]+bv) + 0x8000u;
      unsigned int r2 = __float_as_uint(acc[nt][2]+bv) + 0x8000u;
      unsigned int r3 = __float_as_uint(acc[nt][3]+bv) + 0x8000u;
      uint2 pk;
      pk.x = __builtin_amdgcn_perm(r1, r0, 0x07060302u);
      pk.y = __builtin_amdgcn_perm(r3, r2, 0x07060302u);
      *(uint2*)&T[(nt*16 + m)*72 + w*16 + g*4] = pk;   // T[col-bn][row-bm]
    }
    __syncthreads();
    int d  = t >> 2;            // 0..63 dim within tile
    int qc = (t & 3) * 16;      // query chunk
    short8 v0 = *(const short8*)&T[d*72 + qc];
    short8 v1 = *(const short8*)&T[d*72 + qc + 8];
    unsigned short* dst = VtT + (size_t)(bn - 512 + d)*M + bm + qc;
    *(short8*)(dst)     = v0;
    *(short8*)(dst + 8) = v1;
    return;
  }

  #pragma unroll
  for(int nt=0;nt<4;nt++){
    int col = bn + nt*16 + m;
    float bv = bias ? bias[col] : 0.f;
    #pragma unroll
    for(int r=0;r<4;r++){
      int row = bm + w*16 + g*4 + r;
      float v = acc[nt][r] + bv;
      if(C)  C[row*N + col]  = v;
      if(Cb) Cb[row*N + col] = f2bf(v);
    }
  }
  if(doC){
    #pragma unroll
    for(int r=0;r<4;r++){
      int row = bm + w*16 + g*4 + r;
      if(m<4)      als[row*4 + m]     = acc2[r];
      else if(m<8) ald[row*4 + (m-4)] = acc2[r];
    }
  }
}

// ---------------- CSR build ----------------
__global__ void csr_count(const int* __restrict__ ei, int E, int Etot,
                          int* __restrict__ hist){
  int e = blockIdx.x*256 + threadIdx.x;
  if(e>=Etot) return;
  int d = (e<E) ? (ei[E+e]&4095) : (e-E);
  atomicAdd(&hist[d], 1);
}

__global__ __launch_bounds__(1024) void csr_scan(const int* __restrict__ hist,
                                                 int* __restrict__ row_ptr,
                                                 int* __restrict__ wcnt, int N){
  __shared__ int sh[1024];
  int t = threadIdx.x;
  int base[4];
  int s = 0;
  #pragma unroll
  for(int i=0;i<4;i++){ base[i]=s; s += hist[t*4+i]; }
  sh[t] = s;
  __syncthreads();
  for(int off=1; off<1024; off<<=1){
    int x = (t>=off) ? sh[t-off] : 0;
    __syncthreads();
    sh[t] += x;
    __syncthreads();
  }
  int excl = (t==0) ? 0 : sh[t-1];
  #pragma unroll
  for(int i=0;i<4;i++){
    row_ptr[t*4+i] = excl + base[i];
    wcnt[t*4+i]    = excl + base[i];
  }
  if(t==1023) row_ptr[N] = excl + s;
}

__global__ void csr_scatter(const int* __restrict__ ei, int E, int Etot,
                            int* __restrict__ wcnt, int* __restrict__ col){
  int e = blockIdx.x*256 + threadIdx.x;
  if(e>=Etot) return;
  int s,d;
  if(e<E){ s=ei[e]&4095; d=ei[E+e]&4095; } else { s=d=e-E; }
  int pos = atomicAdd(&wcnt[d], 1);
  col[pos] = s;
}

// ------- fused GAT gather + softmax + bias + ELU + LayerNorm (+residual) -------
// Ping-pong chunk staging: stage chunk c+1 while accumulating chunk c (1 barrier/chunk).
#define CE 128
__global__ void gat_gather_ln(const int* __restrict__ rp,
                              const int* __restrict__ col,
                              const unsigned short* __restrict__ xlb,
                              const float* __restrict__ als,
                              const float* __restrict__ ald,
                              const float* __restrict__ bias,
                              const float* __restrict__ gw,
                              const float* __restrict__ be,
                              const float* __restrict__ res,
                              float* __restrict__ out,
                              unsigned short* __restrict__ outb,
                              int D, int logC, int do_elu){
  int n = blockIdx.x, t = threadIdx.x;
  int c0 = t*2;
  int h = c0 >> logC;            // wave-uniform
  int rowW = D >> 1;
  float4 advv = *(const float4*)(ald + n*4);
  int start = rp[n], end = rp[n+1];
  const unsigned int* xw = (const unsigned int*)xlb;

  __shared__ float pw[2][CE*4];
  __shared__ int offs[2][CE];

  float acc0=0.f, acc1=0.f, den=0.f;
  int nch = (end - start + CE - 1) / CE;

  // stage chunk 0
  {
    int cnt = min(CE, end-start);
    if(t < cnt){
      int s = col[start+t];
      offs[0][t] = s*rowW;
      float4 av = *(const float4*)(als + s*4);
      #pragma unroll
      for(int hh=0;hh<4;hh++){
        float a = ((const float*)&av)[hh] + ((const float*)&advv)[hh];
        a = a>0.f ? a : 0.2f*a;
        pw[0][t*4+hh] = __expf(a);
      }
    }
  }

  for(int c=0;c<nch;c++){
    __syncthreads();                  // chunk c staged & previous reads done
    if(c+1 < nch){
      int base = start + (c+1)*CE;
      int cnt = min(CE, end-base);
      int b2 = (c+1)&1;
      if(t < cnt){
        int s = col[base+t];
        offs[b2][t] = s*rowW;
        float4 av = *(const float4*)(als + s*4);
        #pragma unroll
        for(int hh=0;hh<4;hh++){
          float a = ((const float*)&av)[hh] + ((const float*)&advv)[hh];
          a = a>0.f ? a : 0.2f*a;
          pw[b2][t*4+hh] = __expf(a);
        }
      }
    }
    int base = start + c*CE;
    int cnt = min(CE, end-base);
    int b = c&1;
    #pragma unroll 8
    for(int j=0;j<cnt;j++){
      float p = pw[b][j*4+h];
      unsigned int u = xw[offs[b][j] + t];
      acc0 += p * bf2f((unsigned short)(u & 0xffffu));
      acc1 += p * bf2f((unsigned short)(u >> 16));
      den += p;
    }
  }

  float inv_d = 1.f/(den + 1e-16f);
  float v0 = acc0*inv_d + bias[c0];
  float v1 = acc1*inv_d + bias[c0+1];
  if(do_elu){
    v0 = v0>0.f ? v0 : expm1f(v0);
    v1 = v1>0.f ? v1 : expm1f(v1);
  }
  __shared__ float sh[4];
  int lane=t&63, wid=t>>6, nw = blockDim.x>>6;
  float sum = waveReduceSum(v0+v1);
  if(lane==0) sh[wid]=sum;
  __syncthreads();
  float mean = 0.f;
  for(int i=0;i<nw;i++) mean += sh[i];
  mean /= (float)D;
  __syncthreads();
  float d0 = v0-mean, d1 = v1-mean;
  float vs = waveReduceSum(d0*d0 + d1*d1);
  if(lane==0) sh[wid]=vs;
  __syncthreads();
  float var = 0.f;
  for(int i=0;i<nw;i++) var += sh[i];
  var /= (float)D;
  float inv = rsqrtf(var + 1e-5f);
  float y0 = d0*inv*gw[c0]   + be[c0];
  float y1 = d1*inv*gw[c0+1] + be[c0+1];
  if(res){ float2 rv = *(const float2*)(res + n*D + c0); y0 += rv.x; y1 += rv.y; }
  if(out) *(float2*)(out + n*D + c0) = make_float2(y0, y1);
  if(outb) ((unsigned int*)outb)[n*rowW + t] =
      (unsigned int)f2bf(y0) | ((unsigned int)f2bf(y1) << 16);
}

// --------- MFMA bf16 MHA, flash-decode + XOR-swizzled Ps/Vs (bank-balanced) ---------
#define KS 4
__global__ __launch_bounds__(256) void attention11(const unsigned short* __restrict__ QKV,
                                                   const unsigned short* __restrict__ Vt,
                                                   float* __restrict__ Op,
                                                   float* __restrict__ lp, int S){
  const int RS = 768;
  int qb = blockIdx.x * 64;
  int h  = blockIdx.y;
  int ks = blockIdx.z;
  int t  = threadIdx.x;
  int lane = t & 63, w = t >> 6;
  int m = lane & 15, g = lane >> 4;
  int m7 = m & 7;

  __shared__ unsigned short Ps[64*64];   // [q][key] bf16, swizzled chunks
  __shared__ unsigned short Vs[32*64];   // [dim][key] bf16, swizzled chunks
  __shared__ unsigned short Ks[64*36];   // [key][dim] bf16, stride 36

  short8 aQ = *(const short8*)(QKV + (qb + w*16 + m)*RS + h*32 + g*8);

  float4v o0 = {0.f,0.f,0.f,0.f}, o1 = {0.f,0.f,0.f,0.f};
  float l = 0.f;

  int r8 = t>>3, c8 = t&7;        // V staging: dim row 0..31, key chunk 0..7
  int kr = t>>2, kc = (t&3)*8;    // K staging: key row 0..63, dim chunk
  int kA = ks*(S/KS), kB = kA + S/KS;

  for(int kt=kA; kt<kB; kt+=64){
    short8 v = *(const short8*)(Vt + (h*32 + r8)*S + kt + c8*8);
    short8 kv = *(const short8*)(QKV + (kt + kr)*RS + 256 + h*32 + kc);
    __syncthreads();
    *(short8*)&Vs[r8*64 + ((c8 ^ (r8&7))<<3)] = v;
    *(short8*)&Ks[kr*36 + kc] = kv;
    __syncthreads();

    #pragma unroll
    for(int nt=0;nt<4;nt++){
      short8 aK = *(const short8*)&Ks[(nt*16 + m)*36 + g*8];
      float4v acc = {0.f,0.f,0.f,0.f};
      acc = __builtin_amdgcn_mfma_f32_16x16x32_bf16(aK, aQ, acc, 0,0,0);
      float p0 = __expf(acc[0]);
      float p1 = __expf(acc[1]);
      float p2 = __expf(acc[2]);
      float p3 = __expf(acc[3]);
      l += (p0+p1) + (p2+p3);
      unsigned int r0 = __float_as_uint(p0) + 0x8000u;
      unsigned int r1 = __float_as_uint(p1) + 0x8000u;
      unsigned int r2 = __float_as_uint(p2) + 0x8000u;
      unsigned int r3 = __float_as_uint(p3) + 0x8000u;
      uint2 pk;
      pk.x = __builtin_amdgcn_perm(r1, r0, 0x07060302u);
      pk.y = __builtin_amdgcn_perm(r3, r2, 0x07060302u);
      *(uint2*)&Ps[(w*16 + m)*64 + (((2*nt + (g>>1)) ^ m7)<<3) + ((g&1)<<2)] = pk;
    }

    #pragma unroll
    for(int kh=0;kh<2;kh++){
      int swz = ((kh*4 + g) ^ m7) << 3;
      short8 aP  = *(const short8*)&Ps[(w*16 + m)*64 + swz];
      short8 bV0 = *(const short8*)&Vs[m*64       + swz];
      short8 bV1 = *(const short8*)&Vs[(16+m)*64  + swz];
      o0 = __builtin_amdgcn_mfma_f32_16x16x32_bf16(aP, bV0, o0, 0,0,0);
      o1 = __builtin_amdgcn_mfma_f32_16x16x32_bf16(aP, bV1, o1, 0,0,0);
    }
  }

  l += __shfl_xor(l, 16, 64);
  l += __shfl_xor(l, 32, 64);

  float* Ob = Op + (size_t)ks*S*256;
  #pragma unroll
  for(int r=0;r<4;r++){
    int q = qb + w*16 + g*4 + r;
    Ob[q*256 + h*32 + m]      = o0[r];
    Ob[q*256 + h*32 + 16 + m] = o1[r];
  }
  if(g==0) lp[ks*S*8 + (qb + w*16 + m)*8 + h] = l;
}

__global__ __launch_bounds__(256) void combine(const float* __restrict__ Op,
                                               const float* __restrict__ lp,
                                               unsigned short* __restrict__ aob, int S){
  int q = blockIdx.x, t = threadIdx.x;
  int h = t >> 5;
  float o = 0.f, l = 0.f;
  #pragma unroll
  for(int s=0;s<KS;s++) o += Op[(size_t)s*S*256 + q*256 + t];
  #pragma unroll
  for(int s=0;s<KS;s++) l += lp[s*S*8 + q*8 + h];
  aob[q*256 + t] = f2bf(o / l);
}

extern "C" void kernel_launch(void* const* d_in, const int* in_sizes, int n_in,
                              void* d_out, int out_size, void* d_ws, size_t ws_size,
                              hipStream_t stream) {
  const float* x   = (const float*)d_in[0];
  const int*   ei  = (const int*)d_in[1];
  const float* W0  = (const float*)d_in[2];
  const float* as0 = (const float*)d_in[3];
  const float* ad0 = (const float*)d_in[4];
  const float* b0  = (const float*)d_in[5];
  const float* W1  = (const float*)d_in[6];
  const float* as1 = (const float*)d_in[7];
  const float* ad1 = (const float*)d_in[8];
  const float* b1  = (const float*)d_in[9];
  const float* W2  = (const float*)d_in[10];
  const float* as2 = (const float*)d_in[11];
  const float* ad2 = (const float*)d_in[12];
  const float* b2  = (const float*)d_in[13];
  const float* g0  = (const float*)d_in[14];
  const float* be0 = (const float*)d_in[15];
  const float* g1  = (const float*)d_in[16];
  const float* be1 = (const float*)d_in[17];
  const float* g2  = (const float*)d_in[18];
  const float* be2 = (const float*)d_in[19];
  const float* wq  = (const float*)d_in[20];
  const float* bq  = (const float*)d_in[21];
  const float* wk  = (const float*)d_in[22];
  const float* bk  = (const float*)d_in[23];
  const float* wv  = (const float*)d_in[24];
  const float* bv  = (const float*)d_in[25];
  const float* wo  = (const float*)d_in[26];
  const float* bo  = (const float*)d_in[27];
  float* out = (float*)d_out;

  const int N = 4096;
  const int E = in_sizes[1] / 2;
  const int Etot = E + N;

  char* p = (char*)d_ws;
  auto alloc = [&](size_t bytes){ char* r = p; p += (bytes + 255) & ~(size_t)255; return r; };

  float* h0   = (float*)alloc(N*512*4);
  float* als  = (float*)alloc(N*4*4);
  float* ald  = (float*)alloc(N*4*4);
  unsigned short* xb   = (unsigned short*)alloc(N*128*2);
  unsigned short* xlb  = (unsigned short*)alloc(N*512*2);
  unsigned short* h0b  = (unsigned short*)alloc(N*512*2);
  unsigned short* h1b  = (unsigned short*)alloc(N*512*2);
  unsigned short* h2b  = (unsigned short*)alloc(N*256*2);
  unsigned short* QKVb = (unsigned short*)alloc((size_t)N*768*2);
  unsigned short* Vt   = (unsigned short*)alloc(256*N*2);
  unsigned short* aob  = (unsigned short*)alloc(N*256*2);
  unsigned short* W0t  = (unsigned short*)alloc(512*128*2);
  unsigned short* W1t  = (unsigned short*)alloc(512*512*2);
  unsigned short* W2t  = (unsigned short*)alloc(256*512*2);
  unsigned short* wqkvt= (unsigned short*)alloc(768*256*2);
  float* bqkv = (float*)alloc(768*4);
  unsigned short* wot  = (unsigned short*)alloc(256*256*2);
  unsigned short* Wsd0 = (unsigned short*)alloc(16*128*2);
  unsigned short* Wsd1 = (unsigned short*)alloc(16*512*2);
  unsigned short* Wsd2 = (unsigned short*)alloc(16*512*2);
  float* Op = (float*)alloc((size_t)KS*N*256*4);
  float* lp = (float*)alloc((size_t)KS*N*8*4);
  int* hist = (int*)alloc(N*4);
  int* wcnt = (int*)alloc(N*4);
  int* rp   = (int*)alloc((N+2)*4);
  int* col  = (int*)alloc(Etot*4);

  // ---------- prep (x conv + transposes + bqkv + Wsd) ----------
  prep<<<6017, 256, 0, stream>>>(x, xb, W0, W0t, W1, W1t, W2, W2t,
                                 wq, wk, wv, wqkvt, bq, bk, bv, bqkv, wo, wot,
                                 as0, ad0, Wsd0, as1, ad1, Wsd1, as2, ad2, Wsd2);

  // ---------- CSR build (by destination) ----------
  hipMemsetAsync(hist, 0, N*sizeof(int), stream);
  csr_count<<<(Etot+255)/256, 256, 0, stream>>>(ei, E, Etot, hist);
  csr_scan<<<1, 1024, 0, stream>>>(hist, rp, wcnt, N);
  csr_scatter<<<(Etot+255)/256, 256, 0, stream>>>(ei, E, Etot, wcnt, col);

  // ---------- GAT layer 0: 128 -> 4x128 (512) ----------
  gemm_mfma<<<dim3(8, 64), 256, 0, stream>>>(xb, W0t, nullptr, nullptr, xlb, nullptr, Wsd0, als, ald, N, 128, 512);
  gat_gather_ln<<<N, 256, 0, stream>>>(rp, col, xlb, als, ald, b0, g0, be0,
                                       nullptr, h0, h0b, 512, 7, 1);

  // ---------- GAT layer 1: 512 -> 4x128 (512), residual ----------
  gemm_mfma<<<dim3(8, 64), 256, 0, stream>>>(h0b, W1t, nullptr, nullptr, xlb, nullptr, Wsd1, als, ald, N, 512, 512);
  gat_gather_ln<<<N, 256, 0, stream>>>(rp, col, xlb, als, ald, b1, g1, be1,
                                       h0, nullptr, h1b, 512, 7, 1);

  // ---------- GAT layer 2: 512 -> 1x256, 1 head, no ELU ----------
  gemm_mfma<<<dim3(4, 64), 256, 0, stream>>>(h1b, W2t, nullptr, nullptr, xlb, nullptr, Wsd2, als, ald, N, 512, 256);
  gat_gather_ln<<<N, 128, 0, stream>>>(rp, col, xlb, als, ald, b2, g2, be2,
                                       nullptr, nullptr, h2b, 256, 8, 0);

  // ---------- dense MHA (fused QKV GEMM w/ tiled V-transpose epilogue) ----------
  gemm_mfma<<<dim3(12, 64), 256, 0, stream>>>(h2b, wqkvt, bqkv, nullptr, QKVb, Vt, nullptr, nullptr, nullptr, N, 256, 768);
  attention11<<<dim3(N/64, 8, KS), 256, 0, stream>>>(QKVb, Vt, Op, lp, N);
  combine<<<N, 256, 0, stream>>>(Op, lp, aob, N);
  gemm_mfma<<<dim3(4, 64), 256, 0, stream>>>(aob, wot, bo, out, nullptr, nullptr, nullptr, nullptr, nullptr, N, 256, 256);
}

// Round 16
// 274.906 us; speedup vs baseline: 1.3223x; 1.0082x over previous
//
#include <hip/hip_runtime.h>
#include <math.h>

typedef __attribute__((ext_vector_type(8))) short short8;
typedef __attribute__((ext_vector_type(4))) float float4v;

#define QS 0.17677669529663687f   // 1/sqrt(32), folded into wq/bq; exp via __expf

__device__ __forceinline__ float waveReduceSum(float v){
  #pragma unroll
  for(int o=32;o>0;o>>=1) v += __shfl_down(v,o,64);
  return v;
}

__device__ __forceinline__ unsigned short f2bf(float f){
  unsigned int u = __float_as_uint(f);
  return (unsigned short)((u + 0x7FFFu + ((u>>16)&1u)) >> 16);
}
__device__ __forceinline__ float bf2f(unsigned short u){
  return __uint_as_float(((unsigned int)u)<<16);
}

// ------- fused prep: x->bf16 + LDS-tiled weight transposes + qkv concat + Wsd -------
// blocks: [0,2048) x conv; 2048 bqkv; [2049,2225) 64x64 transpose tiles
// (coalesced float4 reads -> LDS -> coalesced b128 bf16 writes); [2225,3377) Wsd.
__global__ __launch_bounds__(256) void prep(const float* __restrict__ x, unsigned short* __restrict__ xb,
                     const float* __restrict__ W0, unsigned short* __restrict__ W0t,
                     const float* __restrict__ W1, unsigned short* __restrict__ W1t,
                     const float* __restrict__ W2, unsigned short* __restrict__ W2t,
                     const float* __restrict__ wq, const float* __restrict__ wk,
                     const float* __restrict__ wv, unsigned short* __restrict__ wqkvt,
                     const float* __restrict__ bq, const float* __restrict__ bk,
                     const float* __restrict__ bv, float* __restrict__ bqkv,
                     const float* __restrict__ wo, unsigned short* __restrict__ wot,
                     const float* __restrict__ as0, const float* __restrict__ ad0, unsigned short* __restrict__ S0,
                     const float* __restrict__ as1, const float* __restrict__ ad1, unsigned short* __restrict__ S1,
                     const float* __restrict__ as2, const float* __restrict__ ad2, unsigned short* __restrict__ S2){
  int b = blockIdx.x, t = threadIdx.x;
  if(b < 2048){ int i = b*256 + t; xb[i] = f2bf(x[i]); return; }
  if(b == 2048){ bqkv[t] = bq[t]*QS; bqkv[256+t] = bk[t]; bqkv[512+t] = bv[t]; return; }
  if(b < 2225){
    // ---- LDS-tiled transpose: src [K,N] fp32 -> dst [N(+roff), K] bf16 ----
    __shared__ unsigned short tile[64][65];
    int tb = b - 2049;
    const float* src; unsigned short* dst; int K,N,roff,local; float sc = 1.f;
    if(tb<16){src=W0;dst=W0t;K=128;N=512;local=tb;roff=0;}
    else if(tb<80){src=W1;dst=W1t;K=512;N=512;local=tb-16;roff=0;}
    else if(tb<112){src=W2;dst=W2t;K=512;N=256;local=tb-80;roff=0;}
    else if(tb<128){src=wq;dst=wqkvt;K=256;N=256;local=tb-112;roff=0;sc=QS;}
    else if(tb<144){src=wk;dst=wqkvt;K=256;N=256;local=tb-128;roff=256;}
    else if(tb<160){src=wv;dst=wqkvt;K=256;N=256;local=tb-144;roff=512;}
    else {src=wo;dst=wot;K=256;N=256;local=tb-160;roff=0;}
    int ntiles = N>>6;
    int k0 = (local/ntiles)*64, n0 = (local%ntiles)*64;
    int r4 = t>>4, c4 = (t&15)*4;
    #pragma unroll
    for(int it=0;it<4;it++){
      int row = r4 + it*16;
      float4 v = *(const float4*)(src + (size_t)(k0+row)*N + n0 + c4);
      tile[row][c4+0]=f2bf(v.x*sc);
      tile[row][c4+1]=f2bf(v.y*sc);
      tile[row][c4+2]=f2bf(v.z*sc);
      tile[row][c4+3]=f2bf(v.w*sc);
    }
    __syncthreads();
    int r8 = t>>3, c8 = (t&7)*8;
    #pragma unroll
    for(int it=0;it<2;it++){
      int n = r8 + it*32;
      short8 o;
      #pragma unroll
      for(int j=0;j<8;j++) o[j] = (short)tile[c8+j][n];
      *(short8*)(dst + (size_t)(n0+n+roff)*K + k0 + c8) = o;
    }
    return;
  }
  // ---- Wsd build ----
  int bb = b - 2225;
  const float *W,*as,*ad; unsigned short* S; int K,C,H,k;
  if(bb<128){W=W0;as=as0;ad=ad0;S=S0;K=128;C=128;H=4;k=bb;}
  else if(bb<640){W=W1;as=as1;ad=ad1;S=S1;K=512;C=128;H=4;k=bb-128;}
  else {W=W2;as=as2;ad=ad2;S=S2;K=512;C=256;H=1;k=bb-640;}
  int D = H*C;
  __shared__ float s1[4], s2[4];
  int lane=t&63, wid=t>>6;
  for(int h=0;h<H;h++){
    float ps=0.f, pd=0.f;
    for(int c=t;c<C;c+=256){
      float wv2 = W[k*D + h*C + c];
      ps += wv2*as[h*C+c];
      pd += wv2*ad[h*C+c];
    }
    ps = waveReduceSum(ps); pd = waveReduceSum(pd);
    if(lane==0){ s1[wid]=ps; s2[wid]=pd; }
    __syncthreads();
    if(t==0){
      float u=s1[0]+s1[1]+s1[2]+s1[3], v=s2[0]+s2[1]+s2[2]+s2[3];
      S[h*K+k]=f2bf(u); S[(4+h)*K+k]=f2bf(v);
    }
    __syncthreads();
  }
  if(t==0){
    for(int h=H;h<4;h++){ S[h*K+k]=0; S[(4+h)*K+k]=0; }
    for(int r=8;r<16;r++) S[r*K+k]=0;
  }
}

// ------- MFMA bf16 GEMM: double-buffered LDS, software-pipelined -------
// If VtT != null: output-column blocks with bn>=512 write their 64x64 tile
// TRANSPOSED to VtT[(col-512)*M+row] via an LDS-tiled epilogue.
__global__ __launch_bounds__(256) void gemm_mfma(const unsigned short* __restrict__ A,
                                                 const unsigned short* __restrict__ Bt,
                                                 const float* __restrict__ bias,
                                                 float* __restrict__ C,
                                                 unsigned short* __restrict__ Cb,
                                                 unsigned short* __restrict__ VtT,
                                                 const unsigned short* __restrict__ Wsd,
                                                 float* __restrict__ als,
                                                 float* __restrict__ ald,
                                                 int M, int K, int N){
  int t = threadIdx.x, lane = t & 63, w = t >> 6;
  int m = lane & 15, g = lane >> 4;
  int bm = blockIdx.y * 64, bn = blockIdx.x * 64;

  __shared__ unsigned short As[2][64*72];
  __shared__ unsigned short Bs[2][64*72];

  int sr = t >> 3;
  int sc = (t & 7) * 8;
  const unsigned short* Ap = A  + (bm + sr)*K + sc;
  const unsigned short* Bp = Bt + (bn + sr)*K + sc;
  bool doC = (Wsd != nullptr) && (blockIdx.x == 0);

  float4v acc[4];
  #pragma unroll
  for(int nt=0;nt<4;nt++) acc[nt] = (float4v){0.f,0.f,0.f,0.f};
  float4v acc2 = (float4v){0.f,0.f,0.f,0.f};

  short8 a0 = *(const short8*)(Ap);
  short8 a1 = *(const short8*)(Ap + 32*K);
  short8 b0 = *(const short8*)(Bp);
  short8 b1 = *(const short8*)(Bp + 32*K);

  int buf = 0;
  for(int k0=0;k0<K;k0+=64){
    *(short8*)&As[buf][sr*72 + sc]      = a0;
    *(short8*)&As[buf][(sr+32)*72 + sc] = a1;
    *(short8*)&Bs[buf][sr*72 + sc]      = b0;
    *(short8*)&Bs[buf][(sr+32)*72 + sc] = b1;
    if(k0+64 < K){
      a0 = *(const short8*)(Ap + k0+64);
      a1 = *(const short8*)(Ap + 32*K + k0+64);
      b0 = *(const short8*)(Bp + k0+64);
      b1 = *(const short8*)(Bp + 32*K + k0+64);
    }
    __syncthreads();

    #pragma unroll
    for(int ks=0;ks<2;ks++){
      short8 aA = *(const short8*)&As[buf][(w*16 + m)*72 + ks*32 + g*8];
      #pragma unroll
      for(int nt=0;nt<4;nt++){
        short8 bB = *(const short8*)&Bs[buf][(nt*16 + m)*72 + ks*32 + g*8];
        acc[nt] = __builtin_amdgcn_mfma_f32_16x16x32_bf16(aA, bB, acc[nt], 0,0,0);
      }
      if(doC){
        short8 bW = *(const short8*)(Wsd + m*K + k0 + ks*32 + g*8);
        acc2 = __builtin_amdgcn_mfma_f32_16x16x32_bf16(aA, bW, acc2, 0,0,0);
      }
    }
    buf ^= 1;
  }

  if(VtT && bn >= 512){
    __syncthreads();
    unsigned short* T = &As[0][0];
    #pragma unroll
    for(int nt=0;nt<4;nt++){
      int col = bn + nt*16 + m;
      float bv = bias ? bias[col] : 0.f;
      unsigned int r0 = __float_as_uint(acc[nt][0]+bv) + 0x8000u;
      unsigned int r1 = __float_as_uint(acc[nt][1]+bv) + 0x8000u;
      unsigned int r2 = __float_as_uint(acc[nt][2]+bv) + 0x8000u;
      unsigned int r3 = __float_as_uint(acc[nt][3]+bv) + 0x8000u;
      uint2 pk;
      pk.x = __builtin_amdgcn_perm(r1, r0, 0x07060302u);
      pk.y = __builtin_amdgcn_perm(r3, r2, 0x07060302u);
      *(uint2*)&T[(nt*16 + m)*72 + w*16 + g*4] = pk;
    }
    __syncthreads();
    int d  = t >> 2;
    int qc = (t & 3) * 16;
    short8 v0 = *(const short8*)&T[d*72 + qc];
    short8 v1 = *(const short8*)&T[d*72 + qc + 8];
    unsigned short* dst = VtT + (size_t)(bn - 512 + d)*M + bm + qc;
    *(short8*)(dst)     = v0;
    *(short8*)(dst + 8) = v1;
    return;
  }

  #pragma unroll
  for(int nt=0;nt<4;nt++){
    int col = bn + nt*16 + m;
    float bv = bias ? bias[col] : 0.f;
    #pragma unroll
    for(int r=0;r<4;r++){
      int row = bm + w*16 + g*4 + r;
      float v = acc[nt][r] + bv;
      if(C)  C[row*N + col]  = v;
      if(Cb) Cb[row*N + col] = f2bf(v);
    }
  }
  if(doC){
    #pragma unroll
    for(int r=0;r<4;r++){
      int row = bm + w*16 + g*4 + r;
      if(m<4)      als[row*4 + m]     = acc2[r];
      else if(m<8) ald[row*4 + (m-4)] = acc2[r];
    }
  }
}

// ---------------- CSR build ----------------
__global__ void csr_count(const int* __restrict__ ei, int E, int Etot,
                          int* __restrict__ hist){
  int e = blockIdx.x*256 + threadIdx.x;
  if(e>=Etot) return;
  int d = (e<E) ? (ei[E+e]&4095) : (e-E);
  atomicAdd(&hist[d], 1);
}

__global__ __launch_bounds__(1024) void csr_scan(const int* __restrict__ hist,
                                                 int* __restrict__ row_ptr,
                                                 int* __restrict__ wcnt, int N){
  __shared__ int sh[1024];
  int t = threadIdx.x;
  int base[4];
  int s = 0;
  #pragma unroll
  for(int i=0;i<4;i++){ base[i]=s; s += hist[t*4+i]; }
  sh[t] = s;
  __syncthreads();
  for(int off=1; off<1024; off<<=1){
    int x = (t>=off) ? sh[t-off] : 0;
    __syncthreads();
    sh[t] += x;
    __syncthreads();
  }
  int excl = (t==0) ? 0 : sh[t-1];
  #pragma unroll
  for(int i=0;i<4;i++){
    row_ptr[t*4+i] = excl + base[i];
    wcnt[t*4+i]    = excl + base[i];
  }
  if(t==1023) row_ptr[N] = excl + s;
}

__global__ void csr_scatter(const int* __restrict__ ei, int E, int Etot,
                            int* __restrict__ wcnt, int* __restrict__ col){
  int e = blockIdx.x*256 + threadIdx.x;
  if(e>=Etot) return;
  int s,d;
  if(e<E){ s=ei[e]&4095; d=ei[E+e]&4095; } else { s=d=e-E; }
  int pos = atomicAdd(&wcnt[d], 1);
  col[pos] = s;
}

// ------- fused GAT gather + softmax + bias + ELU + LayerNorm (+residual) -------
#define CE 128
__global__ void gat_gather_ln(const int* __restrict__ rp,
                              const int* __restrict__ col,
                              const unsigned short* __restrict__ xlb,
                              const float* __restrict__ als,
                              const float* __restrict__ ald,
                              const float* __restrict__ bias,
                              const float* __restrict__ gw,
                              const float* __restrict__ be,
                              const float* __restrict__ res,
                              float* __restrict__ out,
                              unsigned short* __restrict__ outb,
                              int D, int logC, int do_elu){
  int n = blockIdx.x, t = threadIdx.x;
  int c0 = t*2;
  int h = c0 >> logC;
  int rowW = D >> 1;
  float4 advv = *(const float4*)(ald + n*4);
  int start = rp[n], end = rp[n+1];
  const unsigned int* xw = (const unsigned int*)xlb;

  __shared__ float pw[2][CE*4];
  __shared__ int offs[2][CE];

  float acc0=0.f, acc1=0.f, den=0.f;
  int nch = (end - start + CE - 1) / CE;

  {
    int cnt = min(CE, end-start);
    if(t < cnt){
      int s = col[start+t];
      offs[0][t] = s*rowW;
      float4 av = *(const float4*)(als + s*4);
      #pragma unroll
      for(int hh=0;hh<4;hh++){
        float a = ((const float*)&av)[hh] + ((const float*)&advv)[hh];
        a = a>0.f ? a : 0.2f*a;
        pw[0][t*4+hh] = __expf(a);
      }
    }
  }

  for(int c=0;c<nch;c++){
    __syncthreads();
    if(c+1 < nch){
      int base = start + (c+1)*CE;
      int cnt = min(CE, end-base);
      int b2 = (c+1)&1;
      if(t < cnt){
        int s = col[base+t];
        offs[b2][t] = s*rowW;
        float4 av = *(const float4*)(als + s*4);
        #pragma unroll
        for(int hh=0;hh<4;hh++){
          float a = ((const float*)&av)[hh] + ((const float*)&advv)[hh];
          a = a>0.f ? a : 0.2f*a;
          pw[b2][t*4+hh] = __expf(a);
        }
      }
    }
    int base = start + c*CE;
    int cnt = min(CE, end-base);
    int b = c&1;
    #pragma unroll 8
    for(int j=0;j<cnt;j++){
      float p = pw[b][j*4+h];
      unsigned int u = xw[offs[b][j] + t];
      acc0 += p * bf2f((unsigned short)(u & 0xffffu));
      acc1 += p * bf2f((unsigned short)(u >> 16));
      den += p;
    }
  }

  float inv_d = 1.f/(den + 1e-16f);
  float v0 = acc0*inv_d + bias[c0];
  float v1 = acc1*inv_d + bias[c0+1];
  if(do_elu){
    v0 = v0>0.f ? v0 : expm1f(v0);
    v1 = v1>0.f ? v1 : expm1f(v1);
  }
  __shared__ float sh[4];
  int lane=t&63, wid=t>>6, nw = blockDim.x>>6;
  float sum = waveReduceSum(v0+v1);
  if(lane==0) sh[wid]=sum;
  __syncthreads();
  float mean = 0.f;
  for(int i=0;i<nw;i++) mean += sh[i];
  mean /= (float)D;
  __syncthreads();
  float d0 = v0-mean, d1 = v1-mean;
  float vs = waveReduceSum(d0*d0 + d1*d1);
  if(lane==0) sh[wid]=vs;
  __syncthreads();
  float var = 0.f;
  for(int i=0;i<nw;i++) var += sh[i];
  var /= (float)D;
  float inv = rsqrtf(var + 1e-5f);
  float y0 = d0*inv*gw[c0]   + be[c0];
  float y1 = d1*inv*gw[c0+1] + be[c0+1];
  if(res){ float2 rv = *(const float2*)(res + n*D + c0); y0 += rv.x; y1 += rv.y; }
  if(out) *(float2*)(out + n*D + c0) = make_float2(y0, y1);
  if(outb) ((unsigned int*)outb)[n*rowW + t] =
      (unsigned int)f2bf(y0) | ((unsigned int)f2bf(y1) << 16);
}

// --------- MFMA bf16 MHA, flash-decode + XOR-swizzled Ps/Vs ---------
#define KS 4
__global__ __launch_bounds__(256) void attention11(const unsigned short* __restrict__ QKV,
                                                   const unsigned short* __restrict__ Vt,
                                                   float* __restrict__ Op,
                                                   float* __restrict__ lp, int S){
  const int RS = 768;
  int qb = blockIdx.x * 64;
  int h  = blockIdx.y;
  int ks = blockIdx.z;
  int t  = threadIdx.x;
  int lane = t & 63, w = t >> 6;
  int m = lane & 15, g = lane >> 4;
  int m7 = m & 7;

  __shared__ unsigned short Ps[64*64];
  __shared__ unsigned short Vs[32*64];
  __shared__ unsigned short Ks[64*36];

  short8 aQ = *(const short8*)(QKV + (qb + w*16 + m)*RS + h*32 + g*8);

  float4v o0 = {0.f,0.f,0.f,0.f}, o1 = {0.f,0.f,0.f,0.f};
  float l = 0.f;

  int r8 = t>>3, c8 = t&7;
  int kr = t>>2, kc = (t&3)*8;
  int kA = ks*(S/KS), kB = kA + S/KS;

  for(int kt=kA; kt<kB; kt+=64){
    short8 v = *(const short8*)(Vt + (h*32 + r8)*S + kt + c8*8);
    short8 kv = *(const short8*)(QKV + (kt + kr)*RS + 256 + h*32 + kc);
    __syncthreads();
    *(short8*)&Vs[r8*64 + ((c8 ^ (r8&7))<<3)] = v;
    *(short8*)&Ks[kr*36 + kc] = kv;
    __syncthreads();

    #pragma unroll
    for(int nt=0;nt<4;nt++){
      short8 aK = *(const short8*)&Ks[(nt*16 + m)*36 + g*8];
      float4v acc = {0.f,0.f,0.f,0.f};
      acc = __builtin_amdgcn_mfma_f32_16x16x32_bf16(aK, aQ, acc, 0,0,0);
      float p0 = __expf(acc[0]);
      float p1 = __expf(acc[1]);
      float p2 = __expf(acc[2]);
      float p3 = __expf(acc[3]);
      l += (p0+p1) + (p2+p3);
      unsigned int r0 = __float_as_uint(p0) + 0x8000u;
      unsigned int r1 = __float_as_uint(p1) + 0x8000u;
      unsigned int r2 = __float_as_uint(p2) + 0x8000u;
      unsigned int r3 = __float_as_uint(p3) + 0x8000u;
      uint2 pk;
      pk.x = __builtin_amdgcn_perm(r1, r0, 0x07060302u);
      pk.y = __builtin_amdgcn_perm(r3, r2, 0x07060302u);
      *(uint2*)&Ps[(w*16 + m)*64 + (((2*nt + (g>>1)) ^ m7)<<3) + ((g&1)<<2)] = pk;
    }

    #pragma unroll
    for(int kh=0;kh<2;kh++){
      int swz = ((kh*4 + g) ^ m7) << 3;
      short8 aP  = *(const short8*)&Ps[(w*16 + m)*64 + swz];
      short8 bV0 = *(const short8*)&Vs[m*64       + swz];
      short8 bV1 = *(const short8*)&Vs[(16+m)*64  + swz];
      o0 = __builtin_amdgcn_mfma_f32_16x16x32_bf16(aP, bV0, o0, 0,0,0);
      o1 = __builtin_amdgcn_mfma_f32_16x16x32_bf16(aP, bV1, o1, 0,0,0);
    }
  }

  l += __shfl_xor(l, 16, 64);
  l += __shfl_xor(l, 32, 64);

  float* Ob = Op + (size_t)ks*S*256;
  #pragma unroll
  for(int r=0;r<4;r++){
    int q = qb + w*16 + g*4 + r;
    Ob[q*256 + h*32 + m]      = o0[r];
    Ob[q*256 + h*32 + 16 + m] = o1[r];
  }
  if(g==0) lp[ks*S*8 + (qb + w*16 + m)*8 + h] = l;
}

__global__ __launch_bounds__(256) void combine(const float* __restrict__ Op,
                                               const float* __restrict__ lp,
                                               unsigned short* __restrict__ aob, int S){
  int q = blockIdx.x, t = threadIdx.x;
  int h = t >> 5;
  float o = 0.f, l = 0.f;
  #pragma unroll
  for(int s=0;s<KS;s++) o += Op[(size_t)s*S*256 + q*256 + t];
  #pragma unroll
  for(int s=0;s<KS;s++) l += lp[s*S*8 + q*8 + h];
  aob[q*256 + t] = f2bf(o / l);
}

extern "C" void kernel_launch(void* const* d_in, const int* in_sizes, int n_in,
                              void* d_out, int out_size, void* d_ws, size_t ws_size,
                              hipStream_t stream) {
  const float* x   = (const float*)d_in[0];
  const int*   ei  = (const int*)d_in[1];
  const float* W0  = (const float*)d_in[2];
  const float* as0 = (const float*)d_in[3];
  const float* ad0 = (const float*)d_in[4];
  const float* b0  = (const float*)d_in[5];
  const float* W1  = (const float*)d_in[6];
  const float* as1 = (const float*)d_in[7];
  const float* ad1 = (const float*)d_in[8];
  const float* b1  = (const float*)d_in[9];
  const float* W2  = (const float*)d_in[10];
  const float* as2 = (const float*)d_in[11];
  const float* ad2 = (const float*)d_in[12];
  const float* b2  = (const float*)d_in[13];
  const float* g0  = (const float*)d_in[14];
  const float* be0 = (const float*)d_in[15];
  const float* g1  = (const float*)d_in[16];
  const float* be1 = (const float*)d_in[17];
  const float* g2  = (const float*)d_in[18];
  const float* be2 = (const float*)d_in[19];
  const float* wq  = (const float*)d_in[20];
  const float* bq  = (const float*)d_in[21];
  const float* wk  = (const float*)d_in[22];
  const float* bk  = (const float*)d_in[23];
  const float* wv  = (const float*)d_in[24];
  const float* bv  = (const float*)d_in[25];
  const float* wo  = (const float*)d_in[26];
  const float* bo  = (const float*)d_in[27];
  float* out = (float*)d_out;

  const int N = 4096;
  const int E = in_sizes[1] / 2;
  const int Etot = E + N;

  char* p = (char*)d_ws;
  auto alloc = [&](size_t bytes){ char* r = p; p += (bytes + 255) & ~(size_t)255; return r; };

  float* h0   = (float*)alloc(N*512*4);
  float* als  = (float*)alloc(N*4*4);
  float* ald  = (float*)alloc(N*4*4);
  unsigned short* xb   = (unsigned short*)alloc(N*128*2);
  unsigned short* xlb  = (unsigned short*)alloc(N*512*2);
  unsigned short* h0b  = (unsigned short*)alloc(N*512*2);
  unsigned short* h1b  = (unsigned short*)alloc(N*512*2);
  unsigned short* h2b  = (unsigned short*)alloc(N*256*2);
  unsigned short* QKVb = (unsigned short*)alloc((size_t)N*768*2);
  unsigned short* Vt   = (unsigned short*)alloc(256*N*2);
  unsigned short* aob  = (unsigned short*)alloc(N*256*2);
  unsigned short* W0t  = (unsigned short*)alloc(512*128*2);
  unsigned short* W1t  = (unsigned short*)alloc(512*512*2);
  unsigned short* W2t  = (unsigned short*)alloc(256*512*2);
  unsigned short* wqkvt= (unsigned short*)alloc(768*256*2);
  float* bqkv = (float*)alloc(768*4);
  unsigned short* wot  = (unsigned short*)alloc(256*256*2);
  unsigned short* Wsd0 = (unsigned short*)alloc(16*128*2);
  unsigned short* Wsd1 = (unsigned short*)alloc(16*512*2);
  unsigned short* Wsd2 = (unsigned short*)alloc(16*512*2);
  float* Op = (float*)alloc((size_t)KS*N*256*4);
  float* lp = (float*)alloc((size_t)KS*N*8*4);
  int* hist = (int*)alloc(N*4);
  int* wcnt = (int*)alloc(N*4);
  int* rp   = (int*)alloc((N+2)*4);
  int* col  = (int*)alloc(Etot*4);

  // ---------- prep (x conv + bqkv + tiled transposes + Wsd) ----------
  prep<<<3377, 256, 0, stream>>>(x, xb, W0, W0t, W1, W1t, W2, W2t,
                                 wq, wk, wv, wqkvt, bq, bk, bv, bqkv, wo, wot,
                                 as0, ad0, Wsd0, as1, ad1, Wsd1, as2, ad2, Wsd2);

  // ---------- CSR build (by destination) ----------
  hipMemsetAsync(hist, 0, N*sizeof(int), stream);
  csr_count<<<(Etot+255)/256, 256, 0, stream>>>(ei, E, Etot, hist);
  csr_scan<<<1, 1024, 0, stream>>>(hist, rp, wcnt, N);
  csr_scatter<<<(Etot+255)/256, 256, 0, stream>>>(ei, E, Etot, wcnt, col);

  // ---------- GAT layer 0: 128 -> 4x128 (512) ----------
  gemm_mfma<<<dim3(8, 64), 256, 0, stream>>>(xb, W0t, nullptr, nullptr, xlb, nullptr, Wsd0, als, ald, N, 128, 512);
  gat_gather_ln<<<N, 256, 0, stream>>>(rp, col, xlb, als, ald, b0, g0, be0,
                                       nullptr, h0, h0b, 512, 7, 1);

  // ---------- GAT layer 1: 512 -> 4x128 (512), residual ----------
  gemm_mfma<<<dim3(8, 64), 256, 0, stream>>>(h0b, W1t, nullptr, nullptr, xlb, nullptr, Wsd1, als, ald, N, 512, 512);
  gat_gather_ln<<<N, 256, 0, stream>>>(rp, col, xlb, als, ald, b1, g1, be1,
                                       h0, nullptr, h1b, 512, 7, 1);

  // ---------- GAT layer 2: 512 -> 1x256, 1 head, no ELU ----------
  gemm_mfma<<<dim3(4, 64), 256, 0, stream>>>(h1b, W2t, nullptr, nullptr, xlb, nullptr, Wsd2, als, ald, N, 512, 256);
  gat_gather_ln<<<N, 128, 0, stream>>>(rp, col, xlb, als, ald, b2, g2, be2,
                                       nullptr, nullptr, h2b, 256, 8, 0);

  // ---------- dense MHA (fused QKV GEMM w/ tiled V-transpose epilogue) ----------
  gemm_mfma<<<dim3(12, 64), 256, 0, stream>>>(h2b, wqkvt, bqkv, nullptr, QKVb, Vt, nullptr, nullptr, nullptr, N, 256, 768);
  attention11<<<dim3(N/64, 8, KS), 256, 0, stream>>>(QKVb, Vt, Op, lp, N);
  combine<<<N, 256, 0, stream>>>(Op, lp, aob, N);
  gemm_mfma<<<dim3(4, 64), 256, 0, stream>>>(aob, wot, bo, out, nullptr, nullptr, nullptr, nullptr, nullptr, N, 256, 256);
}

// Round 17
// 269.147 us; speedup vs baseline: 1.3506x; 1.0214x over previous
//
#include <hip/hip_runtime.h>
#include <math.h>

typedef __attribute__((ext_vector_type(8))) short short8;
typedef __attribute__((ext_vector_type(4))) float float4v;

#define QS 0.2550354f   // (1/sqrt(32)) * log2(e), folded into wq/bq; exp via raw v_exp

#if __has_builtin(__builtin_amdgcn_exp2f)
#define EXP2(x) __builtin_amdgcn_exp2f(x)
#else
#define EXP2(x) __expf((x)*0.6931471805599453f)
#endif

__device__ __forceinline__ float waveReduceSum(float v){
  #pragma unroll
  for(int o=32;o>0;o>>=1) v += __shfl_down(v,o,64);
  return v;
}

__device__ __forceinline__ unsigned short f2bf(float f){
  unsigned int u = __float_as_uint(f);
  return (unsigned short)((u + 0x7FFFu + ((u>>16)&1u)) >> 16);
}
__device__ __forceinline__ float bf2f(unsigned short u){
  return __uint_as_float(((unsigned int)u)<<16);
}

// ------- fused prep: x->bf16 + LDS-tiled transposes + qkv concat + Wsd + csr_count -------
// blocks: [0,2048) x conv; 2048 bqkv; [2049,2225) transpose tiles; [2225,3377) Wsd;
// [3377,3905) csr_count (hist must be zeroed before this kernel).
__global__ __launch_bounds__(256) void prep(const float* __restrict__ x, unsigned short* __restrict__ xb,
                     const float* __restrict__ W0, unsigned short* __restrict__ W0t,
                     const float* __restrict__ W1, unsigned short* __restrict__ W1t,
                     const float* __restrict__ W2, unsigned short* __restrict__ W2t,
                     const float* __restrict__ wq, const float* __restrict__ wk,
                     const float* __restrict__ wv, unsigned short* __restrict__ wqkvt,
                     const float* __restrict__ bq, const float* __restrict__ bk,
                     const float* __restrict__ bv, float* __restrict__ bqkv,
                     const float* __restrict__ wo, unsigned short* __restrict__ wot,
                     const float* __restrict__ as0, const float* __restrict__ ad0, unsigned short* __restrict__ S0,
                     const float* __restrict__ as1, const float* __restrict__ ad1, unsigned short* __restrict__ S1,
                     const float* __restrict__ as2, const float* __restrict__ ad2, unsigned short* __restrict__ S2,
                     const int* __restrict__ ei, int E, int Etot, int* __restrict__ hist){
  int b = blockIdx.x, t = threadIdx.x;
  if(b < 2048){ int i = b*256 + t; xb[i] = f2bf(x[i]); return; }
  if(b == 2048){ bqkv[t] = bq[t]*QS; bqkv[256+t] = bk[t]; bqkv[512+t] = bv[t]; return; }
  if(b < 2225){
    // ---- LDS-tiled transpose: src [K,N] fp32 -> dst [N(+roff), K] bf16 ----
    __shared__ unsigned short tile[64][65];
    int tb = b - 2049;
    const float* src; unsigned short* dst; int K,N,roff,local; float sc = 1.f;
    if(tb<16){src=W0;dst=W0t;K=128;N=512;local=tb;roff=0;}
    else if(tb<80){src=W1;dst=W1t;K=512;N=512;local=tb-16;roff=0;}
    else if(tb<112){src=W2;dst=W2t;K=512;N=256;local=tb-80;roff=0;}
    else if(tb<128){src=wq;dst=wqkvt;K=256;N=256;local=tb-112;roff=0;sc=QS;}
    else if(tb<144){src=wk;dst=wqkvt;K=256;N=256;local=tb-128;roff=256;}
    else if(tb<160){src=wv;dst=wqkvt;K=256;N=256;local=tb-144;roff=512;}
    else {src=wo;dst=wot;K=256;N=256;local=tb-160;roff=0;}
    int ntiles = N>>6;
    int k0 = (local/ntiles)*64, n0 = (local%ntiles)*64;
    int r4 = t>>4, c4 = (t&15)*4;
    #pragma unroll
    for(int it=0;it<4;it++){
      int row = r4 + it*16;
      float4 v = *(const float4*)(src + (size_t)(k0+row)*N + n0 + c4);
      tile[row][c4+0]=f2bf(v.x*sc);
      tile[row][c4+1]=f2bf(v.y*sc);
      tile[row][c4+2]=f2bf(v.z*sc);
      tile[row][c4+3]=f2bf(v.w*sc);
    }
    __syncthreads();
    int r8 = t>>3, c8 = (t&7)*8;
    #pragma unroll
    for(int it=0;it<2;it++){
      int n = r8 + it*32;
      short8 o;
      #pragma unroll
      for(int j=0;j<8;j++) o[j] = (short)tile[c8+j][n];
      *(short8*)(dst + (size_t)(n0+n+roff)*K + k0 + c8) = o;
    }
    return;
  }
  if(b >= 3377){
    // ---- csr_count ----
    int e = (b-3377)*256 + t;
    if(e < Etot){
      int d = (e<E) ? (ei[E+e]&4095) : (e-E);
      atomicAdd(&hist[d], 1);
    }
    return;
  }
  // ---- Wsd build ----
  int bb = b - 2225;
  const float *W,*as,*ad; unsigned short* S; int K,C,H,k;
  if(bb<128){W=W0;as=as0;ad=ad0;S=S0;K=128;C=128;H=4;k=bb;}
  else if(bb<640){W=W1;as=as1;ad=ad1;S=S1;K=512;C=128;H=4;k=bb-128;}
  else {W=W2;as=as2;ad=ad2;S=S2;K=512;C=256;H=1;k=bb-640;}
  int D = H*C;
  __shared__ float s1[4], s2[4];
  int lane=t&63, wid=t>>6;
  for(int h=0;h<H;h++){
    float ps=0.f, pd=0.f;
    for(int c=t;c<C;c+=256){
      float wv2 = W[k*D + h*C + c];
      ps += wv2*as[h*C+c];
      pd += wv2*ad[h*C+c];
    }
    ps = waveReduceSum(ps); pd = waveReduceSum(pd);
    if(lane==0){ s1[wid]=ps; s2[wid]=pd; }
    __syncthreads();
    if(t==0){
      float u=s1[0]+s1[1]+s1[2]+s1[3], v=s2[0]+s2[1]+s2[2]+s2[3];
      S[h*K+k]=f2bf(u); S[(4+h)*K+k]=f2bf(v);
    }
    __syncthreads();
  }
  if(t==0){
    for(int h=H;h<4;h++){ S[h*K+k]=0; S[(4+h)*K+k]=0; }
    for(int r=8;r<16;r++) S[r*K+k]=0;
  }
}

// ------- MFMA bf16 GEMM: double-buffered LDS, software-pipelined -------
__global__ __launch_bounds__(256) void gemm_mfma(const unsigned short* __restrict__ A,
                                                 const unsigned short* __restrict__ Bt,
                                                 const float* __restrict__ bias,
                                                 float* __restrict__ C,
                                                 unsigned short* __restrict__ Cb,
                                                 unsigned short* __restrict__ VtT,
                                                 const unsigned short* __restrict__ Wsd,
                                                 float* __restrict__ als,
                                                 float* __restrict__ ald,
                                                 int M, int K, int N){
  int t = threadIdx.x, lane = t & 63, w = t >> 6;
  int m = lane & 15, g = lane >> 4;
  int bm = blockIdx.y * 64, bn = blockIdx.x * 64;

  __shared__ unsigned short As[2][64*72];
  __shared__ unsigned short Bs[2][64*72];

  int sr = t >> 3;
  int sc = (t & 7) * 8;
  const unsigned short* Ap = A  + (bm + sr)*K + sc;
  const unsigned short* Bp = Bt + (bn + sr)*K + sc;
  bool doC = (Wsd != nullptr) && (blockIdx.x == 0);

  float4v acc[4];
  #pragma unroll
  for(int nt=0;nt<4;nt++) acc[nt] = (float4v){0.f,0.f,0.f,0.f};
  float4v acc2 = (float4v){0.f,0.f,0.f,0.f};

  short8 a0 = *(const short8*)(Ap);
  short8 a1 = *(const short8*)(Ap + 32*K);
  short8 b0 = *(const short8*)(Bp);
  short8 b1 = *(const short8*)(Bp + 32*K);

  int buf = 0;
  for(int k0=0;k0<K;k0+=64){
    *(short8*)&As[buf][sr*72 + sc]      = a0;
    *(short8*)&As[buf][(sr+32)*72 + sc] = a1;
    *(short8*)&Bs[buf][sr*72 + sc]      = b0;
    *(short8*)&Bs[buf][(sr+32)*72 + sc] = b1;
    if(k0+64 < K){
      a0 = *(const short8*)(Ap + k0+64);
      a1 = *(const short8*)(Ap + 32*K + k0+64);
      b0 = *(const short8*)(Bp + k0+64);
      b1 = *(const short8*)(Bp + 32*K + k0+64);
    }
    __syncthreads();

    #pragma unroll
    for(int ks=0;ks<2;ks++){
      short8 aA = *(const short8*)&As[buf][(w*16 + m)*72 + ks*32 + g*8];
      #pragma unroll
      for(int nt=0;nt<4;nt++){
        short8 bB = *(const short8*)&Bs[buf][(nt*16 + m)*72 + ks*32 + g*8];
        acc[nt] = __builtin_amdgcn_mfma_f32_16x16x32_bf16(aA, bB, acc[nt], 0,0,0);
      }
      if(doC){
        short8 bW = *(const short8*)(Wsd + m*K + k0 + ks*32 + g*8);
        acc2 = __builtin_amdgcn_mfma_f32_16x16x32_bf16(aA, bW, acc2, 0,0,0);
      }
    }
    buf ^= 1;
  }

  if(VtT && bn >= 512){
    __syncthreads();
    unsigned short* T = &As[0][0];
    #pragma unroll
    for(int nt=0;nt<4;nt++){
      int col = bn + nt*16 + m;
      float bv = bias ? bias[col] : 0.f;
      unsigned int r0 = __float_as_uint(acc[nt][0]+bv) + 0x8000u;
      unsigned int r1 = __float_as_uint(acc[nt][1]+bv) + 0x8000u;
      unsigned int r2 = __float_as_uint(acc[nt][2]+bv) + 0x8000u;
      unsigned int r3 = __float_as_uint(acc[nt][3]+bv) + 0x8000u;
      uint2 pk;
      pk.x = __builtin_amdgcn_perm(r1, r0, 0x07060302u);
      pk.y = __builtin_amdgcn_perm(r3, r2, 0x07060302u);
      *(uint2*)&T[(nt*16 + m)*72 + w*16 + g*4] = pk;
    }
    __syncthreads();
    int d  = t >> 2;
    int qc = (t & 3) * 16;
    short8 v0 = *(const short8*)&T[d*72 + qc];
    short8 v1 = *(const short8*)&T[d*72 + qc + 8];
    unsigned short* dst = VtT + (size_t)(bn - 512 + d)*M + bm + qc;
    *(short8*)(dst)     = v0;
    *(short8*)(dst + 8) = v1;
    return;
  }

  #pragma unroll
  for(int nt=0;nt<4;nt++){
    int col = bn + nt*16 + m;
    float bv = bias ? bias[col] : 0.f;
    #pragma unroll
    for(int r=0;r<4;r++){
      int row = bm + w*16 + g*4 + r;
      float v = acc[nt][r] + bv;
      if(C)  C[row*N + col]  = v;
      if(Cb) Cb[row*N + col] = f2bf(v);
    }
  }
  if(doC){
    #pragma unroll
    for(int r=0;r<4;r++){
      int row = bm + w*16 + g*4 + r;
      if(m<4)      als[row*4 + m]     = acc2[r];
      else if(m<8) ald[row*4 + (m-4)] = acc2[r];
    }
  }
}

// ---------------- CSR scan / scatter ----------------
__global__ __launch_bounds__(1024) void csr_scan(const int* __restrict__ hist,
                                                 int* __restrict__ row_ptr,
                                                 int* __restrict__ wcnt, int N){
  __shared__ int sh[1024];
  int t = threadIdx.x;
  int base[4];
  int s = 0;
  #pragma unroll
  for(int i=0;i<4;i++){ base[i]=s; s += hist[t*4+i]; }
  sh[t] = s;
  __syncthreads();
  for(int off=1; off<1024; off<<=1){
    int x = (t>=off) ? sh[t-off] : 0;
    __syncthreads();
    sh[t] += x;
    __syncthreads();
  }
  int excl = (t==0) ? 0 : sh[t-1];
  #pragma unroll
  for(int i=0;i<4;i++){
    row_ptr[t*4+i] = excl + base[i];
    wcnt[t*4+i]    = excl + base[i];
  }
  if(t==1023) row_ptr[N] = excl + s;
}

__global__ void csr_scatter(const int* __restrict__ ei, int E, int Etot,
                            int* __restrict__ wcnt, int* __restrict__ col){
  int e = blockIdx.x*256 + threadIdx.x;
  if(e>=Etot) return;
  int s,d;
  if(e<E){ s=ei[e]&4095; d=ei[E+e]&4095; } else { s=d=e-E; }
  int pos = atomicAdd(&wcnt[d], 1);
  col[pos] = s;
}

// ------- fused GAT gather + softmax + bias + ELU + LayerNorm (+residual) -------
#define CE 128
__global__ void gat_gather_ln(const int* __restrict__ rp,
                              const int* __restrict__ col,
                              const unsigned short* __restrict__ xlb,
                              const float* __restrict__ als,
                              const float* __restrict__ ald,
                              const float* __restrict__ bias,
                              const float* __restrict__ gw,
                              const float* __restrict__ be,
                              const float* __restrict__ res,
                              float* __restrict__ out,
                              unsigned short* __restrict__ outb,
                              int D, int logC, int do_elu){
  int n = blockIdx.x, t = threadIdx.x;
  int c0 = t*2;
  int h = c0 >> logC;
  int rowW = D >> 1;
  float4 advv = *(const float4*)(ald + n*4);
  int start = rp[n], end = rp[n+1];
  const unsigned int* xw = (const unsigned int*)xlb;

  __shared__ float pw[2][CE*4];
  __shared__ int offs[2][CE];

  float acc0=0.f, acc1=0.f, den=0.f;
  int nch = (end - start + CE - 1) / CE;

  {
    int cnt = min(CE, end-start);
    if(t < cnt){
      int s = col[start+t];
      offs[0][t] = s*rowW;
      float4 av = *(const float4*)(als + s*4);
      #pragma unroll
      for(int hh=0;hh<4;hh++){
        float a = ((const float*)&av)[hh] + ((const float*)&advv)[hh];
        a = a>0.f ? a : 0.2f*a;
        pw[0][t*4+hh] = __expf(a);
      }
    }
  }

  for(int c=0;c<nch;c++){
    __syncthreads();
    if(c+1 < nch){
      int base = start + (c+1)*CE;
      int cnt = min(CE, end-base);
      int b2 = (c+1)&1;
      if(t < cnt){
        int s = col[base+t];
        offs[b2][t] = s*rowW;
        float4 av = *(const float4*)(als + s*4);
        #pragma unroll
        for(int hh=0;hh<4;hh++){
          float a = ((const float*)&av)[hh] + ((const float*)&advv)[hh];
          a = a>0.f ? a : 0.2f*a;
          pw[b2][t*4+hh] = __expf(a);
        }
      }
    }
    int base = start + c*CE;
    int cnt = min(CE, end-base);
    int b = c&1;
    #pragma unroll 8
    for(int j=0;j<cnt;j++){
      float p = pw[b][j*4+h];
      unsigned int u = xw[offs[b][j] + t];
      acc0 += p * bf2f((unsigned short)(u & 0xffffu));
      acc1 += p * bf2f((unsigned short)(u >> 16));
      den += p;
    }
  }

  float inv_d = 1.f/(den + 1e-16f);
  float v0 = acc0*inv_d + bias[c0];
  float v1 = acc1*inv_d + bias[c0+1];
  if(do_elu){
    v0 = v0>0.f ? v0 : expm1f(v0);
    v1 = v1>0.f ? v1 : expm1f(v1);
  }
  __shared__ float sh[4];
  int lane=t&63, wid=t>>6, nw = blockDim.x>>6;
  float sum = waveReduceSum(v0+v1);
  if(lane==0) sh[wid]=sum;
  __syncthreads();
  float mean = 0.f;
  for(int i=0;i<nw;i++) mean += sh[i];
  mean /= (float)D;
  __syncthreads();
  float d0 = v0-mean, d1 = v1-mean;
  float vs = waveReduceSum(d0*d0 + d1*d1);
  if(lane==0) sh[wid]=vs;
  __syncthreads();
  float var = 0.f;
  for(int i=0;i<nw;i++) var += sh[i];
  var /= (float)D;
  float inv = rsqrtf(var + 1e-5f);
  float y0 = d0*inv*gw[c0]   + be[c0];
  float y1 = d1*inv*gw[c0+1] + be[c0+1];
  if(res){ float2 rv = *(const float2*)(res + n*D + c0); y0 += rv.x; y1 += rv.y; }
  if(out) *(float2*)(out + n*D + c0) = make_float2(y0, y1);
  if(outb) ((unsigned int*)outb)[n*rowW + t] =
      (unsigned int)f2bf(y0) | ((unsigned int)f2bf(y1) << 16);
}

// --------- MFMA bf16 MHA: raw v_exp (log2e folded into Q), l via ones-MFMA ---------
#define KS 4
__global__ __launch_bounds__(256) void attention12(const unsigned short* __restrict__ QKV,
                                                   const unsigned short* __restrict__ Vt,
                                                   float* __restrict__ Op,
                                                   float* __restrict__ lp, int S){
  const int RS = 768;
  int qb = blockIdx.x * 64;
  int h  = blockIdx.y;
  int ks = blockIdx.z;
  int t  = threadIdx.x;
  int lane = t & 63, w = t >> 6;
  int m = lane & 15, g = lane >> 4;
  int m7 = m & 7;

  __shared__ unsigned short Ps[64*64];
  __shared__ unsigned short Vs[32*64];
  __shared__ unsigned short Ks[64*36];

  short8 aQ = *(const short8*)(QKV + (qb + w*16 + m)*RS + h*32 + g*8);
  short8 vones;
  #pragma unroll
  for(int j=0;j<8;j++) vones[j] = (short)0x3F80;   // bf16 1.0

  float4v o0 = {0.f,0.f,0.f,0.f}, o1 = {0.f,0.f,0.f,0.f};
  float4v lacc = {0.f,0.f,0.f,0.f};

  int r8 = t>>3, c8 = t&7;
  int kr = t>>2, kc = (t&3)*8;
  int kA = ks*(S/KS), kB = kA + S/KS;

  for(int kt=kA; kt<kB; kt+=64){
    short8 v = *(const short8*)(Vt + (h*32 + r8)*S + kt + c8*8);
    short8 kv = *(const short8*)(QKV + (kt + kr)*RS + 256 + h*32 + kc);
    __syncthreads();
    *(short8*)&Vs[r8*64 + ((c8 ^ (r8&7))<<3)] = v;
    *(short8*)&Ks[kr*36 + kc] = kv;
    __syncthreads();

    #pragma unroll
    for(int nt=0;nt<4;nt++){
      short8 aK = *(const short8*)&Ks[(nt*16 + m)*36 + g*8];
      float4v acc = {0.f,0.f,0.f,0.f};
      acc = __builtin_amdgcn_mfma_f32_16x16x32_bf16(aK, aQ, acc, 0,0,0);
      float p0 = EXP2(acc[0]);
      float p1 = EXP2(acc[1]);
      float p2 = EXP2(acc[2]);
      float p3 = EXP2(acc[3]);
      unsigned int r0 = __float_as_uint(p0) + 0x8000u;
      unsigned int r1 = __float_as_uint(p1) + 0x8000u;
      unsigned int r2 = __float_as_uint(p2) + 0x8000u;
      unsigned int r3 = __float_as_uint(p3) + 0x8000u;
      uint2 pk;
      pk.x = __builtin_amdgcn_perm(r1, r0, 0x07060302u);
      pk.y = __builtin_amdgcn_perm(r3, r2, 0x07060302u);
      *(uint2*)&Ps[(w*16 + m)*64 + (((2*nt + (g>>1)) ^ m7)<<3) + ((g&1)<<2)] = pk;
    }

    #pragma unroll
    for(int kh=0;kh<2;kh++){
      int swz = ((kh*4 + g) ^ m7) << 3;
      short8 aP  = *(const short8*)&Ps[(w*16 + m)*64 + swz];
      short8 bV0 = *(const short8*)&Vs[m*64       + swz];
      short8 bV1 = *(const short8*)&Vs[(16+m)*64  + swz];
      o0 = __builtin_amdgcn_mfma_f32_16x16x32_bf16(aP, bV0, o0, 0,0,0);
      o1 = __builtin_amdgcn_mfma_f32_16x16x32_bf16(aP, bV1, o1, 0,0,0);
      lacc = __builtin_amdgcn_mfma_f32_16x16x32_bf16(aP, vones, lacc, 0,0,0);
    }
  }

  float* Ob = Op + (size_t)ks*S*256;
  #pragma unroll
  for(int r=0;r<4;r++){
    int q = qb + w*16 + g*4 + r;
    Ob[q*256 + h*32 + m]      = o0[r];
    Ob[q*256 + h*32 + 16 + m] = o1[r];
  }
  if(m==0){
    #pragma unroll
    for(int r=0;r<4;r++){
      int q = qb + w*16 + g*4 + r;
      lp[ks*S*8 + q*8 + h] = lacc[r];
    }
  }
}

__global__ __launch_bounds__(256) void combine(const float* __restrict__ Op,
                                               const float* __restrict__ lp,
                                               unsigned short* __restrict__ aob, int S){
  int q = blockIdx.x, t = threadIdx.x;
  int h = t >> 5;
  float o = 0.f, l = 0.f;
  #pragma unroll
  for(int s=0;s<KS;s++) o += Op[(size_t)s*S*256 + q*256 + t];
  #pragma unroll
  for(int s=0;s<KS;s++) l += lp[s*S*8 + q*8 + h];
  aob[q*256 + t] = f2bf(o / l);
}

extern "C" void kernel_launch(void* const* d_in, const int* in_sizes, int n_in,
                              void* d_out, int out_size, void* d_ws, size_t ws_size,
                              hipStream_t stream) {
  const float* x   = (const float*)d_in[0];
  const int*   ei  = (const int*)d_in[1];
  const float* W0  = (const float*)d_in[2];
  const float* as0 = (const float*)d_in[3];
  const float* ad0 = (const float*)d_in[4];
  const float* b0  = (const float*)d_in[5];
  const float* W1  = (const float*)d_in[6];
  const float* as1 = (const float*)d_in[7];
  const float* ad1 = (const float*)d_in[8];
  const float* b1  = (const float*)d_in[9];
  const float* W2  = (const float*)d_in[10];
  const float* as2 = (const float*)d_in[11];
  const float* ad2 = (const float*)d_in[12];
  const float* b2  = (const float*)d_in[13];
  const float* g0  = (const float*)d_in[14];
  const float* be0 = (const float*)d_in[15];
  const float* g1  = (const float*)d_in[16];
  const float* be1 = (const float*)d_in[17];
  const float* g2  = (const float*)d_in[18];
  const float* be2 = (const float*)d_in[19];
  const float* wq  = (const float*)d_in[20];
  const float* bq  = (const float*)d_in[21];
  const float* wk  = (const float*)d_in[22];
  const float* bk  = (const float*)d_in[23];
  const float* wv  = (const float*)d_in[24];
  const float* bv  = (const float*)d_in[25];
  const float* wo  = (const float*)d_in[26];
  const float* bo  = (const float*)d_in[27];
  float* out = (float*)d_out;

  const int N = 4096;
  const int E = in_sizes[1] / 2;
  const int Etot = E + N;

  char* p = (char*)d_ws;
  auto alloc = [&](size_t bytes){ char* r = p; p += (bytes + 255) & ~(size_t)255; return r; };

  float* h0   = (float*)alloc(N*512*4);
  float* als  = (float*)alloc(N*4*4);
  float* ald  = (float*)alloc(N*4*4);
  unsigned short* xb   = (unsigned short*)alloc(N*128*2);
  unsigned short* xlb  = (unsigned short*)alloc(N*512*2);
  unsigned short* h0b  = (unsigned short*)alloc(N*512*2);
  unsigned short* h1b  = (unsigned short*)alloc(N*512*2);
  unsigned short* h2b  = (unsigned short*)alloc(N*256*2);
  unsigned short* QKVb = (unsigned short*)alloc((size_t)N*768*2);
  unsigned short* Vt   = (unsigned short*)alloc(256*N*2);
  unsigned short* aob  = (unsigned short*)alloc(N*256*2);
  unsigned short* W0t  = (unsigned short*)alloc(512*128*2);
  unsigned short* W1t  = (unsigned short*)alloc(512*512*2);
  unsigned short* W2t  = (unsigned short*)alloc(256*512*2);
  unsigned short* wqkvt= (unsigned short*)alloc(768*256*2);
  float* bqkv = (float*)alloc(768*4);
  unsigned short* wot  = (unsigned short*)alloc(256*256*2);
  unsigned short* Wsd0 = (unsigned short*)alloc(16*128*2);
  unsigned short* Wsd1 = (unsigned short*)alloc(16*512*2);
  unsigned short* Wsd2 = (unsigned short*)alloc(16*512*2);
  float* Op = (float*)alloc((size_t)KS*N*256*4);
  float* lp = (float*)alloc((size_t)KS*N*8*4);
  int* hist = (int*)alloc(N*4);
  int* wcnt = (int*)alloc(N*4);
  int* rp   = (int*)alloc((N+2)*4);
  int* col  = (int*)alloc(Etot*4);

  // ---------- prep (x conv + bqkv + tiled transposes + Wsd + csr_count) ----------
  hipMemsetAsync(hist, 0, N*sizeof(int), stream);
  prep<<<3377 + (Etot+255)/256, 256, 0, stream>>>(x, xb, W0, W0t, W1, W1t, W2, W2t,
                                 wq, wk, wv, wqkvt, bq, bk, bv, bqkv, wo, wot,
                                 as0, ad0, Wsd0, as1, ad1, Wsd1, as2, ad2, Wsd2,
                                 ei, E, Etot, hist);

  // ---------- CSR scan + scatter ----------
  csr_scan<<<1, 1024, 0, stream>>>(hist, rp, wcnt, N);
  csr_scatter<<<(Etot+255)/256, 256, 0, stream>>>(ei, E, Etot, wcnt, col);

  // ---------- GAT layer 0: 128 -> 4x128 (512) ----------
  gemm_mfma<<<dim3(8, 64), 256, 0, stream>>>(xb, W0t, nullptr, nullptr, xlb, nullptr, Wsd0, als, ald, N, 128, 512);
  gat_gather_ln<<<N, 256, 0, stream>>>(rp, col, xlb, als, ald, b0, g0, be0,
                                       nullptr, h0, h0b, 512, 7, 1);

  // ---------- GAT layer 1: 512 -> 4x128 (512), residual ----------
  gemm_mfma<<<dim3(8, 64), 256, 0, stream>>>(h0b, W1t, nullptr, nullptr, xlb, nullptr, Wsd1, als, ald, N, 512, 512);
  gat_gather_ln<<<N, 256, 0, stream>>>(rp, col, xlb, als, ald, b1, g1, be1,
                                       h0, nullptr, h1b, 512, 7, 1);

  // ---------- GAT layer 2: 512 -> 1x256, 1 head, no ELU ----------
  gemm_mfma<<<dim3(4, 64), 256, 0, stream>>>(h1b, W2t, nullptr, nullptr, xlb, nullptr, Wsd2, als, ald, N, 512, 256);
  gat_gather_ln<<<N, 128, 0, stream>>>(rp, col, xlb, als, ald, b2, g2, be2,
                                       nullptr, nullptr, h2b, 256, 8, 0);

  // ---------- dense MHA (fused QKV GEMM w/ tiled V-transpose epilogue) ----------
  gemm_mfma<<<dim3(12, 64), 256, 0, stream>>>(h2b, wqkvt, bqkv, nullptr, QKVb, Vt, nullptr, nullptr, nullptr, N, 256, 768);
  attention12<<<dim3(N/64, 8, KS), 256, 0, stream>>>(QKVb, Vt, Op, lp, N);
  combine<<<N, 256, 0, stream>>>(Op, lp, aob, N);
  gemm_mfma<<<dim3(4, 64), 256, 0, stream>>>(aob, wot, bo, out, nullptr, nullptr, nullptr, nullptr, nullptr, N, 256, 256);
}

// Round 18
// 266.222 us; speedup vs baseline: 1.3654x; 1.0110x over previous
//
#include <hip/hip_runtime.h>
#include <math.h>

typedef __attribute__((ext_vector_type(8))) short short8;
typedef __attribute__((ext_vector_type(4))) float float4v;

#define QS 0.2550354f   // (1/sqrt(32)) * log2(e), folded into wq/bq; exp via raw v_exp

#if __has_builtin(__builtin_amdgcn_exp2f)
#define EXP2(x) __builtin_amdgcn_exp2f(x)
#else
#define EXP2(x) __expf((x)*0.6931471805599453f)
#endif

__device__ __forceinline__ float waveReduceSum(float v){
  #pragma unroll
  for(int o=32;o>0;o>>=1) v += __shfl_down(v,o,64);
  return v;
}

__device__ __forceinline__ unsigned short f2bf(float f){
  unsigned int u = __float_as_uint(f);
  return (unsigned short)((u + 0x7FFFu + ((u>>16)&1u)) >> 16);
}
__device__ __forceinline__ float bf2f(unsigned short u){
  return __uint_as_float(((unsigned int)u)<<16);
}

// ------- fused prep: x->bf16 + LDS-tiled transposes + qkv concat + Wsd + csr_count -------
__global__ __launch_bounds__(256) void prep(const float* __restrict__ x, unsigned short* __restrict__ xb,
                     const float* __restrict__ W0, unsigned short* __restrict__ W0t,
                     const float* __restrict__ W1, unsigned short* __restrict__ W1t,
                     const float* __restrict__ W2, unsigned short* __restrict__ W2t,
                     const float* __restrict__ wq, const float* __restrict__ wk,
                     const float* __restrict__ wv, unsigned short* __restrict__ wqkvt,
                     const float* __restrict__ bq, const float* __restrict__ bk,
                     const float* __restrict__ bv, float* __restrict__ bqkv,
                     const float* __restrict__ wo, unsigned short* __restrict__ wot,
                     const float* __restrict__ as0, const float* __restrict__ ad0, unsigned short* __restrict__ S0,
                     const float* __restrict__ as1, const float* __restrict__ ad1, unsigned short* __restrict__ S1,
                     const float* __restrict__ as2, const float* __restrict__ ad2, unsigned short* __restrict__ S2,
                     const int* __restrict__ ei, int E, int Etot, int* __restrict__ hist){
  int b = blockIdx.x, t = threadIdx.x;
  if(b < 2048){ int i = b*256 + t; xb[i] = f2bf(x[i]); return; }
  if(b == 2048){ bqkv[t] = bq[t]*QS; bqkv[256+t] = bk[t]; bqkv[512+t] = bv[t]; return; }
  if(b < 2225){
    __shared__ unsigned short tile[64][65];
    int tb = b - 2049;
    const float* src; unsigned short* dst; int K,N,roff,local; float sc = 1.f;
    if(tb<16){src=W0;dst=W0t;K=128;N=512;local=tb;roff=0;}
    else if(tb<80){src=W1;dst=W1t;K=512;N=512;local=tb-16;roff=0;}
    else if(tb<112){src=W2;dst=W2t;K=512;N=256;local=tb-80;roff=0;}
    else if(tb<128){src=wq;dst=wqkvt;K=256;N=256;local=tb-112;roff=0;sc=QS;}
    else if(tb<144){src=wk;dst=wqkvt;K=256;N=256;local=tb-128;roff=256;}
    else if(tb<160){src=wv;dst=wqkvt;K=256;N=256;local=tb-144;roff=512;}
    else {src=wo;dst=wot;K=256;N=256;local=tb-160;roff=0;}
    int ntiles = N>>6;
    int k0 = (local/ntiles)*64, n0 = (local%ntiles)*64;
    int r4 = t>>4, c4 = (t&15)*4;
    #pragma unroll
    for(int it=0;it<4;it++){
      int row = r4 + it*16;
      float4 v = *(const float4*)(src + (size_t)(k0+row)*N + n0 + c4);
      tile[row][c4+0]=f2bf(v.x*sc);
      tile[row][c4+1]=f2bf(v.y*sc);
      tile[row][c4+2]=f2bf(v.z*sc);
      tile[row][c4+3]=f2bf(v.w*sc);
    }
    __syncthreads();
    int r8 = t>>3, c8 = (t&7)*8;
    #pragma unroll
    for(int it=0;it<2;it++){
      int n = r8 + it*32;
      short8 o;
      #pragma unroll
      for(int j=0;j<8;j++) o[j] = (short)tile[c8+j][n];
      *(short8*)(dst + (size_t)(n0+n+roff)*K + k0 + c8) = o;
    }
    return;
  }
  if(b >= 3377){
    int e = (b-3377)*256 + t;
    if(e < Etot){
      int d = (e<E) ? (ei[E+e]&4095) : (e-E);
      atomicAdd(&hist[d], 1);
    }
    return;
  }
  // ---- Wsd build ----
  int bb = b - 2225;
  const float *W,*as,*ad; unsigned short* S; int K,C,H,k;
  if(bb<128){W=W0;as=as0;ad=ad0;S=S0;K=128;C=128;H=4;k=bb;}
  else if(bb<640){W=W1;as=as1;ad=ad1;S=S1;K=512;C=128;H=4;k=bb-128;}
  else {W=W2;as=as2;ad=ad2;S=S2;K=512;C=256;H=1;k=bb-640;}
  int D = H*C;
  __shared__ float s1[4], s2[4];
  int lane=t&63, wid=t>>6;
  for(int h=0;h<H;h++){
    float ps=0.f, pd=0.f;
    for(int c=t;c<C;c+=256){
      float wv2 = W[k*D + h*C + c];
      ps += wv2*as[h*C+c];
      pd += wv2*ad[h*C+c];
    }
    ps = waveReduceSum(ps); pd = waveReduceSum(pd);
    if(lane==0){ s1[wid]=ps; s2[wid]=pd; }
    __syncthreads();
    if(t==0){
      float u=s1[0]+s1[1]+s1[2]+s1[3], v=s2[0]+s2[1]+s2[2]+s2[3];
      S[h*K+k]=f2bf(u); S[(4+h)*K+k]=f2bf(v);
    }
    __syncthreads();
  }
  if(t==0){
    for(int h=H;h<4;h++){ S[h*K+k]=0; S[(4+h)*K+k]=0; }
    for(int r=8;r<16;r++) S[r*K+k]=0;
  }
}

// ------- MFMA bf16 GEMM: double-buffered LDS, software-pipelined -------
__global__ __launch_bounds__(256) void gemm_mfma(const unsigned short* __restrict__ A,
                                                 const unsigned short* __restrict__ Bt,
                                                 const float* __restrict__ bias,
                                                 float* __restrict__ C,
                                                 unsigned short* __restrict__ Cb,
                                                 unsigned short* __restrict__ VtT,
                                                 const unsigned short* __restrict__ Wsd,
                                                 float* __restrict__ als,
                                                 float* __restrict__ ald,
                                                 int M, int K, int N){
  int t = threadIdx.x, lane = t & 63, w = t >> 6;
  int m = lane & 15, g = lane >> 4;
  int bm = blockIdx.y * 64, bn = blockIdx.x * 64;

  __shared__ unsigned short As[2][64*72];
  __shared__ unsigned short Bs[2][64*72];

  int sr = t >> 3;
  int sc = (t & 7) * 8;
  const unsigned short* Ap = A  + (bm + sr)*K + sc;
  const unsigned short* Bp = Bt + (bn + sr)*K + sc;
  bool doC = (Wsd != nullptr) && (blockIdx.x == 0);

  float4v acc[4];
  #pragma unroll
  for(int nt=0;nt<4;nt++) acc[nt] = (float4v){0.f,0.f,0.f,0.f};
  float4v acc2 = (float4v){0.f,0.f,0.f,0.f};

  short8 a0 = *(const short8*)(Ap);
  short8 a1 = *(const short8*)(Ap + 32*K);
  short8 b0 = *(const short8*)(Bp);
  short8 b1 = *(const short8*)(Bp + 32*K);

  int buf = 0;
  for(int k0=0;k0<K;k0+=64){
    *(short8*)&As[buf][sr*72 + sc]      = a0;
    *(short8*)&As[buf][(sr+32)*72 + sc] = a1;
    *(short8*)&Bs[buf][sr*72 + sc]      = b0;
    *(short8*)&Bs[buf][(sr+32)*72 + sc] = b1;
    if(k0+64 < K){
      a0 = *(const short8*)(Ap + k0+64);
      a1 = *(const short8*)(Ap + 32*K + k0+64);
      b0 = *(const short8*)(Bp + k0+64);
      b1 = *(const short8*)(Bp + 32*K + k0+64);
    }
    __syncthreads();

    #pragma unroll
    for(int ks=0;ks<2;ks++){
      short8 aA = *(const short8*)&As[buf][(w*16 + m)*72 + ks*32 + g*8];
      #pragma unroll
      for(int nt=0;nt<4;nt++){
        short8 bB = *(const short8*)&Bs[buf][(nt*16 + m)*72 + ks*32 + g*8];
        acc[nt] = __builtin_amdgcn_mfma_f32_16x16x32_bf16(aA, bB, acc[nt], 0,0,0);
      }
      if(doC){
        short8 bW = *(const short8*)(Wsd + m*K + k0 + ks*32 + g*8);
        acc2 = __builtin_amdgcn_mfma_f32_16x16x32_bf16(aA, bW, acc2, 0,0,0);
      }
    }
    buf ^= 1;
  }

  if(VtT && bn >= 512){
    __syncthreads();
    unsigned short* T = &As[0][0];
    #pragma unroll
    for(int nt=0;nt<4;nt++){
      int col = bn + nt*16 + m;
      float bv = bias ? bias[col] : 0.f;
      unsigned int r0 = __float_as_uint(acc[nt][0]+bv) + 0x8000u;
      unsigned int r1 = __float_as_uint(acc[nt][1]+bv) + 0x8000u;
      unsigned int r2 = __float_as_uint(acc[nt][2]+bv) + 0x8000u;
      unsigned int r3 = __float_as_uint(acc[nt][3]+bv) + 0x8000u;
      uint2 pk;
      pk.x = __builtin_amdgcn_perm(r1, r0, 0x07060302u);
      pk.y = __builtin_amdgcn_perm(r3, r2, 0x07060302u);
      *(uint2*)&T[(nt*16 + m)*72 + w*16 + g*4] = pk;
    }
    __syncthreads();
    int d  = t >> 2;
    int qc = (t & 3) * 16;
    short8 v0 = *(const short8*)&T[d*72 + qc];
    short8 v1 = *(const short8*)&T[d*72 + qc + 8];
    unsigned short* dst = VtT + (size_t)(bn - 512 + d)*M + bm + qc;
    *(short8*)(dst)     = v0;
    *(short8*)(dst + 8) = v1;
    return;
  }

  #pragma unroll
  for(int nt=0;nt<4;nt++){
    int col = bn + nt*16 + m;
    float bv = bias ? bias[col] : 0.f;
    #pragma unroll
    for(int r=0;r<4;r++){
      int row = bm + w*16 + g*4 + r;
      float v = acc[nt][r] + bv;
      if(C)  C[row*N + col]  = v;
      if(Cb) Cb[row*N + col] = f2bf(v);
    }
  }
  if(doC){
    #pragma unroll
    for(int r=0;r<4;r++){
      int row = bm + w*16 + g*4 + r;
      if(m<4)      als[row*4 + m]     = acc2[r];
      else if(m<8) ald[row*4 + (m-4)] = acc2[r];
    }
  }
}

// ---------------- CSR scan / scatter ----------------
__global__ __launch_bounds__(1024) void csr_scan(const int* __restrict__ hist,
                                                 int* __restrict__ row_ptr,
                                                 int* __restrict__ wcnt, int N){
  __shared__ int sh[1024];
  int t = threadIdx.x;
  int base[4];
  int s = 0;
  #pragma unroll
  for(int i=0;i<4;i++){ base[i]=s; s += hist[t*4+i]; }
  sh[t] = s;
  __syncthreads();
  for(int off=1; off<1024; off<<=1){
    int x = (t>=off) ? sh[t-off] : 0;
    __syncthreads();
    sh[t] += x;
    __syncthreads();
  }
  int excl = (t==0) ? 0 : sh[t-1];
  #pragma unroll
  for(int i=0;i<4;i++){
    row_ptr[t*4+i] = excl + base[i];
    wcnt[t*4+i]    = excl + base[i];
  }
  if(t==1023) row_ptr[N] = excl + s;
}

__global__ void csr_scatter(const int* __restrict__ ei, int E, int Etot,
                            int* __restrict__ wcnt, int* __restrict__ col){
  int e = blockIdx.x*256 + threadIdx.x;
  if(e>=Etot) return;
  int s,d;
  if(e<E){ s=ei[e]&4095; d=ei[E+e]&4095; } else { s=d=e-E; }
  int pos = atomicAdd(&wcnt[d], 1);
  col[pos] = s;
}

// ------- fused GAT gather + softmax + bias + ELU + LayerNorm (+residual) -------
#define CE 128
__global__ void gat_gather_ln(const int* __restrict__ rp,
                              const int* __restrict__ col,
                              const unsigned short* __restrict__ xlb,
                              const float* __restrict__ als,
                              const float* __restrict__ ald,
                              const float* __restrict__ bias,
                              const float* __restrict__ gw,
                              const float* __restrict__ be,
                              const float* __restrict__ res,
                              float* __restrict__ out,
                              unsigned short* __restrict__ outb,
                              int D, int logC, int do_elu){
  int n = blockIdx.x, t = threadIdx.x;
  int c0 = t*2;
  int h = c0 >> logC;
  int rowW = D >> 1;
  float4 advv = *(const float4*)(ald + n*4);
  int start = rp[n], end = rp[n+1];
  const unsigned int* xw = (const unsigned int*)xlb;

  __shared__ float pw[2][CE*4];
  __shared__ int offs[2][CE];

  float acc0=0.f, acc1=0.f, den=0.f;
  int nch = (end - start + CE - 1) / CE;

  {
    int cnt = min(CE, end-start);
    if(t < cnt){
      int s = col[start+t];
      offs[0][t] = s*rowW;
      float4 av = *(const float4*)(als + s*4);
      #pragma unroll
      for(int hh=0;hh<4;hh++){
        float a = ((const float*)&av)[hh] + ((const float*)&advv)[hh];
        a = a>0.f ? a : 0.2f*a;
        pw[0][t*4+hh] = __expf(a);
      }
    }
  }

  for(int c=0;c<nch;c++){
    __syncthreads();
    if(c+1 < nch){
      int base = start + (c+1)*CE;
      int cnt = min(CE, end-base);
      int b2 = (c+1)&1;
      if(t < cnt){
        int s = col[base+t];
        offs[b2][t] = s*rowW;
        float4 av = *(const float4*)(als + s*4);
        #pragma unroll
        for(int hh=0;hh<4;hh++){
          float a = ((const float*)&av)[hh] + ((const float*)&advv)[hh];
          a = a>0.f ? a : 0.2f*a;
          pw[b2][t*4+hh] = __expf(a);
        }
      }
    }
    int base = start + c*CE;
    int cnt = min(CE, end-base);
    int b = c&1;
    #pragma unroll 8
    for(int j=0;j<cnt;j++){
      float p = pw[b][j*4+h];
      unsigned int u = xw[offs[b][j] + t];
      acc0 += p * bf2f((unsigned short)(u & 0xffffu));
      acc1 += p * bf2f((unsigned short)(u >> 16));
      den += p;
    }
  }

  float inv_d = 1.f/(den + 1e-16f);
  float v0 = acc0*inv_d + bias[c0];
  float v1 = acc1*inv_d + bias[c0+1];
  if(do_elu){
    v0 = v0>0.f ? v0 : expm1f(v0);
    v1 = v1>0.f ? v1 : expm1f(v1);
  }
  __shared__ float sh[4];
  int lane=t&63, wid=t>>6, nw = blockDim.x>>6;
  float sum = waveReduceSum(v0+v1);
  if(lane==0) sh[wid]=sum;
  __syncthreads();
  float mean = 0.f;
  for(int i=0;i<nw;i++) mean += sh[i];
  mean /= (float)D;
  __syncthreads();
  float d0 = v0-mean, d1 = v1-mean;
  float vs = waveReduceSum(d0*d0 + d1*d1);
  if(lane==0) sh[wid]=vs;
  __syncthreads();
  float var = 0.f;
  for(int i=0;i<nw;i++) var += sh[i];
  var /= (float)D;
  float inv = rsqrtf(var + 1e-5f);
  float y0 = d0*inv*gw[c0]   + be[c0];
  float y1 = d1*inv*gw[c0+1] + be[c0+1];
  if(res){ float2 rv = *(const float2*)(res + n*D + c0); y0 += rv.x; y1 += rv.y; }
  if(out) *(float2*)(out + n*D + c0) = make_float2(y0, y1);
  if(outb) ((unsigned int*)outb)[n*rowW + t] =
      (unsigned int)f2bf(y0) | ((unsigned int)f2bf(y1) << 16);
}

// --------- MFMA bf16 MHA: raw v_exp, l via ones-MFMA, KS=8 for latency overlap ---------
#define KS 8
__global__ __launch_bounds__(256) void attention12(const unsigned short* __restrict__ QKV,
                                                   const unsigned short* __restrict__ Vt,
                                                   float* __restrict__ Op,
                                                   float* __restrict__ lp, int S){
  const int RS = 768;
  int qb = blockIdx.x * 64;
  int h  = blockIdx.y;
  int ks = blockIdx.z;
  int t  = threadIdx.x;
  int lane = t & 63, w = t >> 6;
  int m = lane & 15, g = lane >> 4;
  int m7 = m & 7;

  __shared__ unsigned short Ps[64*64];
  __shared__ unsigned short Vs[32*64];
  __shared__ unsigned short Ks[64*36];

  short8 aQ = *(const short8*)(QKV + (qb + w*16 + m)*RS + h*32 + g*8);
  short8 vones;
  #pragma unroll
  for(int j=0;j<8;j++) vones[j] = (short)0x3F80;   // bf16 1.0

  float4v o0 = {0.f,0.f,0.f,0.f}, o1 = {0.f,0.f,0.f,0.f};
  float4v lacc = {0.f,0.f,0.f,0.f};

  int r8 = t>>3, c8 = t&7;
  int kr = t>>2, kc = (t&3)*8;
  int kA = ks*(S/KS), kB = kA + S/KS;

  for(int kt=kA; kt<kB; kt+=64){
    short8 v = *(const short8*)(Vt + (h*32 + r8)*S + kt + c8*8);
    short8 kv = *(const short8*)(QKV + (kt + kr)*RS + 256 + h*32 + kc);
    __syncthreads();
    *(short8*)&Vs[r8*64 + ((c8 ^ (r8&7))<<3)] = v;
    *(short8*)&Ks[kr*36 + kc] = kv;
    __syncthreads();

    #pragma unroll
    for(int nt=0;nt<4;nt++){
      short8 aK = *(const short8*)&Ks[(nt*16 + m)*36 + g*8];
      float4v acc = {0.f,0.f,0.f,0.f};
      acc = __builtin_amdgcn_mfma_f32_16x16x32_bf16(aK, aQ, acc, 0,0,0);
      float p0 = EXP2(acc[0]);
      float p1 = EXP2(acc[1]);
      float p2 = EXP2(acc[2]);
      float p3 = EXP2(acc[3]);
      unsigned int r0 = __float_as_uint(p0) + 0x8000u;
      unsigned int r1 = __float_as_uint(p1) + 0x8000u;
      unsigned int r2 = __float_as_uint(p2) + 0x8000u;
      unsigned int r3 = __float_as_uint(p3) + 0x8000u;
      uint2 pk;
      pk.x = __builtin_amdgcn_perm(r1, r0, 0x07060302u);
      pk.y = __builtin_amdgcn_perm(r3, r2, 0x07060302u);
      *(uint2*)&Ps[(w*16 + m)*64 + (((2*nt + (g>>1)) ^ m7)<<3) + ((g&1)<<2)] = pk;
    }

    #pragma unroll
    for(int kh=0;kh<2;kh++){
      int swz = ((kh*4 + g) ^ m7) << 3;
      short8 aP  = *(const short8*)&Ps[(w*16 + m)*64 + swz];
      short8 bV0 = *(const short8*)&Vs[m*64       + swz];
      short8 bV1 = *(const short8*)&Vs[(16+m)*64  + swz];
      o0 = __builtin_amdgcn_mfma_f32_16x16x32_bf16(aP, bV0, o0, 0,0,0);
      o1 = __builtin_amdgcn_mfma_f32_16x16x32_bf16(aP, bV1, o1, 0,0,0);
      lacc = __builtin_amdgcn_mfma_f32_16x16x32_bf16(aP, vones, lacc, 0,0,0);
    }
  }

  float* Ob = Op + (size_t)ks*S*256;
  #pragma unroll
  for(int r=0;r<4;r++){
    int q = qb + w*16 + g*4 + r;
    Ob[q*256 + h*32 + m]      = o0[r];
    Ob[q*256 + h*32 + 16 + m] = o1[r];
  }
  if(m==0){
    #pragma unroll
    for(int r=0;r<4;r++){
      int q = qb + w*16 + g*4 + r;
      lp[ks*S*8 + q*8 + h] = lacc[r];
    }
  }
}

__global__ __launch_bounds__(256) void combine(const float* __restrict__ Op,
                                               const float* __restrict__ lp,
                                               unsigned short* __restrict__ aob, int S){
  int q = blockIdx.x, t = threadIdx.x;
  int h = t >> 5;
  float o = 0.f, l = 0.f;
  #pragma unroll
  for(int s=0;s<KS;s++) o += Op[(size_t)s*S*256 + q*256 + t];
  #pragma unroll
  for(int s=0;s<KS;s++) l += lp[s*S*8 + q*8 + h];
  aob[q*256 + t] = f2bf(o / l);
}

extern "C" void kernel_launch(void* const* d_in, const int* in_sizes, int n_in,
                              void* d_out, int out_size, void* d_ws, size_t ws_size,
                              hipStream_t stream) {
  const float* x   = (const float*)d_in[0];
  const int*   ei  = (const int*)d_in[1];
  const float* W0  = (const float*)d_in[2];
  const float* as0 = (const float*)d_in[3];
  const float* ad0 = (const float*)d_in[4];
  const float* b0  = (const float*)d_in[5];
  const float* W1  = (const float*)d_in[6];
  const float* as1 = (const float*)d_in[7];
  const float* ad1 = (const float*)d_in[8];
  const float* b1  = (const float*)d_in[9];
  const float* W2  = (const float*)d_in[10];
  const float* as2 = (const float*)d_in[11];
  const float* ad2 = (const float*)d_in[12];
  const float* b2  = (const float*)d_in[13];
  const float* g0  = (const float*)d_in[14];
  const float* be0 = (const float*)d_in[15];
  const float* g1  = (const float*)d_in[16];
  const float* be1 = (const float*)d_in[17];
  const float* g2  = (const float*)d_in[18];
  const float* be2 = (const float*)d_in[19];
  const float* wq  = (const float*)d_in[20];
  const float* bq  = (const float*)d_in[21];
  const float* wk  = (const float*)d_in[22];
  const float* bk  = (const float*)d_in[23];
  const float* wv  = (const float*)d_in[24];
  const float* bv  = (const float*)d_in[25];
  const float* wo  = (const float*)d_in[26];
  const float* bo  = (const float*)d_in[27];
  float* out = (float*)d_out;

  const int N = 4096;
  const int E = in_sizes[1] / 2;
  const int Etot = E + N;

  char* p = (char*)d_ws;
  auto alloc = [&](size_t bytes){ char* r = p; p += (bytes + 255) & ~(size_t)255; return r; };

  float* h0   = (float*)alloc(N*512*4);
  float* als  = (float*)alloc(N*4*4);
  float* ald  = (float*)alloc(N*4*4);
  unsigned short* xb   = (unsigned short*)alloc(N*128*2);
  unsigned short* xlb  = (unsigned short*)alloc(N*512*2);
  unsigned short* h0b  = (unsigned short*)alloc(N*512*2);
  unsigned short* h1b  = (unsigned short*)alloc(N*512*2);
  unsigned short* h2b  = (unsigned short*)alloc(N*256*2);
  unsigned short* QKVb = (unsigned short*)alloc((size_t)N*768*2);
  unsigned short* Vt   = (unsigned short*)alloc(256*N*2);
  unsigned short* aob  = (unsigned short*)alloc(N*256*2);
  unsigned short* W0t  = (unsigned short*)alloc(512*128*2);
  unsigned short* W1t  = (unsigned short*)alloc(512*512*2);
  unsigned short* W2t  = (unsigned short*)alloc(256*512*2);
  unsigned short* wqkvt= (unsigned short*)alloc(768*256*2);
  float* bqkv = (float*)alloc(768*4);
  unsigned short* wot  = (unsigned short*)alloc(256*256*2);
  unsigned short* Wsd0 = (unsigned short*)alloc(16*128*2);
  unsigned short* Wsd1 = (unsigned short*)alloc(16*512*2);
  unsigned short* Wsd2 = (unsigned short*)alloc(16*512*2);
  float* Op = (float*)alloc((size_t)KS*N*256*4);
  float* lp = (float*)alloc((size_t)KS*N*8*4);
  int* hist = (int*)alloc(N*4);
  int* wcnt = (int*)alloc(N*4);
  int* rp   = (int*)alloc((N+2)*4);
  int* col  = (int*)alloc(Etot*4);

  // ---------- prep (x conv + bqkv + tiled transposes + Wsd + csr_count) ----------
  hipMemsetAsync(hist, 0, N*sizeof(int), stream);
  prep<<<3377 + (Etot+255)/256, 256, 0, stream>>>(x, xb, W0, W0t, W1, W1t, W2, W2t,
                                 wq, wk, wv, wqkvt, bq, bk, bv, bqkv, wo, wot,
                                 as0, ad0, Wsd0, as1, ad1, Wsd1, as2, ad2, Wsd2,
                                 ei, E, Etot, hist);

  // ---------- CSR scan + scatter ----------
  csr_scan<<<1, 1024, 0, stream>>>(hist, rp, wcnt, N);
  csr_scatter<<<(Etot+255)/256, 256, 0, stream>>>(ei, E, Etot, wcnt, col);

  // ---------- GAT layer 0: 128 -> 4x128 (512) ----------
  gemm_mfma<<<dim3(8, 64), 256, 0, stream>>>(xb, W0t, nullptr, nullptr, xlb, nullptr, Wsd0, als, ald, N, 128, 512);
  gat_gather_ln<<<N, 256, 0, stream>>>(rp, col, xlb, als, ald, b0, g0, be0,
                                       nullptr, h0, h0b, 512, 7, 1);

  // ---------- GAT layer 1: 512 -> 4x128 (512), residual ----------
  gemm_mfma<<<dim3(8, 64), 256, 0, stream>>>(h0b, W1t, nullptr, nullptr, xlb, nullptr, Wsd1, als, ald, N, 512, 512);
  gat_gather_ln<<<N, 256, 0, stream>>>(rp, col, xlb, als, ald, b1, g1, be1,
                                       h0, nullptr, h1b, 512, 7, 1);

  // ---------- GAT layer 2: 512 -> 1x256, 1 head, no ELU ----------
  gemm_mfma<<<dim3(4, 64), 256, 0, stream>>>(h1b, W2t, nullptr, nullptr, xlb, nullptr, Wsd2, als, ald, N, 512, 256);
  gat_gather_ln<<<N, 128, 0, stream>>>(rp, col, xlb, als, ald, b2, g2, be2,
                                       nullptr, nullptr, h2b, 256, 8, 0);

  // ---------- dense MHA (fused QKV GEMM w/ tiled V-transpose epilogue) ----------
  gemm_mfma<<<dim3(12, 64), 256, 0, stream>>>(h2b, wqkvt, bqkv, nullptr, QKVb, Vt, nullptr, nullptr, nullptr, N, 256, 768);
  attention12<<<dim3(N/64, 8, KS), 256, 0, stream>>>(QKVb, Vt, Op, lp, N);
  combine<<<N, 256, 0, stream>>>(Op, lp, aob, N);
  gemm_mfma<<<dim3(4, 64), 256, 0, stream>>>(aob, wot, bo, out, nullptr, nullptr, nullptr, nullptr, nullptr, N, 256, 256);
}